// Round 4
// baseline (987.455 us; speedup 1.0000x reference)
//
#include <hip/hip_runtime.h>
#include <hip/hip_bf16.h>

#define C_    768
#define NH_   8
#define DH_   96
#define S_    729
#define B_    8
#define MTOK  5832
#define C3    2304
#define GUN   12288
#define DK    6144
#define SPAD  736
#define NPB   559872   // C_*S_

typedef __attribute__((ext_vector_type(8))) short short8;
typedef __attribute__((ext_vector_type(4))) float f32x4;
typedef __attribute__((ext_vector_type(4))) unsigned int uint4v;
typedef __hip_bfloat16 bf16;

__device__ __forceinline__ void gld_lds16(const bf16* g, bf16* l) {
  __builtin_amdgcn_global_load_lds((const __attribute__((address_space(1))) void*)g,
                                   (__attribute__((address_space(3))) void*)l, 16, 0, 0);
}
__device__ __forceinline__ void gld_lds16c(const char* g, char* l) {
  __builtin_amdgcn_global_load_lds((const __attribute__((address_space(1))) void*)g,
                                   (__attribute__((address_space(3))) void*)l, 16, 0, 0);
}

// ================= 256x256 8-wave 4-phase deep-pipelined GEMM =================
// C = A @ Bt^T, A[M][K] bf16 (row stride a_rs), Bt[N][K] bf16 (row stride b_rs).
// K-chunk per z: k0 = z*Ksub. mode 0: bf16 out (Cb). mode 1: fp32 partials
// (Cf + z*c_zoff). mode 2: fused MoE epilogue — A,B give interleaved gate/up
// (col 2h = gate_h, 2h+1 = up_h); write bf16 silu(g)*u*wfull to Cb[row][col>>1].
__global__ void __launch_bounds__(512, 2)
gemm8(const bf16* __restrict__ A, long a_rs,
      const bf16* __restrict__ Bt, long b_rs,
      float* __restrict__ Cf, bf16* __restrict__ Cb,
      long c_rs, long c_zoff, int M, int N, int Ksub,
      const float* __restrict__ wfull, int mode)
{
  __shared__ __attribute__((aligned(128))) char ldsc[131072];
  const int tid = threadIdx.x;
  const int wid = tid >> 6, lid = tid & 63;
  const int wm = wid >> 2, wn = wid & 3;           // 2 x 4 wave grid
  const int fr = lid & 15, g8 = (lid >> 4) * 8;
  const int brow = blockIdx.y * 256, bcol = blockIdx.x * 256;
  const long k0b = (long)blockIdx.z * Ksub * 2;    // byte offset of K-chunk
  const long a_rsb = a_rs * 2, b_rsb = b_rs * 2;
  const char* Ab = (const char*)A;
  const char* Bb = (const char*)Bt;
  const int srow = tid >> 3;                        // 0..63 staging row
  const int scol = ((tid & 7) ^ (srow & 7)) << 4;   // pre-swizzled source col byte
  const int NT = Ksub >> 6;
  const int laneA = (wm*128 + fr)*128;
  const int laneB = 32768 + (wn*64 + fr)*128;
  const int colx0 = (g8 << 1) ^ ((fr & 7) << 4);
  const int colx1 = ((32 + g8) << 1) ^ ((fr & 7) << 4);

  f32x4 acc[8][4] = {};
  short8 a4[4][2], b4[4][2];

  auto LDA = [&](int db, int mf, int j) -> short8 {
    return *(const short8*)(ldsc + db*65536 + laneA + mf*2048 + (j ? colx1 : colx0));
  };
  auto LDB = [&](int db, int nf, int j) -> short8 {
    return *(const short8*)(ldsc + db*65536 + laneB + nf*2048 + (j ? colx1 : colx0));
  };
  auto STAGE_A = [&](int kt, int h, int db) {
    const long kb = k0b + (long)kt*128;
    #pragma unroll
    for (int c2 = 0; c2 < 2; ++c2) {
      int row = brow + h*128 + c2*64 + srow;
      if (row > M-1) row = M-1;
      gld_lds16c(Ab + (long)row*a_rsb + kb + scol,
                 ldsc + db*65536 + h*16384 + c2*8192 + wid*1024);
    }
  };
  auto STAGE_B = [&](int kt, int h, int db) {
    const long kb = k0b + (long)kt*128;
    #pragma unroll
    for (int c2 = 0; c2 < 2; ++c2) {
      int row = bcol + h*128 + c2*64 + srow;
      if (row > N-1) row = N-1;
      gld_lds16c(Bb + (long)row*b_rsb + kb + scol,
                 ldsc + db*65536 + 32768 + h*16384 + c2*8192 + wid*1024);
    }
  };

  // prologue: tile0 full, plus B0(1), A0(1)
  STAGE_A(0, 0, 0); STAGE_A(0, 1, 0);
  STAGE_B(0, 0, 0); STAGE_B(0, 1, 0);
  if (NT > 1) {
    STAGE_B(1, 0, 1); STAGE_A(1, 0, 1);
    asm volatile("s_waitcnt vmcnt(4)" ::: "memory");
  } else {
    asm volatile("s_waitcnt vmcnt(0)" ::: "memory");
  }
  __builtin_amdgcn_s_barrier();

  for (int t = 0; t < NT; ++t) {
    const int db = t & 1, nb = db ^ 1;
    // ---- phase 0: Q(m0..3, n0..1) ----
    #pragma unroll
    for (int mf = 0; mf < 4; ++mf)
      #pragma unroll
      for (int j = 0; j < 2; ++j) a4[mf][j] = LDA(db, mf, j);
    #pragma unroll
    for (int nf = 0; nf < 2; ++nf)
      #pragma unroll
      for (int j = 0; j < 2; ++j) b4[nf][j] = LDB(db, nf, j);
    if (t+1 < NT) STAGE_A(t+1, 1, nb);
    __builtin_amdgcn_s_barrier();
    asm volatile("s_waitcnt lgkmcnt(0)" ::: "memory");
    __builtin_amdgcn_sched_barrier(0);
    __builtin_amdgcn_s_setprio(1);
    #pragma unroll
    for (int mf = 0; mf < 4; ++mf)
      #pragma unroll
      for (int nf = 0; nf < 2; ++nf)
        #pragma unroll
        for (int j = 0; j < 2; ++j)
          acc[mf][nf] = __builtin_amdgcn_mfma_f32_16x16x32_bf16(a4[mf][j], b4[nf][j], acc[mf][nf], 0, 0, 0);
    __builtin_amdgcn_s_setprio(0);
    __builtin_amdgcn_s_barrier();
    // ---- phase 1: Q(m0..3, n2..3) ----
    #pragma unroll
    for (int nf = 2; nf < 4; ++nf)
      #pragma unroll
      for (int j = 0; j < 2; ++j) b4[nf][j] = LDB(db, nf, j);
    if (t+1 < NT) STAGE_B(t+1, 1, nb);
    __builtin_amdgcn_s_barrier();
    asm volatile("s_waitcnt lgkmcnt(0)" ::: "memory");
    __builtin_amdgcn_sched_barrier(0);
    __builtin_amdgcn_s_setprio(1);
    #pragma unroll
    for (int mf = 0; mf < 4; ++mf)
      #pragma unroll
      for (int nf = 2; nf < 4; ++nf)
        #pragma unroll
        for (int j = 0; j < 2; ++j)
          acc[mf][nf] = __builtin_amdgcn_mfma_f32_16x16x32_bf16(a4[mf][j], b4[nf][j], acc[mf][nf], 0, 0, 0);
    __builtin_amdgcn_s_setprio(0);
    __builtin_amdgcn_s_barrier();
    // ---- phase 2: Q(m4..7, n2..3) ----
    #pragma unroll
    for (int mi = 0; mi < 4; ++mi)
      #pragma unroll
      for (int j = 0; j < 2; ++j) a4[mi][j] = LDA(db, 4+mi, j);
    if (t+2 < NT) STAGE_B(t+2, 0, db);
    __builtin_amdgcn_s_barrier();
    asm volatile("s_waitcnt lgkmcnt(0)" ::: "memory");
    __builtin_amdgcn_sched_barrier(0);
    __builtin_amdgcn_s_setprio(1);
    #pragma unroll
    for (int mi = 0; mi < 4; ++mi)
      #pragma unroll
      for (int nf = 2; nf < 4; ++nf)
        #pragma unroll
        for (int j = 0; j < 2; ++j)
          acc[4+mi][nf] = __builtin_amdgcn_mfma_f32_16x16x32_bf16(a4[mi][j], b4[nf][j], acc[4+mi][nf], 0, 0, 0);
    __builtin_amdgcn_s_setprio(0);
    __builtin_amdgcn_s_barrier();
    // ---- phase 3: Q(m4..7, n0..1) ----
    if (t+2 < NT) STAGE_A(t+2, 0, db);
    __builtin_amdgcn_s_barrier();
    __builtin_amdgcn_s_setprio(1);
    #pragma unroll
    for (int mi = 0; mi < 4; ++mi)
      #pragma unroll
      for (int nf = 0; nf < 2; ++nf)
        #pragma unroll
        for (int j = 0; j < 2; ++j)
          acc[4+mi][nf] = __builtin_amdgcn_mfma_f32_16x16x32_bf16(a4[mi][j], b4[nf][j], acc[4+mi][nf], 0, 0, 0);
    __builtin_amdgcn_s_setprio(0);
    if (t+2 < NT)      asm volatile("s_waitcnt vmcnt(4)" ::: "memory");
    else if (t+1 < NT) asm volatile("s_waitcnt vmcnt(0)" ::: "memory");
    __builtin_amdgcn_s_barrier();
  }

  const int rg = (lid >> 4) * 4;
  if (mode == 2) {
    // fused silu(g)*u*w epilogue; even lanes hold gate col, odd lanes up col
    #pragma unroll
    for (int mf = 0; mf < 8; ++mf) {
      #pragma unroll
      for (int nf = 0; nf < 4; ++nf) {
        const int col = bcol + wn*64 + nf*16 + fr;
        const int e = col >> 12;
        #pragma unroll
        for (int j = 0; j < 4; ++j) {
          const int row = brow + wm*128 + mf*16 + rg + j;
          float v = acc[mf][nf][j];
          float u = __shfl_xor(v, 1);
          if (!(lid & 1) && row < M) {
            float w = wfull[row*3 + e];
            float sg = v / (1.f + __expf(-v));
            Cb[(long)row*c_rs + (col >> 1)] = __float2bfloat16(sg * u * w);
          }
        }
      }
    }
  } else {
    #pragma unroll
    for (int mf = 0; mf < 8; ++mf) {
      #pragma unroll
      for (int nf = 0; nf < 4; ++nf) {
        const int col = bcol + wn*64 + nf*16 + fr;
        if (col < N) {
          #pragma unroll
          for (int j = 0; j < 4; ++j) {
            const int row = brow + wm*128 + mf*16 + rg + j;
            if (row < M) {
              long off = (long)row*c_rs + col;
              if (mode == 0) Cb[off] = __float2bfloat16(acc[mf][nf][j]);
              else           Cf[(long)blockIdx.z*c_zoff + off] = acc[mf][nf][j];
            }
          }
        }
      }
    }
  }
}

// ---------------- bf16x3 split GEMM: A=(Ah+Al), B=(Bh+Bl), 3 products ----------------
__global__ void __launch_bounds__(256)
gemm3_bt(const bf16* __restrict__ Ah, const bf16* __restrict__ Al,
         long a_rs, long a_oo, long a_oi,
         const bf16* __restrict__ Bth, const bf16* __restrict__ Btl,
         long b_rs, long b_oo, long b_oi,
         float* __restrict__ Cf, bf16* __restrict__ Ch, bf16* __restrict__ Cl,
         long c_rs, long c_oo, long c_oi,
         int M, int N, int K, int nlim, int zdiv)
{
  __shared__ bf16 lAh[4096];
  __shared__ bf16 lAl[4096];
  __shared__ bf16 lBh[4096];
  __shared__ bf16 lBl[4096];
  const int tid = threadIdx.x;
  const int wid = tid >> 6;
  const int lid = tid & 63;
  const int z = blockIdx.z;
  const int zo = z / zdiv, zi = z - zo*zdiv;
  const long aoff = (long)zo*a_oo + (long)zi*a_oi;
  const long boff = (long)zo*b_oo + (long)zi*b_oi;
  const long cbase = (long)zo*c_oo + (long)zi*c_oi;
  const int brow = blockIdx.y * 128;
  const int bcol = blockIdx.x * 128;

  const int ch0 = tid, ch1 = tid + 256;
  int ra0 = brow + (ch0 >> 2); if (ra0 > M-1) ra0 = M-1;
  int ra1 = brow + (ch1 >> 2); if (ra1 > M-1) ra1 = M-1;
  int rb0 = bcol + (ch0 >> 2); if (rb0 > N-1) rb0 = N-1;
  int rb1 = bcol + (ch1 >> 2); if (rb1 > N-1) rb1 = N-1;
  const long ia0 = aoff + (long)ra0*a_rs + (ch0 & 3)*8;
  const long ia1 = aoff + (long)ra1*a_rs + (ch1 & 3)*8;
  const long ib0 = boff + (long)rb0*b_rs + (ch0 & 3)*8;
  const long ib1 = boff + (long)rb1*b_rs + (ch1 & 3)*8;
  bf16* dAh0 = (bf16*)((char*)lAh + wid*1024);
  bf16* dAh1 = (bf16*)((char*)lAh + 4096 + wid*1024);
  bf16* dAl0 = (bf16*)((char*)lAl + wid*1024);
  bf16* dAl1 = (bf16*)((char*)lAl + 4096 + wid*1024);
  bf16* dBh0 = (bf16*)((char*)lBh + wid*1024);
  bf16* dBh1 = (bf16*)((char*)lBh + 4096 + wid*1024);
  bf16* dBl0 = (bf16*)((char*)lBl + wid*1024);
  bf16* dBl1 = (bf16*)((char*)lBl + 4096 + wid*1024);

  f32x4 acc[4][4] = {};
  const int wm = wid >> 1, wn = wid & 1;
  const int fr = lid & 15, g8 = (lid >> 4) * 8;

  for (int kt = 0; kt < K; kt += 32) {
    __syncthreads();
    gld_lds16(Ah + ia0 + kt, dAh0);
    gld_lds16(Ah + ia1 + kt, dAh1);
    gld_lds16(Al + ia0 + kt, dAl0);
    gld_lds16(Al + ia1 + kt, dAl1);
    gld_lds16(Bth + ib0 + kt, dBh0);
    gld_lds16(Bth + ib1 + kt, dBh1);
    gld_lds16(Btl + ib0 + kt, dBl0);
    gld_lds16(Btl + ib1 + kt, dBl1);
    __syncthreads();
    short8 fah[4], fal[4], fbh[4], fbl[4];
    #pragma unroll
    for (int m = 0; m < 4; ++m) {
      int ro = (wm*64 + m*16 + fr)*32 + g8;
      fah[m] = *(const short8*)&lAh[ro];
      fal[m] = *(const short8*)&lAl[ro];
    }
    #pragma unroll
    for (int n = 0; n < 4; ++n) {
      int ro = (wn*64 + n*16 + fr)*32 + g8;
      fbh[n] = *(const short8*)&lBh[ro];
      fbl[n] = *(const short8*)&lBl[ro];
    }
    #pragma unroll
    for (int m = 0; m < 4; ++m)
      #pragma unroll
      for (int n = 0; n < 4; ++n) {
        acc[m][n] = __builtin_amdgcn_mfma_f32_16x16x32_bf16(fal[m], fbh[n], acc[m][n], 0, 0, 0);
        acc[m][n] = __builtin_amdgcn_mfma_f32_16x16x32_bf16(fah[m], fbl[n], acc[m][n], 0, 0, 0);
        acc[m][n] = __builtin_amdgcn_mfma_f32_16x16x32_bf16(fah[m], fbh[n], acc[m][n], 0, 0, 0);
      }
  }

  const int rg = (lid >> 4) * 4;
  #pragma unroll
  for (int m = 0; m < 4; ++m) {
    #pragma unroll
    for (int n = 0; n < 4; ++n) {
      const int col = bcol + wn*64 + n*16 + fr;
      if (col < nlim) {
        #pragma unroll
        for (int j = 0; j < 4; ++j) {
          const int row = brow + wm*64 + m*16 + rg + j;
          if (row < M) {
            long off = cbase + (long)row*c_rs + col;
            float v = acc[m][n][j];
            if (Cl) {
              bf16 h = __float2bfloat16(v);
              Ch[off] = h;
              Cl[off] = __float2bfloat16(v - __bfloat162float(h));
            } else if (Ch) {
              Ch[off] = __float2bfloat16(v);
            } else {
              Cf[off] = v;
            }
          }
        }
      }
    }
  }
}

// ---------------- weight transpose fp32 -> bf16, out[rmul*c + radd][r] ----------------
__global__ void wtrans(const float* __restrict__ in, bf16* __restrict__ out,
                       int R, int Cc, long in_rs, long out_rs, long in_bs, long out_bs,
                       int rmul, int radd)
{
  __shared__ float tile[32][33];
  in  += (long)blockIdx.z * in_bs;
  out += (long)blockIdx.z * out_bs;
  int r0 = blockIdx.y*32, c0 = blockIdx.x*32;
  int tx = threadIdx.x, ty = threadIdx.y;
  #pragma unroll
  for (int i = 0; i < 32; i += 8) {
    int r = r0 + ty + i, c = c0 + tx;
    if (r < R && c < Cc) tile[ty+i][tx] = in[(long)r*in_rs + c];
  }
  __syncthreads();
  #pragma unroll
  for (int i = 0; i < 32; i += 8) {
    int ro = c0 + ty + i, co = r0 + tx;
    if (ro < Cc && co < R) out[(long)(ro*rmul + radd)*out_rs + co] = __float2bfloat16(tile[tx][ty+i]);
  }
}

// ---------------- weight transpose fp32 -> bf16 hi/lo pair ----------------
__global__ void wtrans3(const float* __restrict__ in, bf16* __restrict__ oh, bf16* __restrict__ ol,
                        int R, int Cc, long in_rs, long out_rs)
{
  __shared__ float tile[32][33];
  int r0 = blockIdx.y*32, c0 = blockIdx.x*32;
  int tx = threadIdx.x, ty = threadIdx.y;
  #pragma unroll
  for (int i = 0; i < 32; i += 8) {
    int r = r0 + ty + i, c = c0 + tx;
    if (r < R && c < Cc) tile[ty+i][tx] = in[(long)r*in_rs + c];
  }
  __syncthreads();
  #pragma unroll
  for (int i = 0; i < 32; i += 8) {
    int ro = c0 + ty + i, co = r0 + tx;
    if (ro < Cc && co < R) {
      float v = tile[tx][ty+i];
      bf16 h = __float2bfloat16(v);
      long o = (long)ro*out_rs + co;
      oh[o] = h;
      ol[o] = __float2bfloat16(v - __bfloat162float(h));
    }
  }
}

// ---------------- LayerNorm ----------------
__global__ void ln_partial(const float* __restrict__ x, float* __restrict__ part) {
  int b = blockIdx.y, blk = blockIdx.x;
  const float* xb = x + (long)b*NPB;
  int start = blk * 4374;
  float s = 0.f, ss = 0.f;
  for (int i = start + threadIdx.x; i < start + 4374; i += 256) {
    float v = xb[i]; s += v; ss += v*v;
  }
  #pragma unroll
  for (int o = 32; o; o >>= 1) { s += __shfl_down(s, o); ss += __shfl_down(ss, o); }
  __shared__ float red[2][4];
  int wid = threadIdx.x >> 6, lid = threadIdx.x & 63;
  if (lid == 0) { red[0][wid] = s; red[1][wid] = ss; }
  __syncthreads();
  if (threadIdx.x == 0) {
    float S = 0.f, SS = 0.f;
    for (int w = 0; w < 4; ++w) { S += red[0][w]; SS += red[1][w]; }
    part[(b*128 + blk)*2] = S; part[(b*128 + blk)*2 + 1] = SS;
  }
}

__global__ void ln_final(const float* __restrict__ part, float* __restrict__ stats) {
  int b = blockIdx.x, lid = threadIdx.x;
  float s = 0.f, ss = 0.f;
  for (int i = lid; i < 128; i += 64) { s += part[(b*128+i)*2]; ss += part[(b*128+i)*2+1]; }
  #pragma unroll
  for (int o = 32; o; o >>= 1) { s += __shfl_down(s, o); ss += __shfl_down(ss, o); }
  if (lid == 0) {
    float mean = s / (float)NPB;
    float var = ss / (float)NPB - mean*mean;
    stats[b*2] = mean; stats[b*2+1] = rsqrtf(var + 1e-5f);
  }
}

__global__ void ln_apply3(const float* __restrict__ x, const float* __restrict__ lnw,
                          const float* __restrict__ lnb, const float* __restrict__ stats,
                          bf16* __restrict__ th, bf16* __restrict__ tl)
{
  __shared__ float tile[32][33];
  int b = blockIdx.z;
  int s0 = blockIdx.x*32, c0 = blockIdx.y*32;
  float mean = stats[b*2], rstd = stats[b*2+1];
  int tx = threadIdx.x, ty = threadIdx.y;
  #pragma unroll
  for (int i = 0; i < 32; i += 8) {
    int c = c0 + ty + i, s = s0 + tx;
    if (s < S_) {
      long o = (long)c*S_ + s;
      tile[ty+i][tx] = (x[(long)b*NPB + o] - mean)*rstd*lnw[o] + lnb[o];
    }
  }
  __syncthreads();
  #pragma unroll
  for (int i = 0; i < 32; i += 8) {
    int s = s0 + ty + i, c = c0 + tx;
    if (s < S_) {
      float v = tile[tx][ty+i];
      bf16 h = __float2bfloat16(v);
      long o = ((long)b*S_ + s)*C_ + c;
      th[o] = h;
      tl[o] = __float2bfloat16(v - __bfloat162float(h));
    }
  }
}

// ---------------- V transpose (bf16), zero pad t in [S_, SPAD) ----------------
__global__ void vtrans(const bf16* __restrict__ qkv, bf16* __restrict__ VT) {
  __shared__ float tile[32][33];
  int z = blockIdx.z; int bb = z >> 3, h = z & 7;
  const bf16* v = qkv + (long)bb*S_*C3 + 1536 + h*DH_;
  bf16* o = VT + (long)z*DH_*SPAD;
  int t0 = blockIdx.y*32, d0 = blockIdx.x*32;
  int tx = threadIdx.x, ty = threadIdx.y;
  #pragma unroll
  for (int i = 0; i < 32; i += 8) {
    int t = t0 + ty + i, d = d0 + tx;
    float val = 0.f;
    if (t < S_ && d < DH_) val = __bfloat162float(v[(long)t*C3 + d]);
    tile[ty+i][tx] = val;
  }
  __syncthreads();
  #pragma unroll
  for (int i = 0; i < 32; i += 8) {
    int d = d0 + ty + i, t = t0 + tx;
    if (d < DH_ && t < SPAD) o[(long)d*SPAD + t] = __float2bfloat16(tile[tx][ty+i]);
  }
}

// ---------------- softmax fp32 -> P hi/lo bf16, IN PLACE over scores row ----------------
__global__ void softmax3(float* __restrict__ scores, int nrows) {
  int row = blockIdx.x*4 + (threadIdx.x >> 6);
  if (row >= nrows) return;
  int lid = threadIdx.x & 63;
  float* src = scores + (long)row*SPAD;
  float vals[12];
  float mx = -1e30f;
  #pragma unroll
  for (int i = 0; i < 12; ++i) {
    int t = i*64 + lid;
    float v = (t < S_) ? src[t] : -1e30f;
    vals[i] = v; mx = fmaxf(mx, v);
  }
  #pragma unroll
  for (int o = 32; o; o >>= 1) mx = fmaxf(mx, __shfl_xor(mx, o));
  float sum = 0.f;
  #pragma unroll
  for (int i = 0; i < 12; ++i) { float e = __expf(vals[i] - mx); vals[i] = e; sum += e; }
  #pragma unroll
  for (int o = 32; o; o >>= 1) sum += __shfl_xor(sum, o);
  float inv = 1.f / sum;
  bf16* ph = (bf16*)src;
  bf16* pl = ph + SPAD;
  #pragma unroll
  for (int i = 0; i < 12; ++i) {
    int t = i*64 + lid;
    if (t < SPAD) {
      float p = (t < S_) ? vals[i]*inv : 0.f;
      bf16 h = __float2bfloat16(p);
      ph[t] = h;
      pl[t] = __float2bfloat16(p - __bfloat162float(h));
    }
  }
}

// ---------------- residual transpose-add 1 ----------------
__global__ void tadd1(const float* __restrict__ x, const float* __restrict__ oproj,
                      float* __restrict__ xattn, bf16* __restrict__ tok2,
                      float* __restrict__ tok2f)
{
  __shared__ float t_o[32][33];
  __shared__ float t_x[32][33];
  int b = blockIdx.z;
  int s0 = blockIdx.x*32, c0 = blockIdx.y*32;
  int tx = threadIdx.x, ty = threadIdx.y;
  #pragma unroll
  for (int i = 0; i < 32; i += 8) {
    int s = s0 + ty + i;
    if (s < S_) t_o[ty+i][tx] = oproj[((long)b*S_ + s)*C_ + c0 + tx];
    int s2 = s0 + tx;
    if (s2 < S_) t_x[ty+i][tx] = x[(long)b*NPB + (long)(c0+ty+i)*S_ + s2];
  }
  __syncthreads();
  #pragma unroll
  for (int i = 0; i < 32; i += 8) {
    int s = s0 + tx, c = c0 + ty + i;
    if (s < S_) xattn[(long)b*NPB + (long)c*S_ + s] = t_x[ty+i][tx] + t_o[tx][ty+i];
    int s2 = s0 + ty + i, c2 = c0 + tx;
    if (s2 < S_) {
      float v = t_x[tx][ty+i] + t_o[ty+i][tx];
      long o = ((long)b*S_ + s2)*C_ + c2;
      tok2[o] = __float2bfloat16(v);
      tok2f[o] = v;
    }
  }
}

// ---------------- residual transpose-add 2 (final output), sums nz moe partials ----------------
__global__ void tadd2(const float* __restrict__ xattn, const float* __restrict__ moe,
                      float* __restrict__ out, int nz)
{
  __shared__ float t_m[32][33];
  __shared__ float t_x[32][33];
  int b = blockIdx.z;
  int s0 = blockIdx.x*32, c0 = blockIdx.y*32;
  int tx = threadIdx.x, ty = threadIdx.y;
  #pragma unroll
  for (int i = 0; i < 32; i += 8) {
    int s = s0 + ty + i;
    if (s < S_) {
      long o = ((long)b*S_ + s)*C_ + c0 + tx;
      float acc = 0.f;
      for (int z = 0; z < nz; ++z) acc += moe[(long)z*MTOK*C_ + o];
      t_m[ty+i][tx] = acc;
    }
    int s2 = s0 + tx;
    if (s2 < S_) t_x[ty+i][tx] = xattn[(long)b*NPB + (long)(c0+ty+i)*S_ + s2];
  }
  __syncthreads();
  #pragma unroll
  for (int i = 0; i < 32; i += 8) {
    int s = s0 + tx, c = c0 + ty + i;
    if (s < S_) out[(long)b*NPB + (long)c*S_ + s] = t_x[ty+i][tx] + t_m[tx][ty+i];
  }
}

// ---------------- router: top-2 of 3 from fp32 tok2, normalized weights ----------------
__global__ void router_k(const float* __restrict__ tok2f, const float* __restrict__ rw,
                         float* __restrict__ wfull)
{
  int t = blockIdx.x*4 + (threadIdx.x >> 6);
  if (t >= MTOK) return;
  int lid = threadIdx.x & 63;
  const float* tk = tok2f + (long)t*C_;
  float a0 = 0.f, a1 = 0.f, a2 = 0.f;
  for (int i = lid; i < C_; i += 64) {
    float v = tk[i];
    a0 += v*rw[i*3+0]; a1 += v*rw[i*3+1]; a2 += v*rw[i*3+2];
  }
  #pragma unroll
  for (int o = 32; o; o >>= 1) {
    a0 += __shfl_xor(a0, o); a1 += __shfl_xor(a1, o); a2 += __shfl_xor(a2, o);
  }
  if (lid == 0) {
    float m = fmaxf(a0, fmaxf(a1, a2));
    float e0 = __expf(a0-m), e1 = __expf(a1-m), e2 = __expf(a2-m);
    int emin = 0; float pm = e0;
    if (e1 <= pm) { pm = e1; emin = 1; }
    if (e2 <= pm) { pm = e2; emin = 2; }
    float rest = e0 + e1 + e2 - pm;
    wfull[t*3+0] = (emin == 0) ? 0.f : e0/rest;
    wfull[t*3+1] = (emin == 1) ? 0.f : e1/rest;
    wfull[t*3+2] = (emin == 2) ? 0.f : e2/rest;
  }
}

// =============================== host ===============================
static inline void launch_gemm3(hipStream_t st,
    const bf16* Ah, const bf16* Al, long a_rs, long a_oo, long a_oi,
    const bf16* Bh, const bf16* Bl, long b_rs, long b_oo, long b_oi,
    float* Cf, bf16* Ch, bf16* Cl, long c_rs, long c_oo, long c_oi,
    int M, int N, int K, int nlim, int zdiv, int nz)
{
  dim3 g((N + 127)/128, (M + 127)/128, nz);
  gemm3_bt<<<g, 256, 0, st>>>(Ah, Al, a_rs, a_oo, a_oi, Bh, Bl, b_rs, b_oo, b_oi,
                              Cf, Ch, Cl, c_rs, c_oo, c_oi, M, N, K, nlim, zdiv);
}

extern "C" void kernel_launch(void* const* d_in, const int* in_sizes, int n_in,
                              void* d_out, int out_size, void* d_ws, size_t ws_size,
                              hipStream_t stream)
{
  const float* x      = (const float*)d_in[0];
  const float* ln_w   = (const float*)d_in[1];
  const float* ln_b   = (const float*)d_in[2];
  const float* qkv_w  = (const float*)d_in[3];
  const float* proj_w = (const float*)d_in[4];
  const float* rout_w = (const float*)d_in[5];
  const float* gate_w = (const float*)d_in[6];
  const float* up_w   = (const float*)d_in[7];
  const float* down_w = (const float*)d_in[8];
  float* out = (float*)d_out;

  char* ws = (char*)d_ws;
  size_t off = 0;
  auto alloc = [&](size_t bytes) { size_t r = off; off += (bytes + 255) & ~(size_t)255; return r; };

  // persistent
  size_t o_stats = alloc(8*2*4);
  size_t o_part  = alloc(8*128*2*4);
  size_t o_wfull = alloc((size_t)MTOK*3*4);
  size_t o_qkvTh = alloc((size_t)C3*C_*2);
  size_t o_qkvTl = alloc((size_t)C3*C_*2);
  size_t o_prjTh = alloc((size_t)C_*C_*2);
  size_t o_prjTl = alloc((size_t)C_*C_*2);
  size_t o_guT   = alloc((size_t)GUN*C_*2);
  size_t o_downT = alloc((size_t)C_*DK*2);
  size_t o_xattn = alloc((size_t)B_*NPB*4);
  size_t o_tok2  = alloc((size_t)MTOK*C_*2);
  size_t o_tok2f = alloc((size_t)MTOK*C_*4);
  size_t big0 = off;
  // phase A (attention)
  size_t o_tokh  = alloc((size_t)MTOK*C_*2);
  size_t o_tokl  = alloc((size_t)MTOK*C_*2);
  size_t o_qkvh  = alloc((size_t)MTOK*C3*2);
  size_t o_qkvl  = alloc((size_t)MTOK*C3*2);
  size_t o_VTh   = alloc((size_t)64*DH_*SPAD*2);
  size_t o_VTl   = alloc((size_t)64*DH_*SPAD*2);
  size_t o_aoh   = alloc((size_t)MTOK*C_*2);
  size_t o_aol   = alloc((size_t)MTOK*C_*2);
  size_t o_oproj = alloc((size_t)MTOK*C_*4);
  size_t o_scores= alloc((size_t)16*S_*SPAD*4);
  size_t endA = off;
  // phase B (MoE) overlaps phase A: hidden (bf16) + nz fp32 partials
  off = big0;
  size_t o_hid = alloc((size_t)MTOK*DK*2);
  size_t o_moe = alloc((size_t)MTOK*C_*4*8);   // up to 8 fp32 partials
  size_t endB8 = off;
  size_t endB1 = big0 + (((size_t)MTOK*DK*2 + 255) & ~(size_t)255)
                      + (((size_t)MTOK*C_*4 + 255) & ~(size_t)255);
  int nz;
  if (ws_size >= (endA > endB8 ? endA : endB8)) nz = 8;
  else if (ws_size >= (endA > endB1 ? endA : endB1)) nz = 1;
  else return;  // insufficient workspace: visible failure

  float* stats  = (float*)(ws + o_stats);
  float* part   = (float*)(ws + o_part);
  float* wfull  = (float*)(ws + o_wfull);
  bf16*  qkvTh  = (bf16*)(ws + o_qkvTh);
  bf16*  qkvTl  = (bf16*)(ws + o_qkvTl);
  bf16*  prjTh  = (bf16*)(ws + o_prjTh);
  bf16*  prjTl  = (bf16*)(ws + o_prjTl);
  bf16*  guT    = (bf16*)(ws + o_guT);
  bf16*  downT  = (bf16*)(ws + o_downT);
  float* xattn  = (float*)(ws + o_xattn);
  bf16*  tok2   = (bf16*)(ws + o_tok2);
  float* tok2f  = (float*)(ws + o_tok2f);
  bf16*  tokh   = (bf16*)(ws + o_tokh);
  bf16*  tokl   = (bf16*)(ws + o_tokl);
  bf16*  qkvh   = (bf16*)(ws + o_qkvh);
  bf16*  qkvl   = (bf16*)(ws + o_qkvl);
  bf16*  VTh    = (bf16*)(ws + o_VTh);
  bf16*  VTl    = (bf16*)(ws + o_VTl);
  bf16*  aoh    = (bf16*)(ws + o_aoh);
  bf16*  aol    = (bf16*)(ws + o_aol);
  float* oproj  = (float*)(ws + o_oproj);
  float* scores = (float*)(ws + o_scores);
  bf16*  hidden = (bf16*)(ws + o_hid);
  float* moe    = (float*)(ws + o_moe);

  dim3 b32(32, 8);

  // weight conversions; gate/up interleaved: guT row (e*4096 + 2h) = gate, (+1) = up
  wtrans3<<<dim3(72,24,1), b32, 0, stream>>>(qkv_w,  qkvTh, qkvTl, 768, 2304, 2304, 768);
  wtrans3<<<dim3(24,24,1), b32, 0, stream>>>(proj_w, prjTh, prjTl, 768, 768,  768,  768);
  wtrans<<<dim3(64,24,3), b32, 0, stream>>>(gate_w, guT, 768, 2048, 2048, 768,
                                            (long)768*2048, (long)4096*768, 2, 0);
  wtrans<<<dim3(64,24,3), b32, 0, stream>>>(up_w, guT, 768, 2048, 2048, 768,
                                            (long)768*2048, (long)4096*768, 2, 1);
  wtrans<<<dim3(24,64,3), b32, 0, stream>>>(down_w, downT, 2048, 768, 768, 6144,
                                            (long)2048*768, 2048, 1, 0);

  // LayerNorm -> tok hi/lo (b,s,c)
  ln_partial<<<dim3(128,8), 256, 0, stream>>>(x, part);
  ln_final<<<8, 64, 0, stream>>>(part, stats);
  ln_apply3<<<dim3(23,24,8), b32, 0, stream>>>(x, ln_w, ln_b, stats, tokh, tokl);

  // qkv = tok @ qkv_w (bf16x3, hi/lo out)
  launch_gemm3(stream, tokh, tokl, C_, 0, 0, qkvTh, qkvTl, C_, 0, 0,
               nullptr, qkvh, qkvl, C3, 0, 0, MTOK, C3, C_, C3, 1, 1);

  // V^T per (b,h), zero-padded to SPAD (hi and lo)
  vtrans<<<dim3(3,23,64), b32, 0, stream>>>(qkvh, VTh);
  vtrans<<<dim3(3,23,64), b32, 0, stream>>>(qkvl, VTl);

  // attention in 4 chunks of 16 (b,h)-pairs (2 batches each)
  for (int c = 0; c < 4; ++c) {
    const long qoff = (long)(2*c)*S_*C3;
    launch_gemm3(stream,
        qkvh + qoff, qkvl + qoff, C3, (long)S_*C3, DH_,
        qkvh + qoff + 768, qkvl + qoff + 768, C3, (long)S_*C3, DH_,
        scores, nullptr, nullptr, SPAD, (long)8*S_*SPAD, (long)S_*SPAD,
        S_, S_, DH_, SPAD, 8, 16);
    softmax3<<<2916, 256, 0, stream>>>(scores, 16*S_);
    bf16* Pbase = (bf16*)scores;
    launch_gemm3(stream,
        Pbase, Pbase + SPAD, 2*SPAD, (long)8*S_*2*SPAD, (long)S_*2*SPAD,
        VTh + (size_t)c*16*DH_*SPAD, VTl + (size_t)c*16*DH_*SPAD, SPAD,
        (long)8*DH_*SPAD, (long)DH_*SPAD,
        nullptr, aoh + (size_t)(2*c)*S_*C_, aol + (size_t)(2*c)*S_*C_,
        C_, (long)S_*C_, DH_,
        S_, DH_, SPAD, DH_, 8, 16);
  }

  // oproj = attnout @ proj_w (fp32 out)
  launch_gemm3(stream, aoh, aol, C_, 0, 0, prjTh, prjTl, C_, 0, 0,
               oproj, nullptr, nullptr, C_, 0, 0, MTOK, C_, C_, C_, 1, 1);

  // residual + layouts
  tadd1<<<dim3(23,24,8), b32, 0, stream>>>(x, oproj, xattn, tok2, tok2f);

  // router weights (fp32 path) -- must precede fused GU epilogue
  router_k<<<1458, 256, 0, stream>>>(tok2f, rout_w, wfull);

  // gate|up interleaved GEMM with fused silu*u*w epilogue -> hidden bf16 [MTOK][DK]
  gemm8<<<dim3(GUN/256, 23, 1), 512, 0, stream>>>(
      tok2, C_, guT, C_, nullptr, hidden, DK, 0, MTOK, GUN, C_, wfull, 2);

  // down GEMM (K = 6144) K-split into nz fp32 partials
  gemm8<<<dim3(C_/256, 23, nz), 512, 0, stream>>>(
      hidden, DK, downT, DK, moe, nullptr, C_, (long)MTOK*C_, MTOK, C_, DK/nz, nullptr, 1);

  // final residual transpose-add (sums partials) into output
  tadd2<<<dim3(23,24,8), b32, 0, stream>>>(xattn, moe, out, nz);
}

// Round 6
// 951.592 us; speedup vs baseline: 1.0377x; 1.0377x over previous
//
#include <hip/hip_runtime.h>
#include <hip/hip_bf16.h>

#define C_    768
#define NH_   8
#define DH_   96
#define S_    729
#define B_    8
#define MTOK  5832
#define MHALF 2916
#define C3    2304
#define GUN   12288
#define DK    6144
#define SPAD  736
#define NPB   559872   // C_*S_

typedef __attribute__((ext_vector_type(8))) short short8;
typedef __attribute__((ext_vector_type(4))) float f32x4;
typedef __attribute__((ext_vector_type(4))) unsigned int uint4v;
typedef __hip_bfloat16 bf16;

__device__ __forceinline__ void gld_lds16(const bf16* g, bf16* l) {
  __builtin_amdgcn_global_load_lds((const __attribute__((address_space(1))) void*)g,
                                   (__attribute__((address_space(3))) void*)l, 16, 0, 0);
}
__device__ __forceinline__ void gld_lds16c(const char* g, char* l) {
  __builtin_amdgcn_global_load_lds((const __attribute__((address_space(1))) void*)g,
                                   (__attribute__((address_space(3))) void*)l, 16, 0, 0);
}

// ================= 256x256 8-wave 4-phase deep-pipelined GEMM =================
// C = A @ Bt^T. Tile-pair unrolled: db is compile-time, staging pointers advance
// by +256B/pair, all LDS addrs are base+imm. XOR-swizzle byte^=(row&7)<<4 via
// pre-swizzled global source (linear gld_lds dest) + swizzled ds_read.
template<int DB>
__device__ __forceinline__ void tile_step(
    char* ldsc, char* ldsw,
    const int rA0, const int rA1, const int rB0, const int rB1,
    const char* pA0, const char* pA1, const char* pA2, const char* pA3,
    const char* pB0, const char* pB1, const char* pB2, const char* pB3,
    const int s1, const int s2, const bool gH1, const bool gH0, const int wmode,
    f32x4 (&acc)[8][4], short8 (&a4)[4][2], short8 (&b4)[4][2])
{
  const int DBO = DB * 65536;
  const int NBO = 65536 - DBO;
  // ---- phase 0: read A0-3 + B0-1; stage A-h1(t+1) ----
  #pragma unroll
  for (int mf = 0; mf < 4; ++mf) {
    a4[mf][0] = *(const short8*)(ldsc + DBO + rA0 + mf*2048);
    a4[mf][1] = *(const short8*)(ldsc + DBO + rA1 + mf*2048);
  }
  #pragma unroll
  for (int nf = 0; nf < 2; ++nf) {
    b4[nf][0] = *(const short8*)(ldsc + DBO + rB0 + nf*2048);
    b4[nf][1] = *(const short8*)(ldsc + DBO + rB1 + nf*2048);
  }
  if (gH1) {
    gld_lds16c(pA2 + s1, ldsw + NBO + 16384);
    gld_lds16c(pA3 + s1, ldsw + NBO + 16384 + 8192);
  }
  __builtin_amdgcn_s_barrier();
  asm volatile("s_waitcnt lgkmcnt(0)" ::: "memory");
  __builtin_amdgcn_sched_barrier(0);
  __builtin_amdgcn_s_setprio(1);
  #pragma unroll
  for (int mf = 0; mf < 4; ++mf)
    #pragma unroll
    for (int nf = 0; nf < 2; ++nf)
      #pragma unroll
      for (int j = 0; j < 2; ++j)
        acc[mf][nf] = __builtin_amdgcn_mfma_f32_16x16x32_bf16(a4[mf][j], b4[nf][j], acc[mf][nf], 0, 0, 0);
  __builtin_amdgcn_s_setprio(0);
  __builtin_amdgcn_s_barrier();
  // ---- phase 1: read B2-3; stage B-h1(t+1) ----
  #pragma unroll
  for (int nf = 2; nf < 4; ++nf) {
    b4[nf][0] = *(const short8*)(ldsc + DBO + rB0 + nf*2048);
    b4[nf][1] = *(const short8*)(ldsc + DBO + rB1 + nf*2048);
  }
  if (gH1) {
    gld_lds16c(pB2 + s1, ldsw + NBO + 32768 + 16384);
    gld_lds16c(pB3 + s1, ldsw + NBO + 32768 + 16384 + 8192);
  }
  __builtin_amdgcn_s_barrier();
  asm volatile("s_waitcnt lgkmcnt(0)" ::: "memory");
  __builtin_amdgcn_sched_barrier(0);
  __builtin_amdgcn_s_setprio(1);
  #pragma unroll
  for (int mf = 0; mf < 4; ++mf)
    #pragma unroll
    for (int nf = 2; nf < 4; ++nf)
      #pragma unroll
      for (int j = 0; j < 2; ++j)
        acc[mf][nf] = __builtin_amdgcn_mfma_f32_16x16x32_bf16(a4[mf][j], b4[nf][j], acc[mf][nf], 0, 0, 0);
  __builtin_amdgcn_s_setprio(0);
  __builtin_amdgcn_s_barrier();
  // ---- phase 2: read A4-7; stage B-h0(t+2) ----
  #pragma unroll
  for (int mi = 0; mi < 4; ++mi) {
    a4[mi][0] = *(const short8*)(ldsc + DBO + rA0 + (4+mi)*2048);
    a4[mi][1] = *(const short8*)(ldsc + DBO + rA1 + (4+mi)*2048);
  }
  if (gH0) {
    gld_lds16c(pB0 + s2, ldsw + DBO + 32768);
    gld_lds16c(pB1 + s2, ldsw + DBO + 32768 + 8192);
  }
  __builtin_amdgcn_s_barrier();
  asm volatile("s_waitcnt lgkmcnt(0)" ::: "memory");
  __builtin_amdgcn_sched_barrier(0);
  __builtin_amdgcn_s_setprio(1);
  #pragma unroll
  for (int mi = 0; mi < 4; ++mi)
    #pragma unroll
    for (int nf = 2; nf < 4; ++nf)
      #pragma unroll
      for (int j = 0; j < 2; ++j)
        acc[4+mi][nf] = __builtin_amdgcn_mfma_f32_16x16x32_bf16(a4[mi][j], b4[nf][j], acc[4+mi][nf], 0, 0, 0);
  __builtin_amdgcn_s_setprio(0);
  __builtin_amdgcn_s_barrier();
  // ---- phase 3: stage A-h0(t+2); MFMA m4-7 x n0-1 ----
  if (gH0) {
    gld_lds16c(pA0 + s2, ldsw + DBO);
    gld_lds16c(pA1 + s2, ldsw + DBO + 8192);
  }
  __builtin_amdgcn_s_barrier();
  __builtin_amdgcn_s_setprio(1);
  #pragma unroll
  for (int mi = 0; mi < 4; ++mi)
    #pragma unroll
    for (int nf = 0; nf < 2; ++nf)
      #pragma unroll
      for (int j = 0; j < 2; ++j)
        acc[4+mi][nf] = __builtin_amdgcn_mfma_f32_16x16x32_bf16(a4[mi][j], b4[nf][j], acc[4+mi][nf], 0, 0, 0);
  __builtin_amdgcn_s_setprio(0);
  if (wmode == 0)      asm volatile("s_waitcnt vmcnt(4)" ::: "memory");
  else if (wmode == 1) asm volatile("s_waitcnt vmcnt(0)" ::: "memory");
  __builtin_amdgcn_s_barrier();
}

__global__ void __launch_bounds__(512, 2)
gemm8(const bf16* __restrict__ A, long a_rs,
      const bf16* __restrict__ Bt, long b_rs,
      float* __restrict__ Cf, bf16* __restrict__ Cb,
      long c_rs, long c_zoff, int M, int N, int Ksub)
{
  __shared__ __attribute__((aligned(128))) char ldsc[131072];
  const int tid = threadIdx.x;
  const int wid = tid >> 6, lid = tid & 63;
  const int wm = wid >> 2, wn = wid & 3;           // 2 x 4 wave grid
  const int fr = lid & 15, g8 = (lid >> 4) * 8;
  const int brow = blockIdx.y * 256, bcol = blockIdx.x * 256;
  const long k0b = (long)blockIdx.z * Ksub * 2;
  const long a_rsb = a_rs * 2, b_rsb = b_rs * 2;
  const int srow = tid >> 3;
  const int scol = ((tid & 7) ^ (srow & 7)) << 4;
  const int NT = Ksub >> 6;
  char* ldsw = ldsc + wid * 1024;

  // per-thread global staging pointers (advance +256B per tile-pair)
  int ra0_ = brow + srow;        if (ra0_ > M-1) ra0_ = M-1;
  int ra1_ = brow + 64 + srow;   if (ra1_ > M-1) ra1_ = M-1;
  int ra2_ = brow + 128 + srow;  if (ra2_ > M-1) ra2_ = M-1;
  int ra3_ = brow + 192 + srow;  if (ra3_ > M-1) ra3_ = M-1;
  int rb0_ = bcol + srow;        if (rb0_ > N-1) rb0_ = N-1;
  int rb1_ = bcol + 64 + srow;   if (rb1_ > N-1) rb1_ = N-1;
  int rb2_ = bcol + 128 + srow;  if (rb2_ > N-1) rb2_ = N-1;
  int rb3_ = bcol + 192 + srow;  if (rb3_ > N-1) rb3_ = N-1;
  const char* pA0 = (const char*)A + (long)ra0_*a_rsb + k0b + scol;
  const char* pA1 = (const char*)A + (long)ra1_*a_rsb + k0b + scol;
  const char* pA2 = (const char*)A + (long)ra2_*a_rsb + k0b + scol;
  const char* pA3 = (const char*)A + (long)ra3_*a_rsb + k0b + scol;
  const char* pB0 = (const char*)Bt + (long)rb0_*b_rsb + k0b + scol;
  const char* pB1 = (const char*)Bt + (long)rb1_*b_rsb + k0b + scol;
  const char* pB2 = (const char*)Bt + (long)rb2_*b_rsb + k0b + scol;
  const char* pB3 = (const char*)Bt + (long)rb3_*b_rsb + k0b + scol;

  // LDS read bases (swizzled)
  const int swz = (fr & 7) << 4;
  const int cx0 = (g8 * 2) ^ swz;
  const int cx1 = (64 + g8 * 2) ^ swz;
  const int rA0 = (wm*128 + fr)*128 + cx0;
  const int rA1 = (wm*128 + fr)*128 + cx1;
  const int rB0 = 32768 + (wn*64 + fr)*128 + cx0;
  const int rB1 = 32768 + (wn*64 + fr)*128 + cx1;

  f32x4 acc[8][4] = {};
  short8 a4[4][2], b4[4][2];

  // prologue: T0 full (db0) + T1 h0 (db1)
  gld_lds16c(pA0, ldsw);
  gld_lds16c(pA1, ldsw + 8192);
  gld_lds16c(pA2, ldsw + 16384);
  gld_lds16c(pA3, ldsw + 16384 + 8192);
  gld_lds16c(pB0, ldsw + 32768);
  gld_lds16c(pB1, ldsw + 32768 + 8192);
  gld_lds16c(pB2, ldsw + 32768 + 16384);
  gld_lds16c(pB3, ldsw + 32768 + 16384 + 8192);
  gld_lds16c(pA0 + 128, ldsw + 65536);
  gld_lds16c(pA1 + 128, ldsw + 65536 + 8192);
  gld_lds16c(pB0 + 128, ldsw + 65536 + 32768);
  gld_lds16c(pB1 + 128, ldsw + 65536 + 32768 + 8192);
  asm volatile("s_waitcnt vmcnt(4)" ::: "memory");
  __builtin_amdgcn_s_barrier();

  for (int tp = 0; tp < NT; tp += 2) {
    const bool g2 = (tp + 2) < NT;
    tile_step<0>(ldsc, ldsw, rA0, rA1, rB0, rB1,
                 pA0, pA1, pA2, pA3, pB0, pB1, pB2, pB3,
                 128, 256, true, g2, g2 ? 0 : 1, acc, a4, b4);
    tile_step<1>(ldsc, ldsw, rA0, rA1, rB0, rB1,
                 pA0, pA1, pA2, pA3, pB0, pB1, pB2, pB3,
                 256, 384, g2, g2, g2 ? 0 : 2, acc, a4, b4);
    if (g2) {
      pA0 += 256; pA1 += 256; pA2 += 256; pA3 += 256;
      pB0 += 256; pB1 += 256; pB2 += 256; pB3 += 256;
    }
  }

  const int rg = (lid >> 4) * 4;
  #pragma unroll
  for (int mf = 0; mf < 8; ++mf) {
    #pragma unroll
    for (int nf = 0; nf < 4; ++nf) {
      const int col = bcol + wn*64 + nf*16 + fr;
      if (col < N) {
        #pragma unroll
        for (int j = 0; j < 4; ++j) {
          const int row = brow + wm*128 + mf*16 + rg + j;
          if (row < M) {
            long off = (long)blockIdx.z*c_zoff + (long)row*c_rs + col;
            if (Cb) Cb[off] = __float2bfloat16(acc[mf][nf][j]);
            else    Cf[off] = acc[mf][nf][j];
          }
        }
      }
    }
  }
}

// ---------------- bf16x3 split GEMM: A=(Ah+Al), B=(Bh+Bl), 3 products ----------------
__global__ void __launch_bounds__(256)
gemm3_bt(const bf16* __restrict__ Ah, const bf16* __restrict__ Al,
         long a_rs, long a_oo, long a_oi,
         const bf16* __restrict__ Bth, const bf16* __restrict__ Btl,
         long b_rs, long b_oo, long b_oi,
         float* __restrict__ Cf, bf16* __restrict__ Ch, bf16* __restrict__ Cl,
         long c_rs, long c_oo, long c_oi,
         int M, int N, int K, int nlim, int zdiv)
{
  __shared__ bf16 lAh[4096];
  __shared__ bf16 lAl[4096];
  __shared__ bf16 lBh[4096];
  __shared__ bf16 lBl[4096];
  const int tid = threadIdx.x;
  const int wid = tid >> 6;
  const int lid = tid & 63;
  const int z = blockIdx.z;
  const int zo = z / zdiv, zi = z - zo*zdiv;
  const long aoff = (long)zo*a_oo + (long)zi*a_oi;
  const long boff = (long)zo*b_oo + (long)zi*b_oi;
  const long cbase = (long)zo*c_oo + (long)zi*c_oi;
  const int brow = blockIdx.y * 128;
  const int bcol = blockIdx.x * 128;

  const int ch0 = tid, ch1 = tid + 256;
  int ra0 = brow + (ch0 >> 2); if (ra0 > M-1) ra0 = M-1;
  int ra1 = brow + (ch1 >> 2); if (ra1 > M-1) ra1 = M-1;
  int rb0 = bcol + (ch0 >> 2); if (rb0 > N-1) rb0 = N-1;
  int rb1 = bcol + (ch1 >> 2); if (rb1 > N-1) rb1 = N-1;
  const long ia0 = aoff + (long)ra0*a_rs + (ch0 & 3)*8;
  const long ia1 = aoff + (long)ra1*a_rs + (ch1 & 3)*8;
  const long ib0 = boff + (long)rb0*b_rs + (ch0 & 3)*8;
  const long ib1 = boff + (long)rb1*b_rs + (ch1 & 3)*8;
  bf16* dAh0 = (bf16*)((char*)lAh + wid*1024);
  bf16* dAh1 = (bf16*)((char*)lAh + 4096 + wid*1024);
  bf16* dAl0 = (bf16*)((char*)lAl + wid*1024);
  bf16* dAl1 = (bf16*)((char*)lAl + 4096 + wid*1024);
  bf16* dBh0 = (bf16*)((char*)lBh + wid*1024);
  bf16* dBh1 = (bf16*)((char*)lBh + 4096 + wid*1024);
  bf16* dBl0 = (bf16*)((char*)lBl + wid*1024);
  bf16* dBl1 = (bf16*)((char*)lBl + 4096 + wid*1024);

  f32x4 acc[4][4] = {};
  const int wm = wid >> 1, wn = wid & 1;
  const int fr = lid & 15, g8 = (lid >> 4) * 8;

  for (int kt = 0; kt < K; kt += 32) {
    __syncthreads();
    gld_lds16(Ah + ia0 + kt, dAh0);
    gld_lds16(Ah + ia1 + kt, dAh1);
    gld_lds16(Al + ia0 + kt, dAl0);
    gld_lds16(Al + ia1 + kt, dAl1);
    gld_lds16(Bth + ib0 + kt, dBh0);
    gld_lds16(Bth + ib1 + kt, dBh1);
    gld_lds16(Btl + ib0 + kt, dBl0);
    gld_lds16(Btl + ib1 + kt, dBl1);
    __syncthreads();
    short8 fah[4], fal[4], fbh[4], fbl[4];
    #pragma unroll
    for (int m = 0; m < 4; ++m) {
      int ro = (wm*64 + m*16 + fr)*32 + g8;
      fah[m] = *(const short8*)&lAh[ro];
      fal[m] = *(const short8*)&lAl[ro];
    }
    #pragma unroll
    for (int n = 0; n < 4; ++n) {
      int ro = (wn*64 + n*16 + fr)*32 + g8;
      fbh[n] = *(const short8*)&lBh[ro];
      fbl[n] = *(const short8*)&lBl[ro];
    }
    #pragma unroll
    for (int m = 0; m < 4; ++m)
      #pragma unroll
      for (int n = 0; n < 4; ++n) {
        acc[m][n] = __builtin_amdgcn_mfma_f32_16x16x32_bf16(fal[m], fbh[n], acc[m][n], 0, 0, 0);
        acc[m][n] = __builtin_amdgcn_mfma_f32_16x16x32_bf16(fah[m], fbl[n], acc[m][n], 0, 0, 0);
        acc[m][n] = __builtin_amdgcn_mfma_f32_16x16x32_bf16(fah[m], fbh[n], acc[m][n], 0, 0, 0);
      }
  }

  const int rg = (lid >> 4) * 4;
  #pragma unroll
  for (int m = 0; m < 4; ++m) {
    #pragma unroll
    for (int n = 0; n < 4; ++n) {
      const int col = bcol + wn*64 + n*16 + fr;
      if (col < nlim) {
        #pragma unroll
        for (int j = 0; j < 4; ++j) {
          const int row = brow + wm*64 + m*16 + rg + j;
          if (row < M) {
            long off = cbase + (long)row*c_rs + col;
            float v = acc[m][n][j];
            if (Cl) {
              bf16 h = __float2bfloat16(v);
              Ch[off] = h;
              Cl[off] = __float2bfloat16(v - __bfloat162float(h));
            } else if (Ch) {
              Ch[off] = __float2bfloat16(v);
            } else {
              Cf[off] = v;
            }
          }
        }
      }
    }
  }
}

// ---------------- weight transpose fp32 -> bf16 ----------------
__global__ void wtrans(const float* __restrict__ in, bf16* __restrict__ out,
                       int R, int Cc, long in_rs, long out_rs, long in_bs, long out_bs)
{
  __shared__ float tile[32][33];
  in  += (long)blockIdx.z * in_bs;
  out += (long)blockIdx.z * out_bs;
  int r0 = blockIdx.y*32, c0 = blockIdx.x*32;
  int tx = threadIdx.x, ty = threadIdx.y;
  #pragma unroll
  for (int i = 0; i < 32; i += 8) {
    int r = r0 + ty + i, c = c0 + tx;
    if (r < R && c < Cc) tile[ty+i][tx] = in[(long)r*in_rs + c];
  }
  __syncthreads();
  #pragma unroll
  for (int i = 0; i < 32; i += 8) {
    int ro = c0 + ty + i, co = r0 + tx;
    if (ro < Cc && co < R) out[(long)ro*out_rs + co] = __float2bfloat16(tile[tx][ty+i]);
  }
}

// ---------------- weight transpose fp32 -> bf16 hi/lo pair ----------------
__global__ void wtrans3(const float* __restrict__ in, bf16* __restrict__ oh, bf16* __restrict__ ol,
                        int R, int Cc, long in_rs, long out_rs)
{
  __shared__ float tile[32][33];
  int r0 = blockIdx.y*32, c0 = blockIdx.x*32;
  int tx = threadIdx.x, ty = threadIdx.y;
  #pragma unroll
  for (int i = 0; i < 32; i += 8) {
    int r = r0 + ty + i, c = c0 + tx;
    if (r < R && c < Cc) tile[ty+i][tx] = in[(long)r*in_rs + c];
  }
  __syncthreads();
  #pragma unroll
  for (int i = 0; i < 32; i += 8) {
    int ro = c0 + ty + i, co = r0 + tx;
    if (ro < Cc && co < R) {
      float v = tile[tx][ty+i];
      bf16 h = __float2bfloat16(v);
      long o = (long)ro*out_rs + co;
      oh[o] = h;
      ol[o] = __float2bfloat16(v - __bfloat162float(h));
    }
  }
}

// ---------------- LayerNorm ----------------
__global__ void ln_partial(const float* __restrict__ x, float* __restrict__ part) {
  int b = blockIdx.y, blk = blockIdx.x;
  const float* xb = x + (long)b*NPB;
  int start = blk * 4374;
  float s = 0.f, ss = 0.f;
  for (int i = start + threadIdx.x; i < start + 4374; i += 256) {
    float v = xb[i]; s += v; ss += v*v;
  }
  #pragma unroll
  for (int o = 32; o; o >>= 1) { s += __shfl_down(s, o); ss += __shfl_down(ss, o); }
  __shared__ float red[2][4];
  int wid = threadIdx.x >> 6, lid = threadIdx.x & 63;
  if (lid == 0) { red[0][wid] = s; red[1][wid] = ss; }
  __syncthreads();
  if (threadIdx.x == 0) {
    float S = 0.f, SS = 0.f;
    for (int w = 0; w < 4; ++w) { S += red[0][w]; SS += red[1][w]; }
    part[(b*128 + blk)*2] = S; part[(b*128 + blk)*2 + 1] = SS;
  }
}

__global__ void ln_final(const float* __restrict__ part, float* __restrict__ stats) {
  int b = blockIdx.x, lid = threadIdx.x;
  float s = 0.f, ss = 0.f;
  for (int i = lid; i < 128; i += 64) { s += part[(b*128+i)*2]; ss += part[(b*128+i)*2+1]; }
  #pragma unroll
  for (int o = 32; o; o >>= 1) { s += __shfl_down(s, o); ss += __shfl_down(ss, o); }
  if (lid == 0) {
    float mean = s / (float)NPB;
    float var = ss / (float)NPB - mean*mean;
    stats[b*2] = mean; stats[b*2+1] = rsqrtf(var + 1e-5f);
  }
}

__global__ void ln_apply3(const float* __restrict__ x, const float* __restrict__ lnw,
                          const float* __restrict__ lnb, const float* __restrict__ stats,
                          bf16* __restrict__ th, bf16* __restrict__ tl)
{
  __shared__ float tile[32][33];
  int b = blockIdx.z;
  int s0 = blockIdx.x*32, c0 = blockIdx.y*32;
  float mean = stats[b*2], rstd = stats[b*2+1];
  int tx = threadIdx.x, ty = threadIdx.y;
  #pragma unroll
  for (int i = 0; i < 32; i += 8) {
    int c = c0 + ty + i, s = s0 + tx;
    if (s < S_) {
      long o = (long)c*S_ + s;
      tile[ty+i][tx] = (x[(long)b*NPB + o] - mean)*rstd*lnw[o] + lnb[o];
    }
  }
  __syncthreads();
  #pragma unroll
  for (int i = 0; i < 32; i += 8) {
    int s = s0 + ty + i, c = c0 + tx;
    if (s < S_) {
      float v = tile[tx][ty+i];
      bf16 h = __float2bfloat16(v);
      long o = ((long)b*S_ + s)*C_ + c;
      th[o] = h;
      tl[o] = __float2bfloat16(v - __bfloat162float(h));
    }
  }
}

// ---------------- V transpose (bf16), zero pad t in [S_, SPAD) ----------------
__global__ void vtrans(const bf16* __restrict__ qkv, bf16* __restrict__ VT) {
  __shared__ float tile[32][33];
  int z = blockIdx.z; int bb = z >> 3, h = z & 7;
  const bf16* v = qkv + (long)bb*S_*C3 + 1536 + h*DH_;
  bf16* o = VT + (long)z*DH_*SPAD;
  int t0 = blockIdx.y*32, d0 = blockIdx.x*32;
  int tx = threadIdx.x, ty = threadIdx.y;
  #pragma unroll
  for (int i = 0; i < 32; i += 8) {
    int t = t0 + ty + i, d = d0 + tx;
    float val = 0.f;
    if (t < S_ && d < DH_) val = __bfloat162float(v[(long)t*C3 + d]);
    tile[ty+i][tx] = val;
  }
  __syncthreads();
  #pragma unroll
  for (int i = 0; i < 32; i += 8) {
    int d = d0 + ty + i, t = t0 + tx;
    if (d < DH_ && t < SPAD) o[(long)d*SPAD + t] = __float2bfloat16(tile[tx][ty+i]);
  }
}

// ---------------- softmax fp32 -> P hi/lo bf16, IN PLACE over scores row ----------------
__global__ void softmax3(float* __restrict__ scores, int nrows) {
  int row = blockIdx.x*4 + (threadIdx.x >> 6);
  if (row >= nrows) return;
  int lid = threadIdx.x & 63;
  float* src = scores + (long)row*SPAD;
  float vals[12];
  float mx = -1e30f;
  #pragma unroll
  for (int i = 0; i < 12; ++i) {
    int t = i*64 + lid;
    float v = (t < S_) ? src[t] : -1e30f;
    vals[i] = v; mx = fmaxf(mx, v);
  }
  #pragma unroll
  for (int o = 32; o; o >>= 1) mx = fmaxf(mx, __shfl_xor(mx, o));
  float sum = 0.f;
  #pragma unroll
  for (int i = 0; i < 12; ++i) { float e = __expf(vals[i] - mx); vals[i] = e; sum += e; }
  #pragma unroll
  for (int o = 32; o; o >>= 1) sum += __shfl_xor(sum, o);
  float inv = 1.f / sum;
  bf16* ph = (bf16*)src;
  bf16* pl = ph + SPAD;
  #pragma unroll
  for (int i = 0; i < 12; ++i) {
    int t = i*64 + lid;
    if (t < SPAD) {
      float p = (t < S_) ? vals[i]*inv : 0.f;
      bf16 h = __float2bfloat16(p);
      ph[t] = h;
      pl[t] = __float2bfloat16(p - __bfloat162float(h));
    }
  }
}

// ---------------- residual transpose-add 1 ----------------
__global__ void tadd1(const float* __restrict__ x, const float* __restrict__ oproj,
                      float* __restrict__ xattn, bf16* __restrict__ tok2,
                      float* __restrict__ tok2f)
{
  __shared__ float t_o[32][33];
  __shared__ float t_x[32][33];
  int b = blockIdx.z;
  int s0 = blockIdx.x*32, c0 = blockIdx.y*32;
  int tx = threadIdx.x, ty = threadIdx.y;
  #pragma unroll
  for (int i = 0; i < 32; i += 8) {
    int s = s0 + ty + i;
    if (s < S_) t_o[ty+i][tx] = oproj[((long)b*S_ + s)*C_ + c0 + tx];
    int s2 = s0 + tx;
    if (s2 < S_) t_x[ty+i][tx] = x[(long)b*NPB + (long)(c0+ty+i)*S_ + s2];
  }
  __syncthreads();
  #pragma unroll
  for (int i = 0; i < 32; i += 8) {
    int s = s0 + tx, c = c0 + ty + i;
    if (s < S_) xattn[(long)b*NPB + (long)c*S_ + s] = t_x[ty+i][tx] + t_o[tx][ty+i];
    int s2 = s0 + ty + i, c2 = c0 + tx;
    if (s2 < S_) {
      float v = t_x[tx][ty+i] + t_o[ty+i][tx];
      long o = ((long)b*S_ + s2)*C_ + c2;
      tok2[o] = __float2bfloat16(v);
      tok2f[o] = v;
    }
  }
}

// ---------------- residual transpose-add 2 (final output) ----------------
__global__ void tadd2(const float* __restrict__ xattn, const float* __restrict__ moe,
                      float* __restrict__ out)
{
  __shared__ float t_m[32][33];
  __shared__ float t_x[32][33];
  int b = blockIdx.z;
  int s0 = blockIdx.x*32, c0 = blockIdx.y*32;
  int tx = threadIdx.x, ty = threadIdx.y;
  #pragma unroll
  for (int i = 0; i < 32; i += 8) {
    int s = s0 + ty + i;
    if (s < S_) t_m[ty+i][tx] = moe[((long)b*S_ + s)*C_ + c0 + tx];
    int s2 = s0 + tx;
    if (s2 < S_) t_x[ty+i][tx] = xattn[(long)b*NPB + (long)(c0+ty+i)*S_ + s2];
  }
  __syncthreads();
  #pragma unroll
  for (int i = 0; i < 32; i += 8) {
    int s = s0 + tx, c = c0 + ty + i;
    if (s < S_) out[(long)b*NPB + (long)c*S_ + s] = t_x[ty+i][tx] + t_m[tx][ty+i];
  }
}

// ---------------- router: top-2 of 3 from fp32 tok2, normalized weights ----------------
__global__ void router_k(const float* __restrict__ tok2f, const float* __restrict__ rw,
                         float* __restrict__ wfull)
{
  int t = blockIdx.x*4 + (threadIdx.x >> 6);
  if (t >= MTOK) return;
  int lid = threadIdx.x & 63;
  const float* tk = tok2f + (long)t*C_;
  float a0 = 0.f, a1 = 0.f, a2 = 0.f;
  for (int i = lid; i < C_; i += 64) {
    float v = tk[i];
    a0 += v*rw[i*3+0]; a1 += v*rw[i*3+1]; a2 += v*rw[i*3+2];
  }
  #pragma unroll
  for (int o = 32; o; o >>= 1) {
    a0 += __shfl_xor(a0, o); a1 += __shfl_xor(a1, o); a2 += __shfl_xor(a2, o);
  }
  if (lid == 0) {
    float m = fmaxf(a0, fmaxf(a1, a2));
    float e0 = __expf(a0-m), e1 = __expf(a1-m), e2 = __expf(a2-m);
    int emin = 0; float pm = e0;
    if (e1 <= pm) { pm = e1; emin = 1; }
    if (e2 <= pm) { pm = e2; emin = 2; }
    float rest = e0 + e1 + e2 - pm;
    wfull[t*3+0] = (emin == 0) ? 0.f : e0/rest;
    wfull[t*3+1] = (emin == 1) ? 0.f : e1/rest;
    wfull[t*3+2] = (emin == 2) ? 0.f : e2/rest;
  }
}

// ---------------- silu(g)*u*w, in place into gate half of GU (per M-half) ----------------
__global__ void silu_k(bf16* __restrict__ GU, const float* __restrict__ wfull) {
  long tid8 = (long)blockIdx.x*256 + threadIdx.x;
  long idx = tid8 * 8;
  int m = (int)(idx / DK);
  int j = (int)(idx - (long)m*DK);
  int e = j >> 11;
  float w = wfull[m*3 + e];
  bf16* gp = GU + (long)m*GUN + j;
  const bf16* up = gp + DK;
  union U8 { uint4v u; bf16 h[8]; };
  U8 g8, u8, o8;
  g8.u = *(const uint4v*)gp;
  u8.u = *(const uint4v*)up;
  #pragma unroll
  for (int i = 0; i < 8; ++i) {
    float g = __bfloat162float(g8.h[i]);
    float u = __bfloat162float(u8.h[i]);
    float sg = g / (1.f + __expf(-g));
    o8.h[i] = __float2bfloat16(sg * u * w);
  }
  *(uint4v*)gp = o8.u;
}

// ---------------- sum 8 bf16 partials -> fp32 ----------------
__global__ void reduce8(const bf16* __restrict__ part, float* __restrict__ outp, long n) {
  long i = ((long)blockIdx.x*256 + threadIdx.x) * 8;
  if (i >= n) return;
  float acc[8] = {};
  #pragma unroll
  for (int z = 0; z < 8; ++z) {
    short8 v = *(const short8*)(part + (long)z*n + i);
    #pragma unroll
    for (int j = 0; j < 8; ++j) {
      union { short s; bf16 b; } u; u.s = v[j];
      acc[j] += __bfloat162float(u.b);
    }
  }
  #pragma unroll
  for (int j = 0; j < 8; ++j) outp[i + j] = acc[j];
}

// =============================== host ===============================
static inline void launch_gemm3(hipStream_t st,
    const bf16* Ah, const bf16* Al, long a_rs, long a_oo, long a_oi,
    const bf16* Bh, const bf16* Bl, long b_rs, long b_oo, long b_oi,
    float* Cf, bf16* Ch, bf16* Cl, long c_rs, long c_oo, long c_oi,
    int M, int N, int K, int nlim, int zdiv, int nz)
{
  dim3 g((N + 127)/128, (M + 127)/128, nz);
  gemm3_bt<<<g, 256, 0, st>>>(Ah, Al, a_rs, a_oo, a_oi, Bh, Bl, b_rs, b_oo, b_oi,
                              Cf, Ch, Cl, c_rs, c_oo, c_oi, M, N, K, nlim, zdiv);
}

extern "C" void kernel_launch(void* const* d_in, const int* in_sizes, int n_in,
                              void* d_out, int out_size, void* d_ws, size_t ws_size,
                              hipStream_t stream)
{
  const float* x      = (const float*)d_in[0];
  const float* ln_w   = (const float*)d_in[1];
  const float* ln_b   = (const float*)d_in[2];
  const float* qkv_w  = (const float*)d_in[3];
  const float* proj_w = (const float*)d_in[4];
  const float* rout_w = (const float*)d_in[5];
  const float* gate_w = (const float*)d_in[6];
  const float* up_w   = (const float*)d_in[7];
  const float* down_w = (const float*)d_in[8];
  float* out = (float*)d_out;

  char* ws = (char*)d_ws;
  size_t off = 0;
  auto alloc = [&](size_t bytes) { size_t r = off; off += (bytes + 255) & ~(size_t)255; return r; };

  // persistent (~82.6 MB)
  size_t o_stats = alloc(8*2*4);
  size_t o_part  = alloc(8*128*2*4);
  size_t o_wfull = alloc((size_t)MTOK*3*4);
  size_t o_qkvTh = alloc((size_t)C3*C_*2);
  size_t o_qkvTl = alloc((size_t)C3*C_*2);
  size_t o_prjTh = alloc((size_t)C_*C_*2);
  size_t o_prjTl = alloc((size_t)C_*C_*2);
  size_t o_guT   = alloc((size_t)GUN*C_*2);
  size_t o_downT = alloc((size_t)C_*DK*2);
  size_t o_xattn = alloc((size_t)B_*NPB*4);
  size_t o_tok2  = alloc((size_t)MTOK*C_*2);
  size_t o_tok2f = alloc((size_t)MTOK*C_*4);
  size_t big0 = off;
  // phase A (attention, ~159.9 MB)
  size_t o_tokh  = alloc((size_t)MTOK*C_*2);
  size_t o_tokl  = alloc((size_t)MTOK*C_*2);
  size_t o_qkvh  = alloc((size_t)MTOK*C3*2);
  size_t o_qkvl  = alloc((size_t)MTOK*C3*2);
  size_t o_VTh   = alloc((size_t)64*DH_*SPAD*2);
  size_t o_VTl   = alloc((size_t)64*DH_*SPAD*2);
  size_t o_aoh   = alloc((size_t)MTOK*C_*2);
  size_t o_aol   = alloc((size_t)MTOK*C_*2);
  size_t o_oproj = alloc((size_t)MTOK*C_*4);
  size_t o_scores= alloc((size_t)16*S_*SPAD*4);
  size_t endA = off;
  // phase B (MoE, M-halved, ~125.4 MB) overlaps phase A
  off = big0;
  size_t o_GUb  = alloc((size_t)MHALF*GUN*2);       // 71.7 MB
  size_t o_prt  = alloc((size_t)8*MHALF*C_*2);      // 35.8 MB (bf16 partials)
  size_t o_moe  = alloc((size_t)MTOK*C_*4);         // 17.9 MB
  size_t endB = off;
  size_t needed = endA > endB ? endA : endB;
  if (ws_size < needed) return;  // insufficient workspace: visible failure

  float* stats  = (float*)(ws + o_stats);
  float* part   = (float*)(ws + o_part);
  float* wfull  = (float*)(ws + o_wfull);
  bf16*  qkvTh  = (bf16*)(ws + o_qkvTh);
  bf16*  qkvTl  = (bf16*)(ws + o_qkvTl);
  bf16*  prjTh  = (bf16*)(ws + o_prjTh);
  bf16*  prjTl  = (bf16*)(ws + o_prjTl);
  bf16*  guT    = (bf16*)(ws + o_guT);
  bf16*  downT  = (bf16*)(ws + o_downT);
  float* xattn  = (float*)(ws + o_xattn);
  bf16*  tok2   = (bf16*)(ws + o_tok2);
  float* tok2f  = (float*)(ws + o_tok2f);
  bf16*  tokh   = (bf16*)(ws + o_tokh);
  bf16*  tokl   = (bf16*)(ws + o_tokl);
  bf16*  qkvh   = (bf16*)(ws + o_qkvh);
  bf16*  qkvl   = (bf16*)(ws + o_qkvl);
  bf16*  VTh    = (bf16*)(ws + o_VTh);
  bf16*  VTl    = (bf16*)(ws + o_VTl);
  bf16*  aoh    = (bf16*)(ws + o_aoh);
  bf16*  aol    = (bf16*)(ws + o_aol);
  float* oproj  = (float*)(ws + o_oproj);
  float* scores = (float*)(ws + o_scores);
  bf16*  GUb    = (bf16*)(ws + o_GUb);
  bf16*  prt    = (bf16*)(ws + o_prt);
  float* moe    = (float*)(ws + o_moe);

  dim3 b32(32, 8);

  // weight conversions (gate rows [0,6144), up rows [6144,12288) of guT)
  wtrans3<<<dim3(72,24,1), b32, 0, stream>>>(qkv_w,  qkvTh, qkvTl, 768, 2304, 2304, 768);
  wtrans3<<<dim3(24,24,1), b32, 0, stream>>>(proj_w, prjTh, prjTl, 768, 768,  768,  768);
  wtrans<<<dim3(64,24,3), b32, 0, stream>>>(gate_w, guT, 768, 2048, 2048, 768,
                                            (long)768*2048, (long)2048*768);
  wtrans<<<dim3(64,24,3), b32, 0, stream>>>(up_w, guT + (size_t)DK*C_, 768, 2048, 2048, 768,
                                            (long)768*2048, (long)2048*768);
  wtrans<<<dim3(24,64,3), b32, 0, stream>>>(down_w, downT, 2048, 768, 768, 6144,
                                            (long)2048*768, 2048);

  // LayerNorm -> tok hi/lo (b,s,c)
  ln_partial<<<dim3(128,8), 256, 0, stream>>>(x, part);
  ln_final<<<8, 64, 0, stream>>>(part, stats);
  ln_apply3<<<dim3(23,24,8), b32, 0, stream>>>(x, ln_w, ln_b, stats, tokh, tokl);

  // qkv = tok @ qkv_w (bf16x3, hi/lo out)
  launch_gemm3(stream, tokh, tokl, C_, 0, 0, qkvTh, qkvTl, C_, 0, 0,
               nullptr, qkvh, qkvl, C3, 0, 0, MTOK, C3, C_, C3, 1, 1);

  // V^T per (b,h), zero-padded to SPAD (hi and lo)
  vtrans<<<dim3(3,23,64), b32, 0, stream>>>(qkvh, VTh);
  vtrans<<<dim3(3,23,64), b32, 0, stream>>>(qkvl, VTl);

  // attention in 4 chunks of 16 (b,h)-pairs (2 batches each) — proven layout
  for (int c = 0; c < 4; ++c) {
    const long qoff = (long)(2*c)*S_*C3;
    launch_gemm3(stream,
        qkvh + qoff, qkvl + qoff, C3, (long)S_*C3, DH_,
        qkvh + qoff + 768, qkvl + qoff + 768, C3, (long)S_*C3, DH_,
        scores, nullptr, nullptr, SPAD, (long)8*S_*SPAD, (long)S_*SPAD,
        S_, S_, DH_, SPAD, 8, 16);
    softmax3<<<2916, 256, 0, stream>>>(scores, 16*S_);
    bf16* Pbase = (bf16*)scores;
    launch_gemm3(stream,
        Pbase, Pbase + SPAD, 2*SPAD, (long)8*S_*2*SPAD, (long)S_*2*SPAD,
        VTh + (size_t)c*16*DH_*SPAD, VTl + (size_t)c*16*DH_*SPAD, SPAD,
        (long)8*DH_*SPAD, (long)DH_*SPAD,
        nullptr, aoh + (size_t)(2*c)*S_*C_, aol + (size_t)(2*c)*S_*C_,
        C_, (long)S_*C_, DH_,
        S_, DH_, SPAD, DH_, 8, 16);
  }

  // oproj = attnout @ proj_w (fp32 out)
  launch_gemm3(stream, aoh, aol, C_, 0, 0, prjTh, prjTl, C_, 0, 0,
               oproj, nullptr, nullptr, C_, 0, 0, MTOK, C_, C_, C_, 1, 1);

  // residual + layouts
  tadd1<<<dim3(23,24,8), b32, 0, stream>>>(x, oproj, xattn, tok2, tok2f);

  // router weights (fp32 path)
  router_k<<<1458, 256, 0, stream>>>(tok2f, rout_w, wfull);

  // MoE in two M-halves: GU gemm -> silu -> down (nz=8 bf16 partials) -> reduce
  for (int half = 0; half < 2; ++half) {
    const bf16* tok2h = tok2 + (size_t)half*MHALF*C_;
    gemm8<<<dim3(GUN/256, 12, 1), 512, 0, stream>>>(
        tok2h, C_, guT, C_, nullptr, GUb, GUN, 0, MHALF, GUN, C_);
    silu_k<<<MHALF*DK/2048, 256, 0, stream>>>(GUb, wfull + (size_t)half*MHALF*3);
    gemm8<<<dim3(C_/256, 12, 8), 512, 0, stream>>>(
        GUb, GUN, downT, DK, nullptr, prt, C_, (long)MHALF*C_, MHALF, C_, DK/8);
    reduce8<<<((long)MHALF*C_/8 + 255)/256, 256, 0, stream>>>(
        prt, moe + (size_t)half*MHALF*C_, (long)MHALF*C_);
  }

  // final residual transpose-add into output
  tadd2<<<dim3(23,24,8), b32, 0, stream>>>(xattn, moe, out);
}

// Round 7
// 884.729 us; speedup vs baseline: 1.1161x; 1.0756x over previous
//
#include <hip/hip_runtime.h>
#include <hip/hip_bf16.h>

#define C_    768
#define NH_   8
#define DH_   96
#define S_    729
#define B_    8
#define MTOK  5832
#define C3    2304
#define GUN   12288
#define DK    6144
#define SPAD  736
#define NPB   559872   // C_*S_

typedef __attribute__((ext_vector_type(8))) short short8;
typedef __attribute__((ext_vector_type(4))) float f32x4;
typedef __attribute__((ext_vector_type(4))) unsigned int uint4v;
typedef __hip_bfloat16 bf16;

__device__ __forceinline__ void gld_lds16(const bf16* g, bf16* l) {
  __builtin_amdgcn_global_load_lds((const __attribute__((address_space(1))) void*)g,
                                   (__attribute__((address_space(3))) void*)l, 16, 0, 0);
}
__device__ __forceinline__ void gld_lds16c(const char* g, char* l) {
  __builtin_amdgcn_global_load_lds((const __attribute__((address_space(1))) void*)g,
                                   (__attribute__((address_space(3))) void*)l, 16, 0, 0);
}

// ================= 256x256 8-wave 4-phase deep-pipelined GEMM =================
// C = A @ Bt^T. Tile-pair unrolled: db is compile-time, staging pointers advance
// by +256B/pair, all LDS addrs are base+imm. XOR-swizzle byte^=(row&7)<<4 via
// pre-swizzled global source (linear gld_lds dest) + swizzled ds_read.
template<int DB>
__device__ __forceinline__ void tile_step(
    char* ldsc, char* ldsw,
    const int rA0, const int rA1, const int rB0, const int rB1,
    const char* pA0, const char* pA1, const char* pA2, const char* pA3,
    const char* pB0, const char* pB1, const char* pB2, const char* pB3,
    const int s1, const int s2, const bool gH1, const bool gH0, const int wmode,
    f32x4 (&acc)[8][4], short8 (&a4)[4][2], short8 (&b4)[4][2])
{
  const int DBO = DB * 65536;
  const int NBO = 65536 - DBO;
  // ---- phase 0: read A0-3 + B0-1; stage A-h1(t+1) ----
  #pragma unroll
  for (int mf = 0; mf < 4; ++mf) {
    a4[mf][0] = *(const short8*)(ldsc + DBO + rA0 + mf*2048);
    a4[mf][1] = *(const short8*)(ldsc + DBO + rA1 + mf*2048);
  }
  #pragma unroll
  for (int nf = 0; nf < 2; ++nf) {
    b4[nf][0] = *(const short8*)(ldsc + DBO + rB0 + nf*2048);
    b4[nf][1] = *(const short8*)(ldsc + DBO + rB1 + nf*2048);
  }
  if (gH1) {
    gld_lds16c(pA2 + s1, ldsw + NBO + 16384);
    gld_lds16c(pA3 + s1, ldsw + NBO + 16384 + 8192);
  }
  __builtin_amdgcn_s_barrier();
  asm volatile("s_waitcnt lgkmcnt(0)" ::: "memory");
  __builtin_amdgcn_sched_barrier(0);
  __builtin_amdgcn_s_setprio(1);
  #pragma unroll
  for (int mf = 0; mf < 4; ++mf)
    #pragma unroll
    for (int nf = 0; nf < 2; ++nf)
      #pragma unroll
      for (int j = 0; j < 2; ++j)
        acc[mf][nf] = __builtin_amdgcn_mfma_f32_16x16x32_bf16(a4[mf][j], b4[nf][j], acc[mf][nf], 0, 0, 0);
  __builtin_amdgcn_s_setprio(0);
  __builtin_amdgcn_s_barrier();
  // ---- phase 1: read B2-3; stage B-h1(t+1) ----
  #pragma unroll
  for (int nf = 2; nf < 4; ++nf) {
    b4[nf][0] = *(const short8*)(ldsc + DBO + rB0 + nf*2048);
    b4[nf][1] = *(const short8*)(ldsc + DBO + rB1 + nf*2048);
  }
  if (gH1) {
    gld_lds16c(pB2 + s1, ldsw + NBO + 32768 + 16384);
    gld_lds16c(pB3 + s1, ldsw + NBO + 32768 + 16384 + 8192);
  }
  __builtin_amdgcn_s_barrier();
  asm volatile("s_waitcnt lgkmcnt(0)" ::: "memory");
  __builtin_amdgcn_sched_barrier(0);
  __builtin_amdgcn_s_setprio(1);
  #pragma unroll
  for (int mf = 0; mf < 4; ++mf)
    #pragma unroll
    for (int nf = 2; nf < 4; ++nf)
      #pragma unroll
      for (int j = 0; j < 2; ++j)
        acc[mf][nf] = __builtin_amdgcn_mfma_f32_16x16x32_bf16(a4[mf][j], b4[nf][j], acc[mf][nf], 0, 0, 0);
  __builtin_amdgcn_s_setprio(0);
  __builtin_amdgcn_s_barrier();
  // ---- phase 2: read A4-7; stage B-h0(t+2) ----
  #pragma unroll
  for (int mi = 0; mi < 4; ++mi) {
    a4[mi][0] = *(const short8*)(ldsc + DBO + rA0 + (4+mi)*2048);
    a4[mi][1] = *(const short8*)(ldsc + DBO + rA1 + (4+mi)*2048);
  }
  if (gH0) {
    gld_lds16c(pB0 + s2, ldsw + DBO + 32768);
    gld_lds16c(pB1 + s2, ldsw + DBO + 32768 + 8192);
  }
  __builtin_amdgcn_s_barrier();
  asm volatile("s_waitcnt lgkmcnt(0)" ::: "memory");
  __builtin_amdgcn_sched_barrier(0);
  __builtin_amdgcn_s_setprio(1);
  #pragma unroll
  for (int mi = 0; mi < 4; ++mi)
    #pragma unroll
    for (int nf = 2; nf < 4; ++nf)
      #pragma unroll
      for (int j = 0; j < 2; ++j)
        acc[4+mi][nf] = __builtin_amdgcn_mfma_f32_16x16x32_bf16(a4[mi][j], b4[nf][j], acc[4+mi][nf], 0, 0, 0);
  __builtin_amdgcn_s_setprio(0);
  __builtin_amdgcn_s_barrier();
  // ---- phase 3: stage A-h0(t+2); MFMA m4-7 x n0-1 ----
  if (gH0) {
    gld_lds16c(pA0 + s2, ldsw + DBO);
    gld_lds16c(pA1 + s2, ldsw + DBO + 8192);
  }
  __builtin_amdgcn_s_barrier();
  __builtin_amdgcn_s_setprio(1);
  #pragma unroll
  for (int mi = 0; mi < 4; ++mi)
    #pragma unroll
    for (int nf = 0; nf < 2; ++nf)
      #pragma unroll
      for (int j = 0; j < 2; ++j)
        acc[4+mi][nf] = __builtin_amdgcn_mfma_f32_16x16x32_bf16(a4[mi][j], b4[nf][j], acc[4+mi][nf], 0, 0, 0);
  __builtin_amdgcn_s_setprio(0);
  if (wmode == 0)      asm volatile("s_waitcnt vmcnt(4)" ::: "memory");
  else if (wmode == 1) asm volatile("s_waitcnt vmcnt(0)" ::: "memory");
  __builtin_amdgcn_s_barrier();
}

__global__ void __launch_bounds__(512, 2)
gemm8(const bf16* __restrict__ A, long a_rs,
      const bf16* __restrict__ Bt, long b_rs,
      float* __restrict__ Cf, bf16* __restrict__ Cb,
      long c_rs, long c_zoff, int M, int N, int Ksub)
{
  __shared__ __attribute__((aligned(128))) char ldsc[131072];
  const int tid = threadIdx.x;
  const int wid = tid >> 6, lid = tid & 63;
  const int wm = wid >> 2, wn = wid & 3;           // 2 x 4 wave grid
  const int fr = lid & 15, g8 = (lid >> 4) * 8;
  const int brow = blockIdx.y * 256, bcol = blockIdx.x * 256;
  const long k0b = (long)blockIdx.z * Ksub * 2;
  const long a_rsb = a_rs * 2, b_rsb = b_rs * 2;
  const int srow = tid >> 3;
  const int scol = ((tid & 7) ^ (srow & 7)) << 4;
  const int NT = Ksub >> 6;
  char* ldsw = ldsc + wid * 1024;

  // per-thread global staging pointers (advance +256B per tile-pair)
  int ra0_ = brow + srow;        if (ra0_ > M-1) ra0_ = M-1;
  int ra1_ = brow + 64 + srow;   if (ra1_ > M-1) ra1_ = M-1;
  int ra2_ = brow + 128 + srow;  if (ra2_ > M-1) ra2_ = M-1;
  int ra3_ = brow + 192 + srow;  if (ra3_ > M-1) ra3_ = M-1;
  int rb0_ = bcol + srow;        if (rb0_ > N-1) rb0_ = N-1;
  int rb1_ = bcol + 64 + srow;   if (rb1_ > N-1) rb1_ = N-1;
  int rb2_ = bcol + 128 + srow;  if (rb2_ > N-1) rb2_ = N-1;
  int rb3_ = bcol + 192 + srow;  if (rb3_ > N-1) rb3_ = N-1;
  const char* pA0 = (const char*)A + (long)ra0_*a_rsb + k0b + scol;
  const char* pA1 = (const char*)A + (long)ra1_*a_rsb + k0b + scol;
  const char* pA2 = (const char*)A + (long)ra2_*a_rsb + k0b + scol;
  const char* pA3 = (const char*)A + (long)ra3_*a_rsb + k0b + scol;
  const char* pB0 = (const char*)Bt + (long)rb0_*b_rsb + k0b + scol;
  const char* pB1 = (const char*)Bt + (long)rb1_*b_rsb + k0b + scol;
  const char* pB2 = (const char*)Bt + (long)rb2_*b_rsb + k0b + scol;
  const char* pB3 = (const char*)Bt + (long)rb3_*b_rsb + k0b + scol;

  // LDS read bases (swizzled)
  const int swz = (fr & 7) << 4;
  const int cx0 = (g8 * 2) ^ swz;
  const int cx1 = (64 + g8 * 2) ^ swz;
  const int rA0 = (wm*128 + fr)*128 + cx0;
  const int rA1 = (wm*128 + fr)*128 + cx1;
  const int rB0 = 32768 + (wn*64 + fr)*128 + cx0;
  const int rB1 = 32768 + (wn*64 + fr)*128 + cx1;

  f32x4 acc[8][4] = {};
  short8 a4[4][2], b4[4][2];

  // prologue: T0 full (db0) + T1 h0 (db1)
  gld_lds16c(pA0, ldsw);
  gld_lds16c(pA1, ldsw + 8192);
  gld_lds16c(pA2, ldsw + 16384);
  gld_lds16c(pA3, ldsw + 16384 + 8192);
  gld_lds16c(pB0, ldsw + 32768);
  gld_lds16c(pB1, ldsw + 32768 + 8192);
  gld_lds16c(pB2, ldsw + 32768 + 16384);
  gld_lds16c(pB3, ldsw + 32768 + 16384 + 8192);
  gld_lds16c(pA0 + 128, ldsw + 65536);
  gld_lds16c(pA1 + 128, ldsw + 65536 + 8192);
  gld_lds16c(pB0 + 128, ldsw + 65536 + 32768);
  gld_lds16c(pB1 + 128, ldsw + 65536 + 32768 + 8192);
  asm volatile("s_waitcnt vmcnt(4)" ::: "memory");
  __builtin_amdgcn_s_barrier();

  for (int tp = 0; tp < NT; tp += 2) {
    const bool g2 = (tp + 2) < NT;
    tile_step<0>(ldsc, ldsw, rA0, rA1, rB0, rB1,
                 pA0, pA1, pA2, pA3, pB0, pB1, pB2, pB3,
                 128, 256, true, g2, g2 ? 0 : 1, acc, a4, b4);
    tile_step<1>(ldsc, ldsw, rA0, rA1, rB0, rB1,
                 pA0, pA1, pA2, pA3, pB0, pB1, pB2, pB3,
                 256, 384, g2, g2, g2 ? 0 : 2, acc, a4, b4);
    if (g2) {
      pA0 += 256; pA1 += 256; pA2 += 256; pA3 += 256;
      pB0 += 256; pB1 += 256; pB2 += 256; pB3 += 256;
    }
  }

  const int rg = (lid >> 4) * 4;
  #pragma unroll
  for (int mf = 0; mf < 8; ++mf) {
    #pragma unroll
    for (int nf = 0; nf < 4; ++nf) {
      const int col = bcol + wn*64 + nf*16 + fr;
      if (col < N) {
        #pragma unroll
        for (int j = 0; j < 4; ++j) {
          const int row = brow + wm*128 + mf*16 + rg + j;
          if (row < M) {
            long off = (long)blockIdx.z*c_zoff + (long)row*c_rs + col;
            if (Cb) Cb[off] = __float2bfloat16(acc[mf][nf][j]);
            else    Cf[off] = acc[mf][nf][j];
          }
        }
      }
    }
  }
}

// ---------------- bf16x3 split GEMM: A=(Ah+Al), B=(Bh+Bl), 3 products ----------------
__global__ void __launch_bounds__(256)
gemm3_bt(const bf16* __restrict__ Ah, const bf16* __restrict__ Al,
         long a_rs, long a_oo, long a_oi,
         const bf16* __restrict__ Bth, const bf16* __restrict__ Btl,
         long b_rs, long b_oo, long b_oi,
         float* __restrict__ Cf, bf16* __restrict__ Ch, bf16* __restrict__ Cl,
         long c_rs, long c_oo, long c_oi,
         int M, int N, int K, int nlim, int zdiv)
{
  __shared__ bf16 lAh[4096];
  __shared__ bf16 lAl[4096];
  __shared__ bf16 lBh[4096];
  __shared__ bf16 lBl[4096];
  const int tid = threadIdx.x;
  const int wid = tid >> 6;
  const int lid = tid & 63;
  const int z = blockIdx.z;
  const int zo = z / zdiv, zi = z - zo*zdiv;
  const long aoff = (long)zo*a_oo + (long)zi*a_oi;
  const long boff = (long)zo*b_oo + (long)zi*b_oi;
  const long cbase = (long)zo*c_oo + (long)zi*c_oi;
  const int brow = blockIdx.y * 128;
  const int bcol = blockIdx.x * 128;

  const int ch0 = tid, ch1 = tid + 256;
  int ra0 = brow + (ch0 >> 2); if (ra0 > M-1) ra0 = M-1;
  int ra1 = brow + (ch1 >> 2); if (ra1 > M-1) ra1 = M-1;
  int rb0 = bcol + (ch0 >> 2); if (rb0 > N-1) rb0 = N-1;
  int rb1 = bcol + (ch1 >> 2); if (rb1 > N-1) rb1 = N-1;
  const long ia0 = aoff + (long)ra0*a_rs + (ch0 & 3)*8;
  const long ia1 = aoff + (long)ra1*a_rs + (ch1 & 3)*8;
  const long ib0 = boff + (long)rb0*b_rs + (ch0 & 3)*8;
  const long ib1 = boff + (long)rb1*b_rs + (ch1 & 3)*8;
  bf16* dAh0 = (bf16*)((char*)lAh + wid*1024);
  bf16* dAh1 = (bf16*)((char*)lAh + 4096 + wid*1024);
  bf16* dAl0 = (bf16*)((char*)lAl + wid*1024);
  bf16* dAl1 = (bf16*)((char*)lAl + 4096 + wid*1024);
  bf16* dBh0 = (bf16*)((char*)lBh + wid*1024);
  bf16* dBh1 = (bf16*)((char*)lBh + 4096 + wid*1024);
  bf16* dBl0 = (bf16*)((char*)lBl + wid*1024);
  bf16* dBl1 = (bf16*)((char*)lBl + 4096 + wid*1024);

  f32x4 acc[4][4] = {};
  const int wm = wid >> 1, wn = wid & 1;
  const int fr = lid & 15, g8 = (lid >> 4) * 8;

  for (int kt = 0; kt < K; kt += 32) {
    __syncthreads();
    gld_lds16(Ah + ia0 + kt, dAh0);
    gld_lds16(Ah + ia1 + kt, dAh1);
    gld_lds16(Al + ia0 + kt, dAl0);
    gld_lds16(Al + ia1 + kt, dAl1);
    gld_lds16(Bth + ib0 + kt, dBh0);
    gld_lds16(Bth + ib1 + kt, dBh1);
    gld_lds16(Btl + ib0 + kt, dBl0);
    gld_lds16(Btl + ib1 + kt, dBl1);
    __syncthreads();
    short8 fah[4], fal[4], fbh[4], fbl[4];
    #pragma unroll
    for (int m = 0; m < 4; ++m) {
      int ro = (wm*64 + m*16 + fr)*32 + g8;
      fah[m] = *(const short8*)&lAh[ro];
      fal[m] = *(const short8*)&lAl[ro];
    }
    #pragma unroll
    for (int n = 0; n < 4; ++n) {
      int ro = (wn*64 + n*16 + fr)*32 + g8;
      fbh[n] = *(const short8*)&lBh[ro];
      fbl[n] = *(const short8*)&lBl[ro];
    }
    #pragma unroll
    for (int m = 0; m < 4; ++m)
      #pragma unroll
      for (int n = 0; n < 4; ++n) {
        acc[m][n] = __builtin_amdgcn_mfma_f32_16x16x32_bf16(fal[m], fbh[n], acc[m][n], 0, 0, 0);
        acc[m][n] = __builtin_amdgcn_mfma_f32_16x16x32_bf16(fah[m], fbl[n], acc[m][n], 0, 0, 0);
        acc[m][n] = __builtin_amdgcn_mfma_f32_16x16x32_bf16(fah[m], fbh[n], acc[m][n], 0, 0, 0);
      }
  }

  const int rg = (lid >> 4) * 4;
  #pragma unroll
  for (int m = 0; m < 4; ++m) {
    #pragma unroll
    for (int n = 0; n < 4; ++n) {
      const int col = bcol + wn*64 + n*16 + fr;
      if (col < nlim) {
        #pragma unroll
        for (int j = 0; j < 4; ++j) {
          const int row = brow + wm*64 + m*16 + rg + j;
          if (row < M) {
            long off = cbase + (long)row*c_rs + col;
            float v = acc[m][n][j];
            if (Cl) {
              bf16 h = __float2bfloat16(v);
              Ch[off] = h;
              Cl[off] = __float2bfloat16(v - __bfloat162float(h));
            } else if (Ch) {
              Ch[off] = __float2bfloat16(v);
            } else {
              Cf[off] = v;
            }
          }
        }
      }
    }
  }
}

// ---------------- weight transpose fp32 -> bf16 ----------------
__global__ void wtrans(const float* __restrict__ in, bf16* __restrict__ out,
                       int R, int Cc, long in_rs, long out_rs, long in_bs, long out_bs)
{
  __shared__ float tile[32][33];
  in  += (long)blockIdx.z * in_bs;
  out += (long)blockIdx.z * out_bs;
  int r0 = blockIdx.y*32, c0 = blockIdx.x*32;
  int tx = threadIdx.x, ty = threadIdx.y;
  #pragma unroll
  for (int i = 0; i < 32; i += 8) {
    int r = r0 + ty + i, c = c0 + tx;
    if (r < R && c < Cc) tile[ty+i][tx] = in[(long)r*in_rs + c];
  }
  __syncthreads();
  #pragma unroll
  for (int i = 0; i < 32; i += 8) {
    int ro = c0 + ty + i, co = r0 + tx;
    if (ro < Cc && co < R) out[(long)ro*out_rs + co] = __float2bfloat16(tile[tx][ty+i]);
  }
}

// ---------------- weight transpose fp32 -> bf16 hi/lo pair ----------------
__global__ void wtrans3(const float* __restrict__ in, bf16* __restrict__ oh, bf16* __restrict__ ol,
                        int R, int Cc, long in_rs, long out_rs)
{
  __shared__ float tile[32][33];
  int r0 = blockIdx.y*32, c0 = blockIdx.x*32;
  int tx = threadIdx.x, ty = threadIdx.y;
  #pragma unroll
  for (int i = 0; i < 32; i += 8) {
    int r = r0 + ty + i, c = c0 + tx;
    if (r < R && c < Cc) tile[ty+i][tx] = in[(long)r*in_rs + c];
  }
  __syncthreads();
  #pragma unroll
  for (int i = 0; i < 32; i += 8) {
    int ro = c0 + ty + i, co = r0 + tx;
    if (ro < Cc && co < R) {
      float v = tile[tx][ty+i];
      bf16 h = __float2bfloat16(v);
      long o = (long)ro*out_rs + co;
      oh[o] = h;
      ol[o] = __float2bfloat16(v - __bfloat162float(h));
    }
  }
}

// ---------------- LayerNorm ----------------
__global__ void ln_partial(const float* __restrict__ x, float* __restrict__ part) {
  int b = blockIdx.y, blk = blockIdx.x;
  const float* xb = x + (long)b*NPB;
  int start = blk * 4374;
  float s = 0.f, ss = 0.f;
  for (int i = start + threadIdx.x; i < start + 4374; i += 256) {
    float v = xb[i]; s += v; ss += v*v;
  }
  #pragma unroll
  for (int o = 32; o; o >>= 1) { s += __shfl_down(s, o); ss += __shfl_down(ss, o); }
  __shared__ float red[2][4];
  int wid = threadIdx.x >> 6, lid = threadIdx.x & 63;
  if (lid == 0) { red[0][wid] = s; red[1][wid] = ss; }
  __syncthreads();
  if (threadIdx.x == 0) {
    float S = 0.f, SS = 0.f;
    for (int w = 0; w < 4; ++w) { S += red[0][w]; SS += red[1][w]; }
    part[(b*128 + blk)*2] = S; part[(b*128 + blk)*2 + 1] = SS;
  }
}

__global__ void ln_final(const float* __restrict__ part, float* __restrict__ stats) {
  int b = blockIdx.x, lid = threadIdx.x;
  float s = 0.f, ss = 0.f;
  for (int i = lid; i < 128; i += 64) { s += part[(b*128+i)*2]; ss += part[(b*128+i)*2+1]; }
  #pragma unroll
  for (int o = 32; o; o >>= 1) { s += __shfl_down(s, o); ss += __shfl_down(ss, o); }
  if (lid == 0) {
    float mean = s / (float)NPB;
    float var = ss / (float)NPB - mean*mean;
    stats[b*2] = mean; stats[b*2+1] = rsqrtf(var + 1e-5f);
  }
}

__global__ void ln_apply3(const float* __restrict__ x, const float* __restrict__ lnw,
                          const float* __restrict__ lnb, const float* __restrict__ stats,
                          bf16* __restrict__ th, bf16* __restrict__ tl)
{
  __shared__ float tile[32][33];
  int b = blockIdx.z;
  int s0 = blockIdx.x*32, c0 = blockIdx.y*32;
  float mean = stats[b*2], rstd = stats[b*2+1];
  int tx = threadIdx.x, ty = threadIdx.y;
  #pragma unroll
  for (int i = 0; i < 32; i += 8) {
    int c = c0 + ty + i, s = s0 + tx;
    if (s < S_) {
      long o = (long)c*S_ + s;
      tile[ty+i][tx] = (x[(long)b*NPB + o] - mean)*rstd*lnw[o] + lnb[o];
    }
  }
  __syncthreads();
  #pragma unroll
  for (int i = 0; i < 32; i += 8) {
    int s = s0 + ty + i, c = c0 + tx;
    if (s < S_) {
      float v = tile[tx][ty+i];
      bf16 h = __float2bfloat16(v);
      long o = ((long)b*S_ + s)*C_ + c;
      th[o] = h;
      tl[o] = __float2bfloat16(v - __bfloat162float(h));
    }
  }
}

// ---------------- V transpose (bf16), zero pad t in [S_, SPAD) ----------------
__global__ void vtrans(const bf16* __restrict__ qkv, bf16* __restrict__ VT) {
  __shared__ float tile[32][33];
  int z = blockIdx.z; int bb = z >> 3, h = z & 7;
  const bf16* v = qkv + (long)bb*S_*C3 + 1536 + h*DH_;
  bf16* o = VT + (long)z*DH_*SPAD;
  int t0 = blockIdx.y*32, d0 = blockIdx.x*32;
  int tx = threadIdx.x, ty = threadIdx.y;
  #pragma unroll
  for (int i = 0; i < 32; i += 8) {
    int t = t0 + ty + i, d = d0 + tx;
    float val = 0.f;
    if (t < S_ && d < DH_) val = __bfloat162float(v[(long)t*C3 + d]);
    tile[ty+i][tx] = val;
  }
  __syncthreads();
  #pragma unroll
  for (int i = 0; i < 32; i += 8) {
    int d = d0 + ty + i, t = t0 + tx;
    if (d < DH_ && t < SPAD) o[(long)d*SPAD + t] = __float2bfloat16(tile[tx][ty+i]);
  }
}

// ---------------- softmax fp32 -> P hi/lo bf16, IN PLACE over scores row ----------------
__global__ void softmax3(float* __restrict__ scores, int nrows) {
  int row = blockIdx.x*4 + (threadIdx.x >> 6);
  if (row >= nrows) return;
  int lid = threadIdx.x & 63;
  float* src = scores + (long)row*SPAD;
  float vals[12];
  float mx = -1e30f;
  #pragma unroll
  for (int i = 0; i < 12; ++i) {
    int t = i*64 + lid;
    float v = (t < S_) ? src[t] : -1e30f;
    vals[i] = v; mx = fmaxf(mx, v);
  }
  #pragma unroll
  for (int o = 32; o; o >>= 1) mx = fmaxf(mx, __shfl_xor(mx, o));
  float sum = 0.f;
  #pragma unroll
  for (int i = 0; i < 12; ++i) { float e = __expf(vals[i] - mx); vals[i] = e; sum += e; }
  #pragma unroll
  for (int o = 32; o; o >>= 1) sum += __shfl_xor(sum, o);
  float inv = 1.f / sum;
  bf16* ph = (bf16*)src;
  bf16* pl = ph + SPAD;
  #pragma unroll
  for (int i = 0; i < 12; ++i) {
    int t = i*64 + lid;
    if (t < SPAD) {
      float p = (t < S_) ? vals[i]*inv : 0.f;
      bf16 h = __float2bfloat16(p);
      ph[t] = h;
      pl[t] = __float2bfloat16(p - __bfloat162float(h));
    }
  }
}

// ---------------- residual transpose-add 1 ----------------
__global__ void tadd1(const float* __restrict__ x, const float* __restrict__ oproj,
                      float* __restrict__ xattn, bf16* __restrict__ tok2,
                      float* __restrict__ tok2f)
{
  __shared__ float t_o[32][33];
  __shared__ float t_x[32][33];
  int b = blockIdx.z;
  int s0 = blockIdx.x*32, c0 = blockIdx.y*32;
  int tx = threadIdx.x, ty = threadIdx.y;
  #pragma unroll
  for (int i = 0; i < 32; i += 8) {
    int s = s0 + ty + i;
    if (s < S_) t_o[ty+i][tx] = oproj[((long)b*S_ + s)*C_ + c0 + tx];
    int s2 = s0 + tx;
    if (s2 < S_) t_x[ty+i][tx] = x[(long)b*NPB + (long)(c0+ty+i)*S_ + s2];
  }
  __syncthreads();
  #pragma unroll
  for (int i = 0; i < 32; i += 8) {
    int s = s0 + tx, c = c0 + ty + i;
    if (s < S_) xattn[(long)b*NPB + (long)c*S_ + s] = t_x[ty+i][tx] + t_o[tx][ty+i];
    int s2 = s0 + ty + i, c2 = c0 + tx;
    if (s2 < S_) {
      float v = t_x[tx][ty+i] + t_o[ty+i][tx];
      long o = ((long)b*S_ + s2)*C_ + c2;
      tok2[o] = __float2bfloat16(v);
      tok2f[o] = v;
    }
  }
}

// ---- residual transpose-add 2 (final output), sums 8 bf16 down-partials in place ----
// partial z for token t, col c lives at prt[t*GUN + z*768 + c] (the dead up-half of GU)
__global__ void tadd2(const float* __restrict__ xattn, const bf16* __restrict__ prt,
                      float* __restrict__ out)
{
  __shared__ float t_m[32][33];
  __shared__ float t_x[32][33];
  int b = blockIdx.z;
  int s0 = blockIdx.x*32, c0 = blockIdx.y*32;
  int tx = threadIdx.x, ty = threadIdx.y;
  #pragma unroll
  for (int i = 0; i < 32; i += 8) {
    int s = s0 + ty + i;
    if (s < S_) {
      const bf16* p = prt + ((long)b*S_ + s)*GUN + c0 + tx;
      float acc = 0.f;
      #pragma unroll
      for (int z = 0; z < 8; ++z) acc += __bfloat162float(p[z*768]);
      t_m[ty+i][tx] = acc;
    }
    int s2 = s0 + tx;
    if (s2 < S_) t_x[ty+i][tx] = xattn[(long)b*NPB + (long)(c0+ty+i)*S_ + s2];
  }
  __syncthreads();
  #pragma unroll
  for (int i = 0; i < 32; i += 8) {
    int s = s0 + tx, c = c0 + ty + i;
    if (s < S_) out[(long)b*NPB + (long)c*S_ + s] = t_x[ty+i][tx] + t_m[tx][ty+i];
  }
}

// ---------------- router: top-2 of 3 from fp32 tok2, normalized weights ----------------
__global__ void router_k(const float* __restrict__ tok2f, const float* __restrict__ rw,
                         float* __restrict__ wfull)
{
  int t = blockIdx.x*4 + (threadIdx.x >> 6);
  if (t >= MTOK) return;
  int lid = threadIdx.x & 63;
  const float* tk = tok2f + (long)t*C_;
  float a0 = 0.f, a1 = 0.f, a2 = 0.f;
  for (int i = lid; i < C_; i += 64) {
    float v = tk[i];
    a0 += v*rw[i*3+0]; a1 += v*rw[i*3+1]; a2 += v*rw[i*3+2];
  }
  #pragma unroll
  for (int o = 32; o; o >>= 1) {
    a0 += __shfl_xor(a0, o); a1 += __shfl_xor(a1, o); a2 += __shfl_xor(a2, o);
  }
  if (lid == 0) {
    float m = fmaxf(a0, fmaxf(a1, a2));
    float e0 = __expf(a0-m), e1 = __expf(a1-m), e2 = __expf(a2-m);
    int emin = 0; float pm = e0;
    if (e1 <= pm) { pm = e1; emin = 1; }
    if (e2 <= pm) { pm = e2; emin = 2; }
    float rest = e0 + e1 + e2 - pm;
    wfull[t*3+0] = (emin == 0) ? 0.f : e0/rest;
    wfull[t*3+1] = (emin == 1) ? 0.f : e1/rest;
    wfull[t*3+2] = (emin == 2) ? 0.f : e2/rest;
  }
}

// ---------------- silu(g)*u*w, in place into gate half of GU ----------------
__global__ void silu_k(bf16* __restrict__ GU, const float* __restrict__ wfull) {
  long tid8 = (long)blockIdx.x*256 + threadIdx.x;
  long idx = tid8 * 8;
  int m = (int)(idx / DK);
  int j = (int)(idx - (long)m*DK);
  int e = j >> 11;
  float w = wfull[m*3 + e];
  bf16* gp = GU + (long)m*GUN + j;
  const bf16* up = gp + DK;
  union U8 { uint4v u; bf16 h[8]; };
  U8 g8, u8, o8;
  g8.u = *(const uint4v*)gp;
  u8.u = *(const uint4v*)up;
  #pragma unroll
  for (int i = 0; i < 8; ++i) {
    float g = __bfloat162float(g8.h[i]);
    float u = __bfloat162float(u8.h[i]);
    float sg = g / (1.f + __expf(-g));
    o8.h[i] = __float2bfloat16(sg * u * w);
  }
  *(uint4v*)gp = o8.u;
}

// =============================== host ===============================
static inline void launch_gemm3(hipStream_t st,
    const bf16* Ah, const bf16* Al, long a_rs, long a_oo, long a_oi,
    const bf16* Bh, const bf16* Bl, long b_rs, long b_oo, long b_oi,
    float* Cf, bf16* Ch, bf16* Cl, long c_rs, long c_oo, long c_oi,
    int M, int N, int K, int nlim, int zdiv, int nz)
{
  dim3 g((N + 127)/128, (M + 127)/128, nz);
  gemm3_bt<<<g, 256, 0, st>>>(Ah, Al, a_rs, a_oo, a_oi, Bh, Bl, b_rs, b_oo, b_oi,
                              Cf, Ch, Cl, c_rs, c_oo, c_oi, M, N, K, nlim, zdiv);
}

extern "C" void kernel_launch(void* const* d_in, const int* in_sizes, int n_in,
                              void* d_out, int out_size, void* d_ws, size_t ws_size,
                              hipStream_t stream)
{
  const float* x      = (const float*)d_in[0];
  const float* ln_w   = (const float*)d_in[1];
  const float* ln_b   = (const float*)d_in[2];
  const float* qkv_w  = (const float*)d_in[3];
  const float* proj_w = (const float*)d_in[4];
  const float* rout_w = (const float*)d_in[5];
  const float* gate_w = (const float*)d_in[6];
  const float* up_w   = (const float*)d_in[7];
  const float* down_w = (const float*)d_in[8];
  float* out = (float*)d_out;

  char* ws = (char*)d_ws;
  size_t off = 0;
  auto alloc = [&](size_t bytes) { size_t r = off; off += (bytes + 255) & ~(size_t)255; return r; };

  // persistent (~82.6 MB)
  size_t o_stats = alloc(8*2*4);
  size_t o_part  = alloc(8*128*2*4);
  size_t o_wfull = alloc((size_t)MTOK*3*4);
  size_t o_qkvTh = alloc((size_t)C3*C_*2);
  size_t o_qkvTl = alloc((size_t)C3*C_*2);
  size_t o_prjTh = alloc((size_t)C_*C_*2);
  size_t o_prjTl = alloc((size_t)C_*C_*2);
  size_t o_guT   = alloc((size_t)GUN*C_*2);
  size_t o_downT = alloc((size_t)C_*DK*2);
  size_t o_xattn = alloc((size_t)B_*NPB*4);
  size_t o_tok2  = alloc((size_t)MTOK*C_*2);
  size_t o_tok2f = alloc((size_t)MTOK*C_*4);
  size_t big0 = off;
  // phase A (attention, ~160.1 MB)
  size_t o_tokh  = alloc((size_t)MTOK*C_*2);
  size_t o_tokl  = alloc((size_t)MTOK*C_*2);
  size_t o_qkvh  = alloc((size_t)MTOK*C3*2);
  size_t o_qkvl  = alloc((size_t)MTOK*C3*2);
  size_t o_VTh   = alloc((size_t)64*DH_*SPAD*2);
  size_t o_VTl   = alloc((size_t)64*DH_*SPAD*2);
  size_t o_aoh   = alloc((size_t)MTOK*C_*2);
  size_t o_aol   = alloc((size_t)MTOK*C_*2);
  size_t o_oproj = alloc((size_t)MTOK*C_*4);
  size_t o_scores= alloc((size_t)16*S_*SPAD*4);
  size_t endA = off;
  // phase B (MoE, full-M, ~143.3 MB) overlaps phase A; down partials live in
  // the dead up-half of GU (cols [6144,12288) per row) -> no extra memory
  off = big0;
  size_t o_GU = alloc((size_t)MTOK*GUN*2);
  size_t endB = off;
  size_t needed = endA > endB ? endA : endB;
  if (ws_size < needed) return;  // insufficient workspace: visible failure

  float* stats  = (float*)(ws + o_stats);
  float* part   = (float*)(ws + o_part);
  float* wfull  = (float*)(ws + o_wfull);
  bf16*  qkvTh  = (bf16*)(ws + o_qkvTh);
  bf16*  qkvTl  = (bf16*)(ws + o_qkvTl);
  bf16*  prjTh  = (bf16*)(ws + o_prjTh);
  bf16*  prjTl  = (bf16*)(ws + o_prjTl);
  bf16*  guT    = (bf16*)(ws + o_guT);
  bf16*  downT  = (bf16*)(ws + o_downT);
  float* xattn  = (float*)(ws + o_xattn);
  bf16*  tok2   = (bf16*)(ws + o_tok2);
  float* tok2f  = (float*)(ws + o_tok2f);
  bf16*  tokh   = (bf16*)(ws + o_tokh);
  bf16*  tokl   = (bf16*)(ws + o_tokl);
  bf16*  qkvh   = (bf16*)(ws + o_qkvh);
  bf16*  qkvl   = (bf16*)(ws + o_qkvl);
  bf16*  VTh    = (bf16*)(ws + o_VTh);
  bf16*  VTl    = (bf16*)(ws + o_VTl);
  bf16*  aoh    = (bf16*)(ws + o_aoh);
  bf16*  aol    = (bf16*)(ws + o_aol);
  float* oproj  = (float*)(ws + o_oproj);
  float* scores = (float*)(ws + o_scores);
  bf16*  GU     = (bf16*)(ws + o_GU);

  dim3 b32(32, 8);

  // weight conversions (gate rows [0,6144), up rows [6144,12288) of guT)
  wtrans3<<<dim3(72,24,1), b32, 0, stream>>>(qkv_w,  qkvTh, qkvTl, 768, 2304, 2304, 768);
  wtrans3<<<dim3(24,24,1), b32, 0, stream>>>(proj_w, prjTh, prjTl, 768, 768,  768,  768);
  wtrans<<<dim3(64,24,3), b32, 0, stream>>>(gate_w, guT, 768, 2048, 2048, 768,
                                            (long)768*2048, (long)2048*768);
  wtrans<<<dim3(64,24,3), b32, 0, stream>>>(up_w, guT + (size_t)DK*C_, 768, 2048, 2048, 768,
                                            (long)768*2048, (long)2048*768);
  wtrans<<<dim3(24,64,3), b32, 0, stream>>>(down_w, downT, 2048, 768, 768, 6144,
                                            (long)2048*768, 2048);

  // LayerNorm -> tok hi/lo (b,s,c)
  ln_partial<<<dim3(128,8), 256, 0, stream>>>(x, part);
  ln_final<<<8, 64, 0, stream>>>(part, stats);
  ln_apply3<<<dim3(23,24,8), b32, 0, stream>>>(x, ln_w, ln_b, stats, tokh, tokl);

  // qkv = tok @ qkv_w (bf16x3, hi/lo out)
  launch_gemm3(stream, tokh, tokl, C_, 0, 0, qkvTh, qkvTl, C_, 0, 0,
               nullptr, qkvh, qkvl, C3, 0, 0, MTOK, C3, C_, C3, 1, 1);

  // V^T per (b,h), zero-padded to SPAD (hi and lo)
  vtrans<<<dim3(3,23,64), b32, 0, stream>>>(qkvh, VTh);
  vtrans<<<dim3(3,23,64), b32, 0, stream>>>(qkvl, VTl);

  // attention in 4 chunks of 16 (b,h)-pairs (2 batches each) — proven layout
  for (int c = 0; c < 4; ++c) {
    const long qoff = (long)(2*c)*S_*C3;
    launch_gemm3(stream,
        qkvh + qoff, qkvl + qoff, C3, (long)S_*C3, DH_,
        qkvh + qoff + 768, qkvl + qoff + 768, C3, (long)S_*C3, DH_,
        scores, nullptr, nullptr, SPAD, (long)8*S_*SPAD, (long)S_*SPAD,
        S_, S_, DH_, SPAD, 8, 16);
    softmax3<<<2916, 256, 0, stream>>>(scores, 16*S_);
    bf16* Pbase = (bf16*)scores;
    launch_gemm3(stream,
        Pbase, Pbase + SPAD, 2*SPAD, (long)8*S_*2*SPAD, (long)S_*2*SPAD,
        VTh + (size_t)c*16*DH_*SPAD, VTl + (size_t)c*16*DH_*SPAD, SPAD,
        (long)8*DH_*SPAD, (long)DH_*SPAD,
        nullptr, aoh + (size_t)(2*c)*S_*C_, aol + (size_t)(2*c)*S_*C_,
        C_, (long)S_*C_, DH_,
        S_, DH_, SPAD, DH_, 8, 16);
  }

  // oproj = attnout @ proj_w (fp32 out)
  launch_gemm3(stream, aoh, aol, C_, 0, 0, prjTh, prjTl, C_, 0, 0,
               oproj, nullptr, nullptr, C_, 0, 0, MTOK, C_, C_, C_, 1, 1);

  // residual + layouts
  tadd1<<<dim3(23,24,8), b32, 0, stream>>>(x, oproj, xattn, tok2, tok2f);

  // router weights (fp32 path)
  router_k<<<1458, 256, 0, stream>>>(tok2f, rout_w, wfull);

  // MoE full-M: GU gemm (1104 blocks) -> silu in place -> down (nz=8 K-split,
  // bf16 partials into dead up-half of GU) -> tadd2 sums partials
  gemm8<<<dim3(GUN/256, 23, 1), 512, 0, stream>>>(
      tok2, C_, guT, C_, nullptr, GU, GUN, 0, MTOK, GUN, C_);
  silu_k<<<MTOK*DK/2048, 256, 0, stream>>>(GU, wfull);
  gemm8<<<dim3(C_/256, 23, 8), 512, 0, stream>>>(
      GU, GUN, downT, DK, nullptr, GU + DK, GUN, 768, MTOK, C_, DK/8);

  // final residual transpose-add (sums 8 partials from GU up-half) into output
  tadd2<<<dim3(23,24,8), b32, 0, stream>>>(xattn, GU + DK, out);
}

// Round 8
// 787.267 us; speedup vs baseline: 1.2543x; 1.1238x over previous
//
#include <hip/hip_runtime.h>
#include <hip/hip_bf16.h>

#define C_    768
#define NH_   8
#define DH_   96
#define S_    729
#define B_    8
#define MTOK  5832
#define C3    2304
#define GUN   12288
#define DK    6144
#define SPAD  736
#define NPB   559872   // C_*S_

typedef __attribute__((ext_vector_type(8))) short short8;
typedef __attribute__((ext_vector_type(4))) float f32x4;
typedef __attribute__((ext_vector_type(4))) unsigned int uint4v;
typedef __hip_bfloat16 bf16;

__device__ __forceinline__ void gld_lds16(const bf16* g, bf16* l) {
  __builtin_amdgcn_global_load_lds((const __attribute__((address_space(1))) void*)g,
                                   (__attribute__((address_space(3))) void*)l, 16, 0, 0);
}
__device__ __forceinline__ void gld_lds16c(const char* g, char* l) {
  __builtin_amdgcn_global_load_lds((const __attribute__((address_space(1))) void*)g,
                                   (__attribute__((address_space(3))) void*)l, 16, 0, 0);
}

// ================= 256x256 8-wave 4-phase deep-pipelined GEMM =================
template<int DB>
__device__ __forceinline__ void tile_step(
    char* ldsc, char* ldsw,
    const int rA0, const int rA1, const int rB0, const int rB1,
    const char* pA0, const char* pA1, const char* pA2, const char* pA3,
    const char* pB0, const char* pB1, const char* pB2, const char* pB3,
    const int s1, const int s2, const bool gH1, const bool gH0, const int wmode,
    f32x4 (&acc)[8][4], short8 (&a4)[4][2], short8 (&b4)[4][2])
{
  const int DBO = DB * 65536;
  const int NBO = 65536 - DBO;
  // ---- phase 0: read A0-3 + B0-1; stage A-h1(t+1) ----
  #pragma unroll
  for (int mf = 0; mf < 4; ++mf) {
    a4[mf][0] = *(const short8*)(ldsc + DBO + rA0 + mf*2048);
    a4[mf][1] = *(const short8*)(ldsc + DBO + rA1 + mf*2048);
  }
  #pragma unroll
  for (int nf = 0; nf < 2; ++nf) {
    b4[nf][0] = *(const short8*)(ldsc + DBO + rB0 + nf*2048);
    b4[nf][1] = *(const short8*)(ldsc + DBO + rB1 + nf*2048);
  }
  if (gH1) {
    gld_lds16c(pA2 + s1, ldsw + NBO + 16384);
    gld_lds16c(pA3 + s1, ldsw + NBO + 16384 + 8192);
  }
  __builtin_amdgcn_s_barrier();
  asm volatile("s_waitcnt lgkmcnt(0)" ::: "memory");
  __builtin_amdgcn_sched_barrier(0);
  __builtin_amdgcn_s_setprio(1);
  #pragma unroll
  for (int mf = 0; mf < 4; ++mf)
    #pragma unroll
    for (int nf = 0; nf < 2; ++nf)
      #pragma unroll
      for (int j = 0; j < 2; ++j)
        acc[mf][nf] = __builtin_amdgcn_mfma_f32_16x16x32_bf16(a4[mf][j], b4[nf][j], acc[mf][nf], 0, 0, 0);
  __builtin_amdgcn_s_setprio(0);
  __builtin_amdgcn_s_barrier();
  // ---- phase 1: read B2-3; stage B-h1(t+1) ----
  #pragma unroll
  for (int nf = 2; nf < 4; ++nf) {
    b4[nf][0] = *(const short8*)(ldsc + DBO + rB0 + nf*2048);
    b4[nf][1] = *(const short8*)(ldsc + DBO + rB1 + nf*2048);
  }
  if (gH1) {
    gld_lds16c(pB2 + s1, ldsw + NBO + 32768 + 16384);
    gld_lds16c(pB3 + s1, ldsw + NBO + 32768 + 16384 + 8192);
  }
  __builtin_amdgcn_s_barrier();
  asm volatile("s_waitcnt lgkmcnt(0)" ::: "memory");
  __builtin_amdgcn_sched_barrier(0);
  __builtin_amdgcn_s_setprio(1);
  #pragma unroll
  for (int mf = 0; mf < 4; ++mf)
    #pragma unroll
    for (int nf = 2; nf < 4; ++nf)
      #pragma unroll
      for (int j = 0; j < 2; ++j)
        acc[mf][nf] = __builtin_amdgcn_mfma_f32_16x16x32_bf16(a4[mf][j], b4[nf][j], acc[mf][nf], 0, 0, 0);
  __builtin_amdgcn_s_setprio(0);
  __builtin_amdgcn_s_barrier();
  // ---- phase 2: read A4-7; stage B-h0(t+2) ----
  #pragma unroll
  for (int mi = 0; mi < 4; ++mi) {
    a4[mi][0] = *(const short8*)(ldsc + DBO + rA0 + (4+mi)*2048);
    a4[mi][1] = *(const short8*)(ldsc + DBO + rA1 + (4+mi)*2048);
  }
  if (gH0) {
    gld_lds16c(pB0 + s2, ldsw + DBO + 32768);
    gld_lds16c(pB1 + s2, ldsw + DBO + 32768 + 8192);
  }
  __builtin_amdgcn_s_barrier();
  asm volatile("s_waitcnt lgkmcnt(0)" ::: "memory");
  __builtin_amdgcn_sched_barrier(0);
  __builtin_amdgcn_s_setprio(1);
  #pragma unroll
  for (int mi = 0; mi < 4; ++mi)
    #pragma unroll
    for (int nf = 2; nf < 4; ++nf)
      #pragma unroll
      for (int j = 0; j < 2; ++j)
        acc[4+mi][nf] = __builtin_amdgcn_mfma_f32_16x16x32_bf16(a4[mi][j], b4[nf][j], acc[4+mi][nf], 0, 0, 0);
  __builtin_amdgcn_s_setprio(0);
  __builtin_amdgcn_s_barrier();
  // ---- phase 3: stage A-h0(t+2); MFMA m4-7 x n0-1 ----
  if (gH0) {
    gld_lds16c(pA0 + s2, ldsw + DBO);
    gld_lds16c(pA1 + s2, ldsw + DBO + 8192);
  }
  __builtin_amdgcn_s_barrier();
  __builtin_amdgcn_s_setprio(1);
  #pragma unroll
  for (int mi = 0; mi < 4; ++mi)
    #pragma unroll
    for (int nf = 0; nf < 2; ++nf)
      #pragma unroll
      for (int j = 0; j < 2; ++j)
        acc[4+mi][nf] = __builtin_amdgcn_mfma_f32_16x16x32_bf16(a4[mi][j], b4[nf][j], acc[4+mi][nf], 0, 0, 0);
  __builtin_amdgcn_s_setprio(0);
  if (wmode == 0)      asm volatile("s_waitcnt vmcnt(4)" ::: "memory");
  else if (wmode == 1) asm volatile("s_waitcnt vmcnt(0)" ::: "memory");
  __builtin_amdgcn_s_barrier();
}

__global__ void __launch_bounds__(512, 2)
gemm8(const bf16* __restrict__ A, long a_rs,
      const bf16* __restrict__ Bt, long b_rs,
      float* __restrict__ Cf, bf16* __restrict__ Cb,
      long c_rs, long c_zoff, int M, int N, int Ksub)
{
  __shared__ __attribute__((aligned(128))) char ldsc[131072];
  const int tid = threadIdx.x;
  const int wid = tid >> 6, lid = tid & 63;
  const int wm = wid >> 2, wn = wid & 3;           // 2 x 4 wave grid
  const int fr = lid & 15, g8 = (lid >> 4) * 8;
  const int brow = blockIdx.y * 256, bcol = blockIdx.x * 256;
  const long k0b = (long)blockIdx.z * Ksub * 2;
  const long a_rsb = a_rs * 2, b_rsb = b_rs * 2;
  const int srow = tid >> 3;
  const int scol = ((tid & 7) ^ (srow & 7)) << 4;
  const int NT = Ksub >> 6;
  char* ldsw = ldsc + wid * 1024;

  int ra0_ = brow + srow;        if (ra0_ > M-1) ra0_ = M-1;
  int ra1_ = brow + 64 + srow;   if (ra1_ > M-1) ra1_ = M-1;
  int ra2_ = brow + 128 + srow;  if (ra2_ > M-1) ra2_ = M-1;
  int ra3_ = brow + 192 + srow;  if (ra3_ > M-1) ra3_ = M-1;
  int rb0_ = bcol + srow;        if (rb0_ > N-1) rb0_ = N-1;
  int rb1_ = bcol + 64 + srow;   if (rb1_ > N-1) rb1_ = N-1;
  int rb2_ = bcol + 128 + srow;  if (rb2_ > N-1) rb2_ = N-1;
  int rb3_ = bcol + 192 + srow;  if (rb3_ > N-1) rb3_ = N-1;
  const char* pA0 = (const char*)A + (long)ra0_*a_rsb + k0b + scol;
  const char* pA1 = (const char*)A + (long)ra1_*a_rsb + k0b + scol;
  const char* pA2 = (const char*)A + (long)ra2_*a_rsb + k0b + scol;
  const char* pA3 = (const char*)A + (long)ra3_*a_rsb + k0b + scol;
  const char* pB0 = (const char*)Bt + (long)rb0_*b_rsb + k0b + scol;
  const char* pB1 = (const char*)Bt + (long)rb1_*b_rsb + k0b + scol;
  const char* pB2 = (const char*)Bt + (long)rb2_*b_rsb + k0b + scol;
  const char* pB3 = (const char*)Bt + (long)rb3_*b_rsb + k0b + scol;

  const int swz = (fr & 7) << 4;
  const int cx0 = (g8 * 2) ^ swz;
  const int cx1 = (64 + g8 * 2) ^ swz;
  const int rA0 = (wm*128 + fr)*128 + cx0;
  const int rA1 = (wm*128 + fr)*128 + cx1;
  const int rB0 = 32768 + (wn*64 + fr)*128 + cx0;
  const int rB1 = 32768 + (wn*64 + fr)*128 + cx1;

  f32x4 acc[8][4] = {};
  short8 a4[4][2], b4[4][2];

  gld_lds16c(pA0, ldsw);
  gld_lds16c(pA1, ldsw + 8192);
  gld_lds16c(pA2, ldsw + 16384);
  gld_lds16c(pA3, ldsw + 16384 + 8192);
  gld_lds16c(pB0, ldsw + 32768);
  gld_lds16c(pB1, ldsw + 32768 + 8192);
  gld_lds16c(pB2, ldsw + 32768 + 16384);
  gld_lds16c(pB3, ldsw + 32768 + 16384 + 8192);
  gld_lds16c(pA0 + 128, ldsw + 65536);
  gld_lds16c(pA1 + 128, ldsw + 65536 + 8192);
  gld_lds16c(pB0 + 128, ldsw + 65536 + 32768);
  gld_lds16c(pB1 + 128, ldsw + 65536 + 32768 + 8192);
  asm volatile("s_waitcnt vmcnt(4)" ::: "memory");
  __builtin_amdgcn_s_barrier();

  for (int tp = 0; tp < NT; tp += 2) {
    const bool g2 = (tp + 2) < NT;
    tile_step<0>(ldsc, ldsw, rA0, rA1, rB0, rB1,
                 pA0, pA1, pA2, pA3, pB0, pB1, pB2, pB3,
                 128, 256, true, g2, g2 ? 0 : 1, acc, a4, b4);
    tile_step<1>(ldsc, ldsw, rA0, rA1, rB0, rB1,
                 pA0, pA1, pA2, pA3, pB0, pB1, pB2, pB3,
                 256, 384, g2, g2, g2 ? 0 : 2, acc, a4, b4);
    if (g2) {
      pA0 += 256; pA1 += 256; pA2 += 256; pA3 += 256;
      pB0 += 256; pB1 += 256; pB2 += 256; pB3 += 256;
    }
  }

  const int rg = (lid >> 4) * 4;
  #pragma unroll
  for (int mf = 0; mf < 8; ++mf) {
    #pragma unroll
    for (int nf = 0; nf < 4; ++nf) {
      const int col = bcol + wn*64 + nf*16 + fr;
      if (col < N) {
        #pragma unroll
        for (int j = 0; j < 4; ++j) {
          const int row = brow + wm*128 + mf*16 + rg + j;
          if (row < M) {
            long off = (long)blockIdx.z*c_zoff + (long)row*c_rs + col;
            if (Cb) Cb[off] = __float2bfloat16(acc[mf][nf][j]);
            else    Cf[off] = acc[mf][nf][j];
          }
        }
      }
    }
  }
}

// ---------------- bf16x3 split GEMM: A=(Ah+Al), B=(Bh+Bl), 3 products ----------------
__global__ void __launch_bounds__(256)
gemm3_bt(const bf16* __restrict__ Ah, const bf16* __restrict__ Al,
         long a_rs, long a_oo, long a_oi,
         const bf16* __restrict__ Bth, const bf16* __restrict__ Btl,
         long b_rs, long b_oo, long b_oi,
         float* __restrict__ Cf, bf16* __restrict__ Ch, bf16* __restrict__ Cl,
         long c_rs, long c_oo, long c_oi,
         int M, int N, int K, int nlim, int zdiv)
{
  __shared__ bf16 lAh[4096];
  __shared__ bf16 lAl[4096];
  __shared__ bf16 lBh[4096];
  __shared__ bf16 lBl[4096];
  const int tid = threadIdx.x;
  const int wid = tid >> 6;
  const int lid = tid & 63;
  const int z = blockIdx.z;
  const int zo = z / zdiv, zi = z - zo*zdiv;
  const long aoff = (long)zo*a_oo + (long)zi*a_oi;
  const long boff = (long)zo*b_oo + (long)zi*b_oi;
  const long cbase = (long)zo*c_oo + (long)zi*c_oi;
  const int brow = blockIdx.y * 128;
  const int bcol = blockIdx.x * 128;

  const int ch0 = tid, ch1 = tid + 256;
  int ra0 = brow + (ch0 >> 2); if (ra0 > M-1) ra0 = M-1;
  int ra1 = brow + (ch1 >> 2); if (ra1 > M-1) ra1 = M-1;
  int rb0 = bcol + (ch0 >> 2); if (rb0 > N-1) rb0 = N-1;
  int rb1 = bcol + (ch1 >> 2); if (rb1 > N-1) rb1 = N-1;
  const long ia0 = aoff + (long)ra0*a_rs + (ch0 & 3)*8;
  const long ia1 = aoff + (long)ra1*a_rs + (ch1 & 3)*8;
  const long ib0 = boff + (long)rb0*b_rs + (ch0 & 3)*8;
  const long ib1 = boff + (long)rb1*b_rs + (ch1 & 3)*8;
  bf16* dAh0 = (bf16*)((char*)lAh + wid*1024);
  bf16* dAh1 = (bf16*)((char*)lAh + 4096 + wid*1024);
  bf16* dAl0 = (bf16*)((char*)lAl + wid*1024);
  bf16* dAl1 = (bf16*)((char*)lAl + 4096 + wid*1024);
  bf16* dBh0 = (bf16*)((char*)lBh + wid*1024);
  bf16* dBh1 = (bf16*)((char*)lBh + 4096 + wid*1024);
  bf16* dBl0 = (bf16*)((char*)lBl + wid*1024);
  bf16* dBl1 = (bf16*)((char*)lBl + 4096 + wid*1024);

  f32x4 acc[4][4] = {};
  const int wm = wid >> 1, wn = wid & 1;
  const int fr = lid & 15, g8 = (lid >> 4) * 8;

  for (int kt = 0; kt < K; kt += 32) {
    __syncthreads();
    gld_lds16(Ah + ia0 + kt, dAh0);
    gld_lds16(Ah + ia1 + kt, dAh1);
    gld_lds16(Al + ia0 + kt, dAl0);
    gld_lds16(Al + ia1 + kt, dAl1);
    gld_lds16(Bth + ib0 + kt, dBh0);
    gld_lds16(Bth + ib1 + kt, dBh1);
    gld_lds16(Btl + ib0 + kt, dBl0);
    gld_lds16(Btl + ib1 + kt, dBl1);
    __syncthreads();
    short8 fah[4], fal[4], fbh[4], fbl[4];
    #pragma unroll
    for (int m = 0; m < 4; ++m) {
      int ro = (wm*64 + m*16 + fr)*32 + g8;
      fah[m] = *(const short8*)&lAh[ro];
      fal[m] = *(const short8*)&lAl[ro];
    }
    #pragma unroll
    for (int n = 0; n < 4; ++n) {
      int ro = (wn*64 + n*16 + fr)*32 + g8;
      fbh[n] = *(const short8*)&lBh[ro];
      fbl[n] = *(const short8*)&lBl[ro];
    }
    #pragma unroll
    for (int m = 0; m < 4; ++m)
      #pragma unroll
      for (int n = 0; n < 4; ++n) {
        acc[m][n] = __builtin_amdgcn_mfma_f32_16x16x32_bf16(fal[m], fbh[n], acc[m][n], 0, 0, 0);
        acc[m][n] = __builtin_amdgcn_mfma_f32_16x16x32_bf16(fah[m], fbl[n], acc[m][n], 0, 0, 0);
        acc[m][n] = __builtin_amdgcn_mfma_f32_16x16x32_bf16(fah[m], fbh[n], acc[m][n], 0, 0, 0);
      }
  }

  const int rg = (lid >> 4) * 4;
  #pragma unroll
  for (int m = 0; m < 4; ++m) {
    #pragma unroll
    for (int n = 0; n < 4; ++n) {
      const int col = bcol + wn*64 + n*16 + fr;
      if (col < nlim) {
        #pragma unroll
        for (int j = 0; j < 4; ++j) {
          const int row = brow + wm*64 + m*16 + rg + j;
          if (row < M) {
            long off = cbase + (long)row*c_rs + col;
            float v = acc[m][n][j];
            if (Cl) {
              bf16 h = __float2bfloat16(v);
              Ch[off] = h;
              Cl[off] = __float2bfloat16(v - __bfloat162float(h));
            } else if (Ch) {
              Ch[off] = __float2bfloat16(v);
            } else {
              Cf[off] = v;
            }
          }
        }
      }
    }
  }
}

// ---------------- weight transpose fp32 -> bf16 ----------------
__global__ void wtrans(const float* __restrict__ in, bf16* __restrict__ out,
                       int R, int Cc, long in_rs, long out_rs, long in_bs, long out_bs)
{
  __shared__ float tile[32][33];
  in  += (long)blockIdx.z * in_bs;
  out += (long)blockIdx.z * out_bs;
  int r0 = blockIdx.y*32, c0 = blockIdx.x*32;
  int tx = threadIdx.x, ty = threadIdx.y;
  #pragma unroll
  for (int i = 0; i < 32; i += 8) {
    int r = r0 + ty + i, c = c0 + tx;
    if (r < R && c < Cc) tile[ty+i][tx] = in[(long)r*in_rs + c];
  }
  __syncthreads();
  #pragma unroll
  for (int i = 0; i < 32; i += 8) {
    int ro = c0 + ty + i, co = r0 + tx;
    if (ro < Cc && co < R) out[(long)ro*out_rs + co] = __float2bfloat16(tile[tx][ty+i]);
  }
}

// ---------------- weight transpose fp32 -> bf16 hi/lo pair ----------------
__global__ void wtrans3(const float* __restrict__ in, bf16* __restrict__ oh, bf16* __restrict__ ol,
                        int R, int Cc, long in_rs, long out_rs)
{
  __shared__ float tile[32][33];
  int r0 = blockIdx.y*32, c0 = blockIdx.x*32;
  int tx = threadIdx.x, ty = threadIdx.y;
  #pragma unroll
  for (int i = 0; i < 32; i += 8) {
    int r = r0 + ty + i, c = c0 + tx;
    if (r < R && c < Cc) tile[ty+i][tx] = in[(long)r*in_rs + c];
  }
  __syncthreads();
  #pragma unroll
  for (int i = 0; i < 32; i += 8) {
    int ro = c0 + ty + i, co = r0 + tx;
    if (ro < Cc && co < R) {
      float v = tile[tx][ty+i];
      bf16 h = __float2bfloat16(v);
      long o = (long)ro*out_rs + co;
      oh[o] = h;
      ol[o] = __float2bfloat16(v - __bfloat162float(h));
    }
  }
}

// ---------------- LayerNorm ----------------
__global__ void ln_partial(const float* __restrict__ x, float* __restrict__ part) {
  int b = blockIdx.y, blk = blockIdx.x;
  const float* xb = x + (long)b*NPB;
  int start = blk * 4374;
  float s = 0.f, ss = 0.f;
  for (int i = start + threadIdx.x; i < start + 4374; i += 256) {
    float v = xb[i]; s += v; ss += v*v;
  }
  #pragma unroll
  for (int o = 32; o; o >>= 1) { s += __shfl_down(s, o); ss += __shfl_down(ss, o); }
  __shared__ float red[2][4];
  int wid = threadIdx.x >> 6, lid = threadIdx.x & 63;
  if (lid == 0) { red[0][wid] = s; red[1][wid] = ss; }
  __syncthreads();
  if (threadIdx.x == 0) {
    float S = 0.f, SS = 0.f;
    for (int w = 0; w < 4; ++w) { S += red[0][w]; SS += red[1][w]; }
    part[(b*128 + blk)*2] = S; part[(b*128 + blk)*2 + 1] = SS;
  }
}

__global__ void ln_final(const float* __restrict__ part, float* __restrict__ stats) {
  int b = blockIdx.x, lid = threadIdx.x;
  float s = 0.f, ss = 0.f;
  for (int i = lid; i < 128; i += 64) { s += part[(b*128+i)*2]; ss += part[(b*128+i)*2+1]; }
  #pragma unroll
  for (int o = 32; o; o >>= 1) { s += __shfl_down(s, o); ss += __shfl_down(ss, o); }
  if (lid == 0) {
    float mean = s / (float)NPB;
    float var = ss / (float)NPB - mean*mean;
    stats[b*2] = mean; stats[b*2+1] = rsqrtf(var + 1e-5f);
  }
}

__global__ void ln_apply3(const float* __restrict__ x, const float* __restrict__ lnw,
                          const float* __restrict__ lnb, const float* __restrict__ stats,
                          bf16* __restrict__ th, bf16* __restrict__ tl)
{
  __shared__ float tile[32][33];
  int b = blockIdx.z;
  int s0 = blockIdx.x*32, c0 = blockIdx.y*32;
  float mean = stats[b*2], rstd = stats[b*2+1];
  int tx = threadIdx.x, ty = threadIdx.y;
  #pragma unroll
  for (int i = 0; i < 32; i += 8) {
    int c = c0 + ty + i, s = s0 + tx;
    if (s < S_) {
      long o = (long)c*S_ + s;
      tile[ty+i][tx] = (x[(long)b*NPB + o] - mean)*rstd*lnw[o] + lnb[o];
    }
  }
  __syncthreads();
  #pragma unroll
  for (int i = 0; i < 32; i += 8) {
    int s = s0 + ty + i, c = c0 + tx;
    if (s < S_) {
      float v = tile[tx][ty+i];
      bf16 h = __float2bfloat16(v);
      long o = ((long)b*S_ + s)*C_ + c;
      th[o] = h;
      tl[o] = __float2bfloat16(v - __bfloat162float(h));
    }
  }
}

// ---------------- V transpose (bf16), zero pad t in [S_, SPAD) ----------------
__global__ void vtrans(const bf16* __restrict__ qkv, bf16* __restrict__ VT) {
  __shared__ float tile[32][33];
  int z = blockIdx.z; int bb = z >> 3, h = z & 7;
  const bf16* v = qkv + (long)bb*S_*C3 + 1536 + h*DH_;
  bf16* o = VT + (long)z*DH_*SPAD;
  int t0 = blockIdx.y*32, d0 = blockIdx.x*32;
  int tx = threadIdx.x, ty = threadIdx.y;
  #pragma unroll
  for (int i = 0; i < 32; i += 8) {
    int t = t0 + ty + i, d = d0 + tx;
    float val = 0.f;
    if (t < S_ && d < DH_) val = __bfloat162float(v[(long)t*C3 + d]);
    tile[ty+i][tx] = val;
  }
  __syncthreads();
  #pragma unroll
  for (int i = 0; i < 32; i += 8) {
    int d = d0 + ty + i, t = t0 + tx;
    if (d < DH_ && t < SPAD) o[(long)d*SPAD + t] = __float2bfloat16(tile[tx][ty+i]);
  }
}

// -------- softmax over bf16 hi/lo score rows, IN PLACE (row stride 2*SPAD) --------
__global__ void softmax3p(bf16* __restrict__ scores, int nrows) {
  int row = blockIdx.x*4 + (threadIdx.x >> 6);
  if (row >= nrows) return;
  int lid = threadIdx.x & 63;
  bf16* ph = scores + (long)row*2*SPAD;
  bf16* pl = ph + SPAD;
  float vals[12];
  float mx = -1e30f;
  #pragma unroll
  for (int i = 0; i < 12; ++i) {
    int t = i*64 + lid;
    float v = -1e30f;
    if (t < S_) v = __bfloat162float(ph[t]) + __bfloat162float(pl[t]);
    vals[i] = v; mx = fmaxf(mx, v);
  }
  #pragma unroll
  for (int o = 32; o; o >>= 1) mx = fmaxf(mx, __shfl_xor(mx, o));
  float sum = 0.f;
  #pragma unroll
  for (int i = 0; i < 12; ++i) { float e = __expf(vals[i] - mx); vals[i] = e; sum += e; }
  #pragma unroll
  for (int o = 32; o; o >>= 1) sum += __shfl_xor(sum, o);
  float inv = 1.f / sum;
  #pragma unroll
  for (int i = 0; i < 12; ++i) {
    int t = i*64 + lid;
    if (t < SPAD) {
      float p = (t < S_) ? vals[i]*inv : 0.f;
      bf16 h = __float2bfloat16(p);
      ph[t] = h;
      pl[t] = __float2bfloat16(p - __bfloat162float(h));
    }
  }
}

// ---------------- residual transpose-add 1 ----------------
__global__ void tadd1(const float* __restrict__ x, const float* __restrict__ oproj,
                      float* __restrict__ xattn, bf16* __restrict__ tok2,
                      float* __restrict__ tok2f)
{
  __shared__ float t_o[32][33];
  __shared__ float t_x[32][33];
  int b = blockIdx.z;
  int s0 = blockIdx.x*32, c0 = blockIdx.y*32;
  int tx = threadIdx.x, ty = threadIdx.y;
  #pragma unroll
  for (int i = 0; i < 32; i += 8) {
    int s = s0 + ty + i;
    if (s < S_) t_o[ty+i][tx] = oproj[((long)b*S_ + s)*C_ + c0 + tx];
    int s2 = s0 + tx;
    if (s2 < S_) t_x[ty+i][tx] = x[(long)b*NPB + (long)(c0+ty+i)*S_ + s2];
  }
  __syncthreads();
  #pragma unroll
  for (int i = 0; i < 32; i += 8) {
    int s = s0 + tx, c = c0 + ty + i;
    if (s < S_) xattn[(long)b*NPB + (long)c*S_ + s] = t_x[ty+i][tx] + t_o[tx][ty+i];
    int s2 = s0 + ty + i, c2 = c0 + tx;
    if (s2 < S_) {
      float v = t_x[tx][ty+i] + t_o[ty+i][tx];
      long o = ((long)b*S_ + s2)*C_ + c2;
      tok2[o] = __float2bfloat16(v);
      tok2f[o] = v;
    }
  }
}

// ---- residual transpose-add 2 (final output), sums 8 bf16 down-partials in place ----
__global__ void tadd2(const float* __restrict__ xattn, const bf16* __restrict__ prt,
                      float* __restrict__ out)
{
  __shared__ float t_m[32][33];
  __shared__ float t_x[32][33];
  int b = blockIdx.z;
  int s0 = blockIdx.x*32, c0 = blockIdx.y*32;
  int tx = threadIdx.x, ty = threadIdx.y;
  #pragma unroll
  for (int i = 0; i < 32; i += 8) {
    int s = s0 + ty + i;
    if (s < S_) {
      const bf16* p = prt + ((long)b*S_ + s)*GUN + c0 + tx;
      float acc = 0.f;
      #pragma unroll
      for (int z = 0; z < 8; ++z) acc += __bfloat162float(p[z*768]);
      t_m[ty+i][tx] = acc;
    }
    int s2 = s0 + tx;
    if (s2 < S_) t_x[ty+i][tx] = xattn[(long)b*NPB + (long)(c0+ty+i)*S_ + s2];
  }
  __syncthreads();
  #pragma unroll
  for (int i = 0; i < 32; i += 8) {
    int s = s0 + tx, c = c0 + ty + i;
    if (s < S_) out[(long)b*NPB + (long)c*S_ + s] = t_x[ty+i][tx] + t_m[tx][ty+i];
  }
}

// ---------------- router: top-2 of 3 from fp32 tok2, normalized weights ----------------
__global__ void router_k(const float* __restrict__ tok2f, const float* __restrict__ rw,
                         float* __restrict__ wfull)
{
  int t = blockIdx.x*4 + (threadIdx.x >> 6);
  if (t >= MTOK) return;
  int lid = threadIdx.x & 63;
  const float* tk = tok2f + (long)t*C_;
  float a0 = 0.f, a1 = 0.f, a2 = 0.f;
  for (int i = lid; i < C_; i += 64) {
    float v = tk[i];
    a0 += v*rw[i*3+0]; a1 += v*rw[i*3+1]; a2 += v*rw[i*3+2];
  }
  #pragma unroll
  for (int o = 32; o; o >>= 1) {
    a0 += __shfl_xor(a0, o); a1 += __shfl_xor(a1, o); a2 += __shfl_xor(a2, o);
  }
  if (lid == 0) {
    float m = fmaxf(a0, fmaxf(a1, a2));
    float e0 = __expf(a0-m), e1 = __expf(a1-m), e2 = __expf(a2-m);
    int emin = 0; float pm = e0;
    if (e1 <= pm) { pm = e1; emin = 1; }
    if (e2 <= pm) { pm = e2; emin = 2; }
    float rest = e0 + e1 + e2 - pm;
    wfull[t*3+0] = (emin == 0) ? 0.f : e0/rest;
    wfull[t*3+1] = (emin == 1) ? 0.f : e1/rest;
    wfull[t*3+2] = (emin == 2) ? 0.f : e2/rest;
  }
}

// ---------------- silu(g)*u*w, in place into gate half of GU ----------------
__global__ void silu_k(bf16* __restrict__ GU, const float* __restrict__ wfull) {
  long tid8 = (long)blockIdx.x*256 + threadIdx.x;
  long idx = tid8 * 8;
  int m = (int)(idx / DK);
  int j = (int)(idx - (long)m*DK);
  int e = j >> 11;
  float w = wfull[m*3 + e];
  bf16* gp = GU + (long)m*GUN + j;
  const bf16* up = gp + DK;
  union U8 { uint4v u; bf16 h[8]; };
  U8 g8, u8, o8;
  g8.u = *(const uint4v*)gp;
  u8.u = *(const uint4v*)up;
  #pragma unroll
  for (int i = 0; i < 8; ++i) {
    float g = __bfloat162float(g8.h[i]);
    float u = __bfloat162float(u8.h[i]);
    float sg = g / (1.f + __expf(-g));
    o8.h[i] = __float2bfloat16(sg * u * w);
  }
  *(uint4v*)gp = o8.u;
}

// =============================== host ===============================
static inline void launch_gemm3(hipStream_t st,
    const bf16* Ah, const bf16* Al, long a_rs, long a_oo, long a_oi,
    const bf16* Bh, const bf16* Bl, long b_rs, long b_oo, long b_oi,
    float* Cf, bf16* Ch, bf16* Cl, long c_rs, long c_oo, long c_oi,
    int M, int N, int K, int nlim, int zdiv, int nz)
{
  dim3 g((N + 127)/128, (M + 127)/128, nz);
  gemm3_bt<<<g, 256, 0, st>>>(Ah, Al, a_rs, a_oo, a_oi, Bh, Bl, b_rs, b_oo, b_oi,
                              Cf, Ch, Cl, c_rs, c_oo, c_oi, M, N, K, nlim, zdiv);
}

extern "C" void kernel_launch(void* const* d_in, const int* in_sizes, int n_in,
                              void* d_out, int out_size, void* d_ws, size_t ws_size,
                              hipStream_t stream)
{
  const float* x      = (const float*)d_in[0];
  const float* ln_w   = (const float*)d_in[1];
  const float* ln_b   = (const float*)d_in[2];
  const float* qkv_w  = (const float*)d_in[3];
  const float* proj_w = (const float*)d_in[4];
  const float* rout_w = (const float*)d_in[5];
  const float* gate_w = (const float*)d_in[6];
  const float* up_w   = (const float*)d_in[7];
  const float* down_w = (const float*)d_in[8];
  float* out = (float*)d_out;

  char* ws = (char*)d_ws;
  size_t off = 0;
  auto alloc = [&](size_t bytes) { size_t r = off; off += (bytes + 255) & ~(size_t)255; return r; };

  // persistent (~82.6 MB)
  size_t o_stats = alloc(8*2*4);
  size_t o_part  = alloc(8*128*2*4);
  size_t o_wfull = alloc((size_t)MTOK*3*4);
  size_t o_qkvTh = alloc((size_t)C3*C_*2);
  size_t o_qkvTl = alloc((size_t)C3*C_*2);
  size_t o_prjTh = alloc((size_t)C_*C_*2);
  size_t o_prjTl = alloc((size_t)C_*C_*2);
  size_t o_guT   = alloc((size_t)GUN*C_*2);
  size_t o_downT = alloc((size_t)C_*DK*2);
  size_t o_xattn = alloc((size_t)B_*NPB*4);
  size_t o_tok2  = alloc((size_t)MTOK*C_*2);
  size_t o_tok2f = alloc((size_t)MTOK*C_*4);
  size_t big0 = off;
  // phase A (attention): fixed buffers + one union region (tok | scores | oproj)
  size_t o_qkvh  = alloc((size_t)MTOK*C3*2);
  size_t o_qkvl  = alloc((size_t)MTOK*C3*2);
  size_t o_VTh   = alloc((size_t)64*DH_*SPAD*2);
  size_t o_VTl   = alloc((size_t)64*DH_*SPAD*2);
  size_t o_aoh   = alloc((size_t)MTOK*C_*2);
  size_t o_aol   = alloc((size_t)MTOK*C_*2);
  size_t o_union = alloc((size_t)32*S_*SPAD*4);   // 68.7 MB: scores(32 pairs) | tok hi+lo | oproj
  size_t endA = off;
  // phase B (MoE, full-M) overlaps phase A; down partials use dead up-half of GU
  off = big0;
  size_t o_GU = alloc((size_t)MTOK*GUN*2);
  size_t endB = off;
  size_t needed = endA > endB ? endA : endB;
  if (ws_size < needed) return;  // insufficient workspace: visible failure

  float* stats  = (float*)(ws + o_stats);
  float* part   = (float*)(ws + o_part);
  float* wfull  = (float*)(ws + o_wfull);
  bf16*  qkvTh  = (bf16*)(ws + o_qkvTh);
  bf16*  qkvTl  = (bf16*)(ws + o_qkvTl);
  bf16*  prjTh  = (bf16*)(ws + o_prjTh);
  bf16*  prjTl  = (bf16*)(ws + o_prjTl);
  bf16*  guT    = (bf16*)(ws + o_guT);
  bf16*  downT  = (bf16*)(ws + o_downT);
  float* xattn  = (float*)(ws + o_xattn);
  bf16*  tok2   = (bf16*)(ws + o_tok2);
  float* tok2f  = (float*)(ws + o_tok2f);
  bf16*  qkvh   = (bf16*)(ws + o_qkvh);
  bf16*  qkvl   = (bf16*)(ws + o_qkvl);
  bf16*  VTh    = (bf16*)(ws + o_VTh);
  bf16*  VTl    = (bf16*)(ws + o_VTl);
  bf16*  aoh    = (bf16*)(ws + o_aoh);
  bf16*  aol    = (bf16*)(ws + o_aol);
  // union region occupants (live ranges are disjoint in stream order):
  bf16*  tokh   = (bf16*)(ws + o_union);                          // dead after qkv gemm
  bf16*  tokl   = (bf16*)(ws + o_union + (size_t)MTOK*C_*2);
  bf16*  Pbase  = (bf16*)(ws + o_union);                          // scores/P hi-lo pairs
  float* oproj  = (float*)(ws + o_union);                         // written after PV done
  bf16*  GU     = (bf16*)(ws + o_GU);

  dim3 b32(32, 8);

  // weight conversions (gate rows [0,6144), up rows [6144,12288) of guT)
  wtrans3<<<dim3(72,24,1), b32, 0, stream>>>(qkv_w,  qkvTh, qkvTl, 768, 2304, 2304, 768);
  wtrans3<<<dim3(24,24,1), b32, 0, stream>>>(proj_w, prjTh, prjTl, 768, 768,  768,  768);
  wtrans<<<dim3(64,24,3), b32, 0, stream>>>(gate_w, guT, 768, 2048, 2048, 768,
                                            (long)768*2048, (long)2048*768);
  wtrans<<<dim3(64,24,3), b32, 0, stream>>>(up_w, guT + (size_t)DK*C_, 768, 2048, 2048, 768,
                                            (long)768*2048, (long)2048*768);
  wtrans<<<dim3(24,64,3), b32, 0, stream>>>(down_w, downT, 2048, 768, 768, 6144,
                                            (long)2048*768, 2048);

  // LayerNorm -> tok hi/lo (b,s,c)
  ln_partial<<<dim3(128,8), 256, 0, stream>>>(x, part);
  ln_final<<<8, 64, 0, stream>>>(part, stats);
  ln_apply3<<<dim3(23,24,8), b32, 0, stream>>>(x, ln_w, ln_b, stats, tokh, tokl);

  // qkv = tok @ qkv_w (bf16x3, hi/lo out); tok region dead afterwards
  launch_gemm3(stream, tokh, tokl, C_, 0, 0, qkvTh, qkvTl, C_, 0, 0,
               nullptr, qkvh, qkvl, C3, 0, 0, MTOK, C3, C_, C3, 1, 1);

  // V^T per (b,h), zero-padded to SPAD (hi and lo)
  vtrans<<<dim3(3,23,64), b32, 0, stream>>>(qkvh, VTh);
  vtrans<<<dim3(3,23,64), b32, 0, stream>>>(qkvl, VTl);

  // attention in 2 chunks of 32 (b,h)-pairs (4 batches each)
  for (int c = 0; c < 2; ++c) {
    const long qoff = (long)(4*c)*S_*C3;
    // QK^T -> bf16 hi/lo pairs directly (row: [hi x736][lo x736])
    launch_gemm3(stream,
        qkvh + qoff, qkvl + qoff, C3, (long)S_*C3, DH_,
        qkvh + qoff + 768, qkvl + qoff + 768, C3, (long)S_*C3, DH_,
        nullptr, Pbase, Pbase + SPAD, 2*SPAD, (long)8*S_*2*SPAD, (long)S_*2*SPAD,
        S_, S_, DH_, SPAD, 8, 32);
    softmax3p<<<5832, 256, 0, stream>>>(Pbase, 32*S_);
    launch_gemm3(stream,
        Pbase, Pbase + SPAD, 2*SPAD, (long)8*S_*2*SPAD, (long)S_*2*SPAD,
        VTh + (size_t)c*32*DH_*SPAD, VTl + (size_t)c*32*DH_*SPAD, SPAD,
        (long)8*DH_*SPAD, (long)DH_*SPAD,
        nullptr, aoh + (size_t)(4*c)*S_*C_, aol + (size_t)(4*c)*S_*C_,
        C_, (long)S_*C_, DH_,
        S_, DH_, SPAD, DH_, 8, 32);
  }

  // oproj = attnout @ proj_w (fp32 out, into union region — P dead now)
  launch_gemm3(stream, aoh, aol, C_, 0, 0, prjTh, prjTl, C_, 0, 0,
               oproj, nullptr, nullptr, C_, 0, 0, MTOK, C_, C_, C_, 1, 1);

  // residual + layouts
  tadd1<<<dim3(23,24,8), b32, 0, stream>>>(x, oproj, xattn, tok2, tok2f);

  // router weights (fp32 path)
  router_k<<<1458, 256, 0, stream>>>(tok2f, rout_w, wfull);

  // MoE full-M: GU gemm -> silu in place -> down (nz=8 K-split, bf16 partials
  // into dead up-half of GU) -> tadd2 sums partials
  gemm8<<<dim3(GUN/256, 23, 1), 512, 0, stream>>>(
      tok2, C_, guT, C_, nullptr, GU, GUN, 0, MTOK, GUN, C_);
  silu_k<<<MTOK*DK/2048, 256, 0, stream>>>(GU, wfull);
  gemm8<<<dim3(C_/256, 23, 8), 512, 0, stream>>>(
      GU, GUN, downT, DK, nullptr, GU + DK, GUN, 768, MTOK, C_, DK/8);

  // final residual transpose-add (sums 8 partials from GU up-half) into output
  tadd2<<<dim3(23,24,8), b32, 0, stream>>>(xattn, GU + DK, out);
}

// Round 9
// 786.017 us; speedup vs baseline: 1.2563x; 1.0016x over previous
//
#include <hip/hip_runtime.h>
#include <hip/hip_bf16.h>

#define C_    768
#define NH_   8
#define DH_   96
#define S_    729
#define B_    8
#define MTOK  5832
#define C3    2304
#define GUN   12288
#define DK    6144
#define SPAD  736
#define NPB   559872   // C_*S_

typedef __attribute__((ext_vector_type(8))) short short8;
typedef __attribute__((ext_vector_type(4))) float f32x4;
typedef __attribute__((ext_vector_type(4))) unsigned int uint4v;
typedef __hip_bfloat16 bf16;

__device__ __forceinline__ void gld_lds16(const bf16* g, bf16* l) {
  __builtin_amdgcn_global_load_lds((const __attribute__((address_space(1))) void*)g,
                                   (__attribute__((address_space(3))) void*)l, 16, 0, 0);
}
__device__ __forceinline__ void gld_lds16c(const char* g, char* l) {
  __builtin_amdgcn_global_load_lds((const __attribute__((address_space(1))) void*)g,
                                   (__attribute__((address_space(3))) void*)l, 16, 0, 0);
}

// ================= 256x256 8-wave 4-phase deep-pipelined GEMM =================
template<int DB>
__device__ __forceinline__ void tile_step(
    char* ldsc, char* ldsw,
    const int rA0, const int rA1, const int rB0, const int rB1,
    const char* pA0, const char* pA1, const char* pA2, const char* pA3,
    const char* pB0, const char* pB1, const char* pB2, const char* pB3,
    const int s1, const int s2, const bool gH1, const bool gH0, const int wmode,
    f32x4 (&acc)[8][4], short8 (&a4)[4][2], short8 (&b4)[4][2])
{
  const int DBO = DB * 65536;
  const int NBO = 65536 - DBO;
  // ---- phase 0: read A0-3 + B0-1; stage A-h1(t+1) ----
  #pragma unroll
  for (int mf = 0; mf < 4; ++mf) {
    a4[mf][0] = *(const short8*)(ldsc + DBO + rA0 + mf*2048);
    a4[mf][1] = *(const short8*)(ldsc + DBO + rA1 + mf*2048);
  }
  #pragma unroll
  for (int nf = 0; nf < 2; ++nf) {
    b4[nf][0] = *(const short8*)(ldsc + DBO + rB0 + nf*2048);
    b4[nf][1] = *(const short8*)(ldsc + DBO + rB1 + nf*2048);
  }
  if (gH1) {
    gld_lds16c(pA2 + s1, ldsw + NBO + 16384);
    gld_lds16c(pA3 + s1, ldsw + NBO + 16384 + 8192);
  }
  __builtin_amdgcn_s_barrier();
  asm volatile("s_waitcnt lgkmcnt(0)" ::: "memory");
  __builtin_amdgcn_sched_barrier(0);
  __builtin_amdgcn_s_setprio(1);
  #pragma unroll
  for (int mf = 0; mf < 4; ++mf)
    #pragma unroll
    for (int nf = 0; nf < 2; ++nf)
      #pragma unroll
      for (int j = 0; j < 2; ++j)
        acc[mf][nf] = __builtin_amdgcn_mfma_f32_16x16x32_bf16(a4[mf][j], b4[nf][j], acc[mf][nf], 0, 0, 0);
  __builtin_amdgcn_s_setprio(0);
  __builtin_amdgcn_s_barrier();
  // ---- phase 1: read B2-3; stage B-h1(t+1) ----
  #pragma unroll
  for (int nf = 2; nf < 4; ++nf) {
    b4[nf][0] = *(const short8*)(ldsc + DBO + rB0 + nf*2048);
    b4[nf][1] = *(const short8*)(ldsc + DBO + rB1 + nf*2048);
  }
  if (gH1) {
    gld_lds16c(pB2 + s1, ldsw + NBO + 32768 + 16384);
    gld_lds16c(pB3 + s1, ldsw + NBO + 32768 + 16384 + 8192);
  }
  __builtin_amdgcn_s_barrier();
  asm volatile("s_waitcnt lgkmcnt(0)" ::: "memory");
  __builtin_amdgcn_sched_barrier(0);
  __builtin_amdgcn_s_setprio(1);
  #pragma unroll
  for (int mf = 0; mf < 4; ++mf)
    #pragma unroll
    for (int nf = 2; nf < 4; ++nf)
      #pragma unroll
      for (int j = 0; j < 2; ++j)
        acc[mf][nf] = __builtin_amdgcn_mfma_f32_16x16x32_bf16(a4[mf][j], b4[nf][j], acc[mf][nf], 0, 0, 0);
  __builtin_amdgcn_s_setprio(0);
  __builtin_amdgcn_s_barrier();
  // ---- phase 2: read A4-7; stage B-h0(t+2) ----
  #pragma unroll
  for (int mi = 0; mi < 4; ++mi) {
    a4[mi][0] = *(const short8*)(ldsc + DBO + rA0 + (4+mi)*2048);
    a4[mi][1] = *(const short8*)(ldsc + DBO + rA1 + (4+mi)*2048);
  }
  if (gH0) {
    gld_lds16c(pB0 + s2, ldsw + DBO + 32768);
    gld_lds16c(pB1 + s2, ldsw + DBO + 32768 + 8192);
  }
  __builtin_amdgcn_s_barrier();
  asm volatile("s_waitcnt lgkmcnt(0)" ::: "memory");
  __builtin_amdgcn_sched_barrier(0);
  __builtin_amdgcn_s_setprio(1);
  #pragma unroll
  for (int mi = 0; mi < 4; ++mi)
    #pragma unroll
    for (int nf = 2; nf < 4; ++nf)
      #pragma unroll
      for (int j = 0; j < 2; ++j)
        acc[4+mi][nf] = __builtin_amdgcn_mfma_f32_16x16x32_bf16(a4[mi][j], b4[nf][j], acc[4+mi][nf], 0, 0, 0);
  __builtin_amdgcn_s_setprio(0);
  __builtin_amdgcn_s_barrier();
  // ---- phase 3: stage A-h0(t+2); MFMA m4-7 x n0-1 ----
  if (gH0) {
    gld_lds16c(pA0 + s2, ldsw + DBO);
    gld_lds16c(pA1 + s2, ldsw + DBO + 8192);
  }
  __builtin_amdgcn_s_barrier();
  __builtin_amdgcn_s_setprio(1);
  #pragma unroll
  for (int mi = 0; mi < 4; ++mi)
    #pragma unroll
    for (int nf = 0; nf < 2; ++nf)
      #pragma unroll
      for (int j = 0; j < 2; ++j)
        acc[4+mi][nf] = __builtin_amdgcn_mfma_f32_16x16x32_bf16(a4[mi][j], b4[nf][j], acc[4+mi][nf], 0, 0, 0);
  __builtin_amdgcn_s_setprio(0);
  if (wmode == 0)      asm volatile("s_waitcnt vmcnt(4)" ::: "memory");
  else if (wmode == 1) asm volatile("s_waitcnt vmcnt(0)" ::: "memory");
  __builtin_amdgcn_s_barrier();
}

__global__ void __launch_bounds__(512, 2)
gemm8(const bf16* __restrict__ A, long a_rs,
      const bf16* __restrict__ Bt, long b_rs,
      float* __restrict__ Cf, bf16* __restrict__ Cb,
      long c_rs, long c_zoff, int M, int N, int Ksub)
{
  __shared__ __attribute__((aligned(128))) char ldsc[131072];
  const int tid = threadIdx.x;
  const int wid = tid >> 6, lid = tid & 63;
  const int wm = wid >> 2, wn = wid & 3;           // 2 x 4 wave grid
  const int fr = lid & 15, g8 = (lid >> 4) * 8;
  const int brow = blockIdx.y * 256, bcol = blockIdx.x * 256;
  const long k0b = (long)blockIdx.z * Ksub * 2;
  const long a_rsb = a_rs * 2, b_rsb = b_rs * 2;
  const int srow = tid >> 3;
  const int scol = ((tid & 7) ^ (srow & 7)) << 4;
  const int NT = Ksub >> 6;
  char* ldsw = ldsc + wid * 1024;

  int ra0_ = brow + srow;        if (ra0_ > M-1) ra0_ = M-1;
  int ra1_ = brow + 64 + srow;   if (ra1_ > M-1) ra1_ = M-1;
  int ra2_ = brow + 128 + srow;  if (ra2_ > M-1) ra2_ = M-1;
  int ra3_ = brow + 192 + srow;  if (ra3_ > M-1) ra3_ = M-1;
  int rb0_ = bcol + srow;        if (rb0_ > N-1) rb0_ = N-1;
  int rb1_ = bcol + 64 + srow;   if (rb1_ > N-1) rb1_ = N-1;
  int rb2_ = bcol + 128 + srow;  if (rb2_ > N-1) rb2_ = N-1;
  int rb3_ = bcol + 192 + srow;  if (rb3_ > N-1) rb3_ = N-1;
  const char* pA0 = (const char*)A + (long)ra0_*a_rsb + k0b + scol;
  const char* pA1 = (const char*)A + (long)ra1_*a_rsb + k0b + scol;
  const char* pA2 = (const char*)A + (long)ra2_*a_rsb + k0b + scol;
  const char* pA3 = (const char*)A + (long)ra3_*a_rsb + k0b + scol;
  const char* pB0 = (const char*)Bt + (long)rb0_*b_rsb + k0b + scol;
  const char* pB1 = (const char*)Bt + (long)rb1_*b_rsb + k0b + scol;
  const char* pB2 = (const char*)Bt + (long)rb2_*b_rsb + k0b + scol;
  const char* pB3 = (const char*)Bt + (long)rb3_*b_rsb + k0b + scol;

  const int swz = (fr & 7) << 4;
  const int cx0 = (g8 * 2) ^ swz;
  const int cx1 = (64 + g8 * 2) ^ swz;
  const int rA0 = (wm*128 + fr)*128 + cx0;
  const int rA1 = (wm*128 + fr)*128 + cx1;
  const int rB0 = 32768 + (wn*64 + fr)*128 + cx0;
  const int rB1 = 32768 + (wn*64 + fr)*128 + cx1;

  f32x4 acc[8][4] = {};
  short8 a4[4][2], b4[4][2];

  gld_lds16c(pA0, ldsw);
  gld_lds16c(pA1, ldsw + 8192);
  gld_lds16c(pA2, ldsw + 16384);
  gld_lds16c(pA3, ldsw + 16384 + 8192);
  gld_lds16c(pB0, ldsw + 32768);
  gld_lds16c(pB1, ldsw + 32768 + 8192);
  gld_lds16c(pB2, ldsw + 32768 + 16384);
  gld_lds16c(pB3, ldsw + 32768 + 16384 + 8192);
  gld_lds16c(pA0 + 128, ldsw + 65536);
  gld_lds16c(pA1 + 128, ldsw + 65536 + 8192);
  gld_lds16c(pB0 + 128, ldsw + 65536 + 32768);
  gld_lds16c(pB1 + 128, ldsw + 65536 + 32768 + 8192);
  asm volatile("s_waitcnt vmcnt(4)" ::: "memory");
  __builtin_amdgcn_s_barrier();

  for (int tp = 0; tp < NT; tp += 2) {
    const bool g2 = (tp + 2) < NT;
    tile_step<0>(ldsc, ldsw, rA0, rA1, rB0, rB1,
                 pA0, pA1, pA2, pA3, pB0, pB1, pB2, pB3,
                 128, 256, true, g2, g2 ? 0 : 1, acc, a4, b4);
    tile_step<1>(ldsc, ldsw, rA0, rA1, rB0, rB1,
                 pA0, pA1, pA2, pA3, pB0, pB1, pB2, pB3,
                 256, 384, g2, g2, g2 ? 0 : 2, acc, a4, b4);
    if (g2) {
      pA0 += 256; pA1 += 256; pA2 += 256; pA3 += 256;
      pB0 += 256; pB1 += 256; pB2 += 256; pB3 += 256;
    }
  }

  const int rg = (lid >> 4) * 4;
  #pragma unroll
  for (int mf = 0; mf < 8; ++mf) {
    #pragma unroll
    for (int nf = 0; nf < 4; ++nf) {
      const int col = bcol + wn*64 + nf*16 + fr;
      if (col < N) {
        #pragma unroll
        for (int j = 0; j < 4; ++j) {
          const int row = brow + wm*128 + mf*16 + rg + j;
          if (row < M) {
            long off = (long)blockIdx.z*c_zoff + (long)row*c_rs + col;
            if (Cb) Cb[off] = __float2bfloat16(acc[mf][nf][j]);
            else    Cf[off] = acc[mf][nf][j];
          }
        }
      }
    }
  }
}

// ---------------- bf16x3 split GEMM: A=(Ah+Al), B=(Bh+Bl), 3 products ----------------
// LDS chunk-XOR swizzle: 16B chunk index c at LDS row r holds global chunk c^(r&3)
// (pre-swizzled global source, linear gld_lds dest); reads XOR g8 with (row&3)<<3.
__global__ void __launch_bounds__(256)
gemm3_bt(const bf16* __restrict__ Ah, const bf16* __restrict__ Al,
         long a_rs, long a_oo, long a_oi,
         const bf16* __restrict__ Bth, const bf16* __restrict__ Btl,
         long b_rs, long b_oo, long b_oi,
         float* __restrict__ Cf, bf16* __restrict__ Ch, bf16* __restrict__ Cl,
         long c_rs, long c_oo, long c_oi,
         int M, int N, int K, int nlim, int zdiv)
{
  __shared__ bf16 lAh[4096];
  __shared__ bf16 lAl[4096];
  __shared__ bf16 lBh[4096];
  __shared__ bf16 lBl[4096];
  const int tid = threadIdx.x;
  const int wid = tid >> 6;
  const int lid = tid & 63;
  const int z = blockIdx.z;
  const int zo = z / zdiv, zi = z - zo*zdiv;
  const long aoff = (long)zo*a_oo + (long)zi*a_oi;
  const long boff = (long)zo*b_oo + (long)zi*b_oi;
  const long cbase = (long)zo*c_oo + (long)zi*c_oi;
  const int brow = blockIdx.y * 128;
  const int bcol = blockIdx.x * 128;

  const int ch0 = tid, ch1 = tid + 256;
  int ra0 = brow + (ch0 >> 2); if (ra0 > M-1) ra0 = M-1;
  int ra1 = brow + (ch1 >> 2); if (ra1 > M-1) ra1 = M-1;
  int rb0 = bcol + (ch0 >> 2); if (rb0 > N-1) rb0 = N-1;
  int rb1 = bcol + (ch1 >> 2); if (rb1 > N-1) rb1 = N-1;
  // pre-swizzled source chunk: chunk ^ (ldsrow & 3)  (same for ch0/ch1)
  const int sw = ((ch0 ^ (ch0 >> 2)) & 3) * 8;
  const long ia0 = aoff + (long)ra0*a_rs + sw;
  const long ia1 = aoff + (long)ra1*a_rs + sw;
  const long ib0 = boff + (long)rb0*b_rs + sw;
  const long ib1 = boff + (long)rb1*b_rs + sw;
  bf16* dAh0 = (bf16*)((char*)lAh + wid*1024);
  bf16* dAh1 = (bf16*)((char*)lAh + 4096 + wid*1024);
  bf16* dAl0 = (bf16*)((char*)lAl + wid*1024);
  bf16* dAl1 = (bf16*)((char*)lAl + 4096 + wid*1024);
  bf16* dBh0 = (bf16*)((char*)lBh + wid*1024);
  bf16* dBh1 = (bf16*)((char*)lBh + 4096 + wid*1024);
  bf16* dBl0 = (bf16*)((char*)lBl + wid*1024);
  bf16* dBl1 = (bf16*)((char*)lBl + 4096 + wid*1024);

  f32x4 acc[4][4] = {};
  const int wm = wid >> 1, wn = wid & 1;
  const int fr = lid & 15, g8 = (lid >> 4) * 8;
  const int gx = g8 ^ ((lid & 3) << 3);   // read-side chunk XOR (row&3 == lid&3)

  for (int kt = 0; kt < K; kt += 32) {
    __syncthreads();
    gld_lds16(Ah + ia0 + kt, dAh0);
    gld_lds16(Ah + ia1 + kt, dAh1);
    gld_lds16(Al + ia0 + kt, dAl0);
    gld_lds16(Al + ia1 + kt, dAl1);
    gld_lds16(Bth + ib0 + kt, dBh0);
    gld_lds16(Bth + ib1 + kt, dBh1);
    gld_lds16(Btl + ib0 + kt, dBl0);
    gld_lds16(Btl + ib1 + kt, dBl1);
    __syncthreads();
    short8 fah[4], fal[4], fbh[4], fbl[4];
    #pragma unroll
    for (int m = 0; m < 4; ++m) {
      int ro = (wm*64 + m*16 + fr)*32 + gx;
      fah[m] = *(const short8*)&lAh[ro];
      fal[m] = *(const short8*)&lAl[ro];
    }
    #pragma unroll
    for (int n = 0; n < 4; ++n) {
      int ro = (wn*64 + n*16 + fr)*32 + gx;
      fbh[n] = *(const short8*)&lBh[ro];
      fbl[n] = *(const short8*)&lBl[ro];
    }
    #pragma unroll
    for (int m = 0; m < 4; ++m)
      #pragma unroll
      for (int n = 0; n < 4; ++n) {
        acc[m][n] = __builtin_amdgcn_mfma_f32_16x16x32_bf16(fal[m], fbh[n], acc[m][n], 0, 0, 0);
        acc[m][n] = __builtin_amdgcn_mfma_f32_16x16x32_bf16(fah[m], fbl[n], acc[m][n], 0, 0, 0);
        acc[m][n] = __builtin_amdgcn_mfma_f32_16x16x32_bf16(fah[m], fbh[n], acc[m][n], 0, 0, 0);
      }
  }

  const int rg = (lid >> 4) * 4;
  #pragma unroll
  for (int m = 0; m < 4; ++m) {
    #pragma unroll
    for (int n = 0; n < 4; ++n) {
      const int col = bcol + wn*64 + n*16 + fr;
      if (col < nlim) {
        #pragma unroll
        for (int j = 0; j < 4; ++j) {
          const int row = brow + wm*64 + m*16 + rg + j;
          if (row < M) {
            long off = cbase + (long)row*c_rs + col;
            float v = acc[m][n][j];
            if (Cl) {
              bf16 h = __float2bfloat16(v);
              Ch[off] = h;
              Cl[off] = __float2bfloat16(v - __bfloat162float(h));
            } else if (Ch) {
              Ch[off] = __float2bfloat16(v);
            } else {
              Cf[off] = v;
            }
          }
        }
      }
    }
  }
}

// ---------------- weight transpose fp32 -> bf16 ----------------
__global__ void wtrans(const float* __restrict__ in, bf16* __restrict__ out,
                       int R, int Cc, long in_rs, long out_rs, long in_bs, long out_bs)
{
  __shared__ float tile[32][33];
  in  += (long)blockIdx.z * in_bs;
  out += (long)blockIdx.z * out_bs;
  int r0 = blockIdx.y*32, c0 = blockIdx.x*32;
  int tx = threadIdx.x, ty = threadIdx.y;
  #pragma unroll
  for (int i = 0; i < 32; i += 8) {
    int r = r0 + ty + i, c = c0 + tx;
    if (r < R && c < Cc) tile[ty+i][tx] = in[(long)r*in_rs + c];
  }
  __syncthreads();
  #pragma unroll
  for (int i = 0; i < 32; i += 8) {
    int ro = c0 + ty + i, co = r0 + tx;
    if (ro < Cc && co < R) out[(long)ro*out_rs + co] = __float2bfloat16(tile[tx][ty+i]);
  }
}

// ---------------- weight transpose fp32 -> bf16 hi/lo pair ----------------
__global__ void wtrans3(const float* __restrict__ in, bf16* __restrict__ oh, bf16* __restrict__ ol,
                        int R, int Cc, long in_rs, long out_rs)
{
  __shared__ float tile[32][33];
  int r0 = blockIdx.y*32, c0 = blockIdx.x*32;
  int tx = threadIdx.x, ty = threadIdx.y;
  #pragma unroll
  for (int i = 0; i < 32; i += 8) {
    int r = r0 + ty + i, c = c0 + tx;
    if (r < R && c < Cc) tile[ty+i][tx] = in[(long)r*in_rs + c];
  }
  __syncthreads();
  #pragma unroll
  for (int i = 0; i < 32; i += 8) {
    int ro = c0 + ty + i, co = r0 + tx;
    if (ro < Cc && co < R) {
      float v = tile[tx][ty+i];
      bf16 h = __float2bfloat16(v);
      long o = (long)ro*out_rs + co;
      oh[o] = h;
      ol[o] = __float2bfloat16(v - __bfloat162float(h));
    }
  }
}

// ---------------- LayerNorm ----------------
__global__ void ln_partial(const float* __restrict__ x, float* __restrict__ part) {
  int b = blockIdx.y, blk = blockIdx.x;
  const float* xb = x + (long)b*NPB;
  int start = blk * 4374;
  float s = 0.f, ss = 0.f;
  for (int i = start + threadIdx.x; i < start + 4374; i += 256) {
    float v = xb[i]; s += v; ss += v*v;
  }
  #pragma unroll
  for (int o = 32; o; o >>= 1) { s += __shfl_down(s, o); ss += __shfl_down(ss, o); }
  __shared__ float red[2][4];
  int wid = threadIdx.x >> 6, lid = threadIdx.x & 63;
  if (lid == 0) { red[0][wid] = s; red[1][wid] = ss; }
  __syncthreads();
  if (threadIdx.x == 0) {
    float S = 0.f, SS = 0.f;
    for (int w = 0; w < 4; ++w) { S += red[0][w]; SS += red[1][w]; }
    part[(b*128 + blk)*2] = S; part[(b*128 + blk)*2 + 1] = SS;
  }
}

__global__ void ln_final(const float* __restrict__ part, float* __restrict__ stats) {
  int b = blockIdx.x, lid = threadIdx.x;
  float s = 0.f, ss = 0.f;
  for (int i = lid; i < 128; i += 64) { s += part[(b*128+i)*2]; ss += part[(b*128+i)*2+1]; }
  #pragma unroll
  for (int o = 32; o; o >>= 1) { s += __shfl_down(s, o); ss += __shfl_down(ss, o); }
  if (lid == 0) {
    float mean = s / (float)NPB;
    float var = ss / (float)NPB - mean*mean;
    stats[b*2] = mean; stats[b*2+1] = rsqrtf(var + 1e-5f);
  }
}

__global__ void ln_apply3(const float* __restrict__ x, const float* __restrict__ lnw,
                          const float* __restrict__ lnb, const float* __restrict__ stats,
                          bf16* __restrict__ th, bf16* __restrict__ tl)
{
  __shared__ float tile[32][33];
  int b = blockIdx.z;
  int s0 = blockIdx.x*32, c0 = blockIdx.y*32;
  float mean = stats[b*2], rstd = stats[b*2+1];
  int tx = threadIdx.x, ty = threadIdx.y;
  #pragma unroll
  for (int i = 0; i < 32; i += 8) {
    int c = c0 + ty + i, s = s0 + tx;
    if (s < S_) {
      long o = (long)c*S_ + s;
      tile[ty+i][tx] = (x[(long)b*NPB + o] - mean)*rstd*lnw[o] + lnb[o];
    }
  }
  __syncthreads();
  #pragma unroll
  for (int i = 0; i < 32; i += 8) {
    int s = s0 + ty + i, c = c0 + tx;
    if (s < S_) {
      float v = tile[tx][ty+i];
      bf16 h = __float2bfloat16(v);
      long o = ((long)b*S_ + s)*C_ + c;
      th[o] = h;
      tl[o] = __float2bfloat16(v - __bfloat162float(h));
    }
  }
}

// ---------------- V transpose (bf16), zero pad t in [S_, SPAD) ----------------
__global__ void vtrans(const bf16* __restrict__ qkv, bf16* __restrict__ VT) {
  __shared__ float tile[32][33];
  int z = blockIdx.z; int bb = z >> 3, h = z & 7;
  const bf16* v = qkv + (long)bb*S_*C3 + 1536 + h*DH_;
  bf16* o = VT + (long)z*DH_*SPAD;
  int t0 = blockIdx.y*32, d0 = blockIdx.x*32;
  int tx = threadIdx.x, ty = threadIdx.y;
  #pragma unroll
  for (int i = 0; i < 32; i += 8) {
    int t = t0 + ty + i, d = d0 + tx;
    float val = 0.f;
    if (t < S_ && d < DH_) val = __bfloat162float(v[(long)t*C3 + d]);
    tile[ty+i][tx] = val;
  }
  __syncthreads();
  #pragma unroll
  for (int i = 0; i < 32; i += 8) {
    int d = d0 + ty + i, t = t0 + tx;
    if (d < DH_ && t < SPAD) o[(long)d*SPAD + t] = __float2bfloat16(tile[tx][ty+i]);
  }
}

// -------- softmax over bf16 hi/lo score rows, IN PLACE (row stride 2*SPAD) --------
__global__ void softmax3p(bf16* __restrict__ scores, int nrows) {
  int row = blockIdx.x*4 + (threadIdx.x >> 6);
  if (row >= nrows) return;
  int lid = threadIdx.x & 63;
  bf16* ph = scores + (long)row*2*SPAD;
  bf16* pl = ph + SPAD;
  float vals[12];
  float mx = -1e30f;
  #pragma unroll
  for (int i = 0; i < 12; ++i) {
    int t = i*64 + lid;
    float v = -1e30f;
    if (t < S_) v = __bfloat162float(ph[t]) + __bfloat162float(pl[t]);
    vals[i] = v; mx = fmaxf(mx, v);
  }
  #pragma unroll
  for (int o = 32; o; o >>= 1) mx = fmaxf(mx, __shfl_xor(mx, o));
  float sum = 0.f;
  #pragma unroll
  for (int i = 0; i < 12; ++i) { float e = __expf(vals[i] - mx); vals[i] = e; sum += e; }
  #pragma unroll
  for (int o = 32; o; o >>= 1) sum += __shfl_xor(sum, o);
  float inv = 1.f / sum;
  #pragma unroll
  for (int i = 0; i < 12; ++i) {
    int t = i*64 + lid;
    if (t < SPAD) {
      float p = (t < S_) ? vals[i]*inv : 0.f;
      bf16 h = __float2bfloat16(p);
      ph[t] = h;
      pl[t] = __float2bfloat16(p - __bfloat162float(h));
    }
  }
}

// ---------------- residual transpose-add 1 ----------------
__global__ void tadd1(const float* __restrict__ x, const float* __restrict__ oproj,
                      float* __restrict__ xattn, bf16* __restrict__ tok2,
                      float* __restrict__ tok2f)
{
  __shared__ float t_o[32][33];
  __shared__ float t_x[32][33];
  int b = blockIdx.z;
  int s0 = blockIdx.x*32, c0 = blockIdx.y*32;
  int tx = threadIdx.x, ty = threadIdx.y;
  #pragma unroll
  for (int i = 0; i < 32; i += 8) {
    int s = s0 + ty + i;
    if (s < S_) t_o[ty+i][tx] = oproj[((long)b*S_ + s)*C_ + c0 + tx];
    int s2 = s0 + tx;
    if (s2 < S_) t_x[ty+i][tx] = x[(long)b*NPB + (long)(c0+ty+i)*S_ + s2];
  }
  __syncthreads();
  #pragma unroll
  for (int i = 0; i < 32; i += 8) {
    int s = s0 + tx, c = c0 + ty + i;
    if (s < S_) xattn[(long)b*NPB + (long)c*S_ + s] = t_x[ty+i][tx] + t_o[tx][ty+i];
    int s2 = s0 + ty + i, c2 = c0 + tx;
    if (s2 < S_) {
      float v = t_x[tx][ty+i] + t_o[ty+i][tx];
      long o = ((long)b*S_ + s2)*C_ + c2;
      tok2[o] = __float2bfloat16(v);
      tok2f[o] = v;
    }
  }
}

// ---- residual transpose-add 2 (final output), sums 8 bf16 down-partials in place ----
__global__ void tadd2(const float* __restrict__ xattn, const bf16* __restrict__ prt,
                      float* __restrict__ out)
{
  __shared__ float t_m[32][33];
  __shared__ float t_x[32][33];
  int b = blockIdx.z;
  int s0 = blockIdx.x*32, c0 = blockIdx.y*32;
  int tx = threadIdx.x, ty = threadIdx.y;
  #pragma unroll
  for (int i = 0; i < 32; i += 8) {
    int s = s0 + ty + i;
    if (s < S_) {
      const bf16* p = prt + ((long)b*S_ + s)*GUN + c0 + tx;
      float acc = 0.f;
      #pragma unroll
      for (int z = 0; z < 8; ++z) acc += __bfloat162float(p[z*768]);
      t_m[ty+i][tx] = acc;
    }
    int s2 = s0 + tx;
    if (s2 < S_) t_x[ty+i][tx] = xattn[(long)b*NPB + (long)(c0+ty+i)*S_ + s2];
  }
  __syncthreads();
  #pragma unroll
  for (int i = 0; i < 32; i += 8) {
    int s = s0 + tx, c = c0 + ty + i;
    if (s < S_) out[(long)b*NPB + (long)c*S_ + s] = t_x[ty+i][tx] + t_m[tx][ty+i];
  }
}

// ---------------- router: top-2 of 3 from fp32 tok2, normalized weights ----------------
__global__ void router_k(const float* __restrict__ tok2f, const float* __restrict__ rw,
                         float* __restrict__ wfull)
{
  int t = blockIdx.x*4 + (threadIdx.x >> 6);
  if (t >= MTOK) return;
  int lid = threadIdx.x & 63;
  const float* tk = tok2f + (long)t*C_;
  float a0 = 0.f, a1 = 0.f, a2 = 0.f;
  for (int i = lid; i < C_; i += 64) {
    float v = tk[i];
    a0 += v*rw[i*3+0]; a1 += v*rw[i*3+1]; a2 += v*rw[i*3+2];
  }
  #pragma unroll
  for (int o = 32; o; o >>= 1) {
    a0 += __shfl_xor(a0, o); a1 += __shfl_xor(a1, o); a2 += __shfl_xor(a2, o);
  }
  if (lid == 0) {
    float m = fmaxf(a0, fmaxf(a1, a2));
    float e0 = __expf(a0-m), e1 = __expf(a1-m), e2 = __expf(a2-m);
    int emin = 0; float pm = e0;
    if (e1 <= pm) { pm = e1; emin = 1; }
    if (e2 <= pm) { pm = e2; emin = 2; }
    float rest = e0 + e1 + e2 - pm;
    wfull[t*3+0] = (emin == 0) ? 0.f : e0/rest;
    wfull[t*3+1] = (emin == 1) ? 0.f : e1/rest;
    wfull[t*3+2] = (emin == 2) ? 0.f : e2/rest;
  }
}

// ---------------- silu(g)*u*w, in place into gate half of GU ----------------
__global__ void silu_k(bf16* __restrict__ GU, const float* __restrict__ wfull) {
  long tid8 = (long)blockIdx.x*256 + threadIdx.x;
  long idx = tid8 * 8;
  int m = (int)(idx / DK);
  int j = (int)(idx - (long)m*DK);
  int e = j >> 11;
  float w = wfull[m*3 + e];
  bf16* gp = GU + (long)m*GUN + j;
  const bf16* up = gp + DK;
  union U8 { uint4v u; bf16 h[8]; };
  U8 g8, u8, o8;
  g8.u = *(const uint4v*)gp;
  u8.u = *(const uint4v*)up;
  #pragma unroll
  for (int i = 0; i < 8; ++i) {
    float g = __bfloat162float(g8.h[i]);
    float u = __bfloat162float(u8.h[i]);
    float sg = g / (1.f + __expf(-g));
    o8.h[i] = __float2bfloat16(sg * u * w);
  }
  *(uint4v*)gp = o8.u;
}

// =============================== host ===============================
static inline void launch_gemm3(hipStream_t st,
    const bf16* Ah, const bf16* Al, long a_rs, long a_oo, long a_oi,
    const bf16* Bh, const bf16* Bl, long b_rs, long b_oo, long b_oi,
    float* Cf, bf16* Ch, bf16* Cl, long c_rs, long c_oo, long c_oi,
    int M, int N, int K, int nlim, int zdiv, int nz)
{
  dim3 g((N + 127)/128, (M + 127)/128, nz);
  gemm3_bt<<<g, 256, 0, st>>>(Ah, Al, a_rs, a_oo, a_oi, Bh, Bl, b_rs, b_oo, b_oi,
                              Cf, Ch, Cl, c_rs, c_oo, c_oi, M, N, K, nlim, zdiv);
}

extern "C" void kernel_launch(void* const* d_in, const int* in_sizes, int n_in,
                              void* d_out, int out_size, void* d_ws, size_t ws_size,
                              hipStream_t stream)
{
  const float* x      = (const float*)d_in[0];
  const float* ln_w   = (const float*)d_in[1];
  const float* ln_b   = (const float*)d_in[2];
  const float* qkv_w  = (const float*)d_in[3];
  const float* proj_w = (const float*)d_in[4];
  const float* rout_w = (const float*)d_in[5];
  const float* gate_w = (const float*)d_in[6];
  const float* up_w   = (const float*)d_in[7];
  const float* down_w = (const float*)d_in[8];
  float* out = (float*)d_out;

  char* ws = (char*)d_ws;
  size_t off = 0;
  auto alloc = [&](size_t bytes) { size_t r = off; off += (bytes + 255) & ~(size_t)255; return r; };

  // persistent (~82.6 MB)
  size_t o_stats = alloc(8*2*4);
  size_t o_part  = alloc(8*128*2*4);
  size_t o_wfull = alloc((size_t)MTOK*3*4);
  size_t o_qkvTh = alloc((size_t)C3*C_*2);
  size_t o_qkvTl = alloc((size_t)C3*C_*2);
  size_t o_prjTh = alloc((size_t)C_*C_*2);
  size_t o_prjTl = alloc((size_t)C_*C_*2);
  size_t o_guT   = alloc((size_t)GUN*C_*2);
  size_t o_downT = alloc((size_t)C_*DK*2);
  size_t o_xattn = alloc((size_t)B_*NPB*4);
  size_t o_tok2  = alloc((size_t)MTOK*C_*2);
  size_t o_tok2f = alloc((size_t)MTOK*C_*4);
  size_t big0 = off;
  // phase A (attention): fixed buffers + one union region (tok | scores | oproj)
  size_t o_qkvh  = alloc((size_t)MTOK*C3*2);
  size_t o_qkvl  = alloc((size_t)MTOK*C3*2);
  size_t o_VTh   = alloc((size_t)64*DH_*SPAD*2);
  size_t o_VTl   = alloc((size_t)64*DH_*SPAD*2);
  size_t o_aoh   = alloc((size_t)MTOK*C_*2);
  size_t o_aol   = alloc((size_t)MTOK*C_*2);
  size_t o_union = alloc((size_t)32*S_*SPAD*4);   // 68.7 MB: scores(32 pairs) | tok hi+lo | oproj
  size_t endA = off;
  // phase B (MoE, full-M) overlaps phase A; down partials use dead up-half of GU
  off = big0;
  size_t o_GU = alloc((size_t)MTOK*GUN*2);
  size_t endB = off;
  size_t needed = endA > endB ? endA : endB;
  if (ws_size < needed) return;  // insufficient workspace: visible failure

  float* stats  = (float*)(ws + o_stats);
  float* part   = (float*)(ws + o_part);
  float* wfull  = (float*)(ws + o_wfull);
  bf16*  qkvTh  = (bf16*)(ws + o_qkvTh);
  bf16*  qkvTl  = (bf16*)(ws + o_qkvTl);
  bf16*  prjTh  = (bf16*)(ws + o_prjTh);
  bf16*  prjTl  = (bf16*)(ws + o_prjTl);
  bf16*  guT    = (bf16*)(ws + o_guT);
  bf16*  downT  = (bf16*)(ws + o_downT);
  float* xattn  = (float*)(ws + o_xattn);
  bf16*  tok2   = (bf16*)(ws + o_tok2);
  float* tok2f  = (float*)(ws + o_tok2f);
  bf16*  qkvh   = (bf16*)(ws + o_qkvh);
  bf16*  qkvl   = (bf16*)(ws + o_qkvl);
  bf16*  VTh    = (bf16*)(ws + o_VTh);
  bf16*  VTl    = (bf16*)(ws + o_VTl);
  bf16*  aoh    = (bf16*)(ws + o_aoh);
  bf16*  aol    = (bf16*)(ws + o_aol);
  // union region occupants (live ranges are disjoint in stream order):
  bf16*  tokh   = (bf16*)(ws + o_union);                          // dead after qkv gemm
  bf16*  tokl   = (bf16*)(ws + o_union + (size_t)MTOK*C_*2);
  bf16*  Pbase  = (bf16*)(ws + o_union);                          // scores/P hi-lo pairs
  float* oproj  = (float*)(ws + o_union);                         // written after PV done
  bf16*  GU     = (bf16*)(ws + o_GU);

  dim3 b32(32, 8);

  // weight conversions (gate rows [0,6144), up rows [6144,12288) of guT)
  wtrans3<<<dim3(72,24,1), b32, 0, stream>>>(qkv_w,  qkvTh, qkvTl, 768, 2304, 2304, 768);
  wtrans3<<<dim3(24,24,1), b32, 0, stream>>>(proj_w, prjTh, prjTl, 768, 768,  768,  768);
  wtrans<<<dim3(64,24,3), b32, 0, stream>>>(gate_w, guT, 768, 2048, 2048, 768,
                                            (long)768*2048, (long)2048*768);
  wtrans<<<dim3(64,24,3), b32, 0, stream>>>(up_w, guT + (size_t)DK*C_, 768, 2048, 2048, 768,
                                            (long)768*2048, (long)2048*768);
  wtrans<<<dim3(24,64,3), b32, 0, stream>>>(down_w, downT, 2048, 768, 768, 6144,
                                            (long)2048*768, 2048);

  // LayerNorm -> tok hi/lo (b,s,c)
  ln_partial<<<dim3(128,8), 256, 0, stream>>>(x, part);
  ln_final<<<8, 64, 0, stream>>>(part, stats);
  ln_apply3<<<dim3(23,24,8), b32, 0, stream>>>(x, ln_w, ln_b, stats, tokh, tokl);

  // qkv = tok @ qkv_w (bf16x3, hi/lo out); tok region dead afterwards
  launch_gemm3(stream, tokh, tokl, C_, 0, 0, qkvTh, qkvTl, C_, 0, 0,
               nullptr, qkvh, qkvl, C3, 0, 0, MTOK, C3, C_, C3, 1, 1);

  // V^T per (b,h), zero-padded to SPAD (hi and lo)
  vtrans<<<dim3(3,23,64), b32, 0, stream>>>(qkvh, VTh);
  vtrans<<<dim3(3,23,64), b32, 0, stream>>>(qkvl, VTl);

  // attention in 2 chunks of 32 (b,h)-pairs (4 batches each)
  for (int c = 0; c < 2; ++c) {
    const long qoff = (long)(4*c)*S_*C3;
    // QK^T -> bf16 hi/lo pairs directly (row: [hi x736][lo x736])
    launch_gemm3(stream,
        qkvh + qoff, qkvl + qoff, C3, (long)S_*C3, DH_,
        qkvh + qoff + 768, qkvl + qoff + 768, C3, (long)S_*C3, DH_,
        nullptr, Pbase, Pbase + SPAD, 2*SPAD, (long)8*S_*2*SPAD, (long)S_*2*SPAD,
        S_, S_, DH_, SPAD, 8, 32);
    softmax3p<<<5832, 256, 0, stream>>>(Pbase, 32*S_);
    launch_gemm3(stream,
        Pbase, Pbase + SPAD, 2*SPAD, (long)8*S_*2*SPAD, (long)S_*2*SPAD,
        VTh + (size_t)c*32*DH_*SPAD, VTl + (size_t)c*32*DH_*SPAD, SPAD,
        (long)8*DH_*SPAD, (long)DH_*SPAD,
        nullptr, aoh + (size_t)(4*c)*S_*C_, aol + (size_t)(4*c)*S_*C_,
        C_, (long)S_*C_, DH_,
        S_, DH_, SPAD, DH_, 8, 32);
  }

  // oproj = attnout @ proj_w (fp32 out, into union region — P dead now)
  launch_gemm3(stream, aoh, aol, C_, 0, 0, prjTh, prjTl, C_, 0, 0,
               oproj, nullptr, nullptr, C_, 0, 0, MTOK, C_, C_, C_, 1, 1);

  // residual + layouts
  tadd1<<<dim3(23,24,8), b32, 0, stream>>>(x, oproj, xattn, tok2, tok2f);

  // router weights (fp32 path)
  router_k<<<1458, 256, 0, stream>>>(tok2f, rout_w, wfull);

  // MoE full-M: GU gemm -> silu in place -> down (nz=8 K-split, bf16 partials
  // into dead up-half of GU) -> tadd2 sums partials
  gemm8<<<dim3(GUN/256, 23, 1), 512, 0, stream>>>(
      tok2, C_, guT, C_, nullptr, GU, GUN, 0, MTOK, GUN, C_);
  silu_k<<<MTOK*DK/2048, 256, 0, stream>>>(GU, wfull);
  gemm8<<<dim3(C_/256, 23, 8), 512, 0, stream>>>(
      GU, GUN, downT, DK, nullptr, GU + DK, GUN, 768, MTOK, C_, DK/8);

  // final residual transpose-add (sums 8 partials from GU up-half) into output
  tadd2<<<dim3(23,24,8), b32, 0, stream>>>(xattn, GU + DK, out);
}

// Round 11
// 782.526 us; speedup vs baseline: 1.2619x; 1.0045x over previous
//
#include <hip/hip_runtime.h>
#include <hip/hip_bf16.h>

#define C_    768
#define NH_   8
#define DH_   96
#define S_    729
#define B_    8
#define MTOK  5832
#define C3    2304
#define GUN   12288
#define DK    6144
#define SPAD  736
#define NPB   559872   // C_*S_

typedef __attribute__((ext_vector_type(8))) short short8;
typedef __attribute__((ext_vector_type(4))) float f32x4;
typedef __attribute__((ext_vector_type(4))) unsigned int uint4v;
typedef __hip_bfloat16 bf16;

__device__ __forceinline__ void gld_lds16(const bf16* g, bf16* l) {
  __builtin_amdgcn_global_load_lds((const __attribute__((address_space(1))) void*)g,
                                   (__attribute__((address_space(3))) void*)l, 16, 0, 0);
}
__device__ __forceinline__ void gld_lds16c(const char* g, char* l) {
  __builtin_amdgcn_global_load_lds((const __attribute__((address_space(1))) void*)g,
                                   (__attribute__((address_space(3))) void*)l, 16, 0, 0);
}

// ================= 256x256 8-wave 4-phase deep-pipelined GEMM =================
template<int DB>
__device__ __forceinline__ void tile_step(
    char* ldsc, char* ldsw,
    const int rA0, const int rA1, const int rB0, const int rB1,
    const char* pA0, const char* pA1, const char* pA2, const char* pA3,
    const char* pB0, const char* pB1, const char* pB2, const char* pB3,
    const int s1, const int s2, const bool gH1, const bool gH0, const int wmode,
    f32x4 (&acc)[8][4], short8 (&a4)[4][2], short8 (&b4)[4][2])
{
  const int DBO = DB * 65536;
  const int NBO = 65536 - DBO;
  // ---- phase 0: read A0-3 + B0-1; stage A-h1(t+1) ----
  #pragma unroll
  for (int mf = 0; mf < 4; ++mf) {
    a4[mf][0] = *(const short8*)(ldsc + DBO + rA0 + mf*2048);
    a4[mf][1] = *(const short8*)(ldsc + DBO + rA1 + mf*2048);
  }
  #pragma unroll
  for (int nf = 0; nf < 2; ++nf) {
    b4[nf][0] = *(const short8*)(ldsc + DBO + rB0 + nf*2048);
    b4[nf][1] = *(const short8*)(ldsc + DBO + rB1 + nf*2048);
  }
  if (gH1) {
    gld_lds16c(pA2 + s1, ldsw + NBO + 16384);
    gld_lds16c(pA3 + s1, ldsw + NBO + 16384 + 8192);
  }
  __builtin_amdgcn_s_barrier();
  asm volatile("s_waitcnt lgkmcnt(0)" ::: "memory");
  __builtin_amdgcn_sched_barrier(0);
  __builtin_amdgcn_s_setprio(1);
  #pragma unroll
  for (int mf = 0; mf < 4; ++mf)
    #pragma unroll
    for (int nf = 0; nf < 2; ++nf)
      #pragma unroll
      for (int j = 0; j < 2; ++j)
        acc[mf][nf] = __builtin_amdgcn_mfma_f32_16x16x32_bf16(a4[mf][j], b4[nf][j], acc[mf][nf], 0, 0, 0);
  __builtin_amdgcn_s_setprio(0);
  __builtin_amdgcn_s_barrier();
  // ---- phase 1: read B2-3; stage B-h1(t+1) ----
  #pragma unroll
  for (int nf = 2; nf < 4; ++nf) {
    b4[nf][0] = *(const short8*)(ldsc + DBO + rB0 + nf*2048);
    b4[nf][1] = *(const short8*)(ldsc + DBO + rB1 + nf*2048);
  }
  if (gH1) {
    gld_lds16c(pB2 + s1, ldsw + NBO + 32768 + 16384);
    gld_lds16c(pB3 + s1, ldsw + NBO + 32768 + 16384 + 8192);
  }
  __builtin_amdgcn_s_barrier();
  asm volatile("s_waitcnt lgkmcnt(0)" ::: "memory");
  __builtin_amdgcn_sched_barrier(0);
  __builtin_amdgcn_s_setprio(1);
  #pragma unroll
  for (int mf = 0; mf < 4; ++mf)
    #pragma unroll
    for (int nf = 2; nf < 4; ++nf)
      #pragma unroll
      for (int j = 0; j < 2; ++j)
        acc[mf][nf] = __builtin_amdgcn_mfma_f32_16x16x32_bf16(a4[mf][j], b4[nf][j], acc[mf][nf], 0, 0, 0);
  __builtin_amdgcn_s_setprio(0);
  __builtin_amdgcn_s_barrier();
  // ---- phase 2: read A4-7; stage B-h0(t+2) ----
  #pragma unroll
  for (int mi = 0; mi < 4; ++mi) {
    a4[mi][0] = *(const short8*)(ldsc + DBO + rA0 + (4+mi)*2048);
    a4[mi][1] = *(const short8*)(ldsc + DBO + rA1 + (4+mi)*2048);
  }
  if (gH0) {
    gld_lds16c(pB0 + s2, ldsw + DBO + 32768);
    gld_lds16c(pB1 + s2, ldsw + DBO + 32768 + 8192);
  }
  __builtin_amdgcn_s_barrier();
  asm volatile("s_waitcnt lgkmcnt(0)" ::: "memory");
  __builtin_amdgcn_sched_barrier(0);
  __builtin_amdgcn_s_setprio(1);
  #pragma unroll
  for (int mi = 0; mi < 4; ++mi)
    #pragma unroll
    for (int nf = 2; nf < 4; ++nf)
      #pragma unroll
      for (int j = 0; j < 2; ++j)
        acc[4+mi][nf] = __builtin_amdgcn_mfma_f32_16x16x32_bf16(a4[mi][j], b4[nf][j], acc[4+mi][nf], 0, 0, 0);
  __builtin_amdgcn_s_setprio(0);
  __builtin_amdgcn_s_barrier();
  // ---- phase 3: stage A-h0(t+2); MFMA m4-7 x n0-1 ----
  if (gH0) {
    gld_lds16c(pA0 + s2, ldsw + DBO);
    gld_lds16c(pA1 + s2, ldsw + DBO + 8192);
  }
  __builtin_amdgcn_s_barrier();
  __builtin_amdgcn_s_setprio(1);
  #pragma unroll
  for (int mi = 0; mi < 4; ++mi)
    #pragma unroll
    for (int nf = 0; nf < 2; ++nf)
      #pragma unroll
      for (int j = 0; j < 2; ++j)
        acc[4+mi][nf] = __builtin_amdgcn_mfma_f32_16x16x32_bf16(a4[mi][j], b4[nf][j], acc[4+mi][nf], 0, 0, 0);
  __builtin_amdgcn_s_setprio(0);
  if (wmode == 0)      asm volatile("s_waitcnt vmcnt(4)" ::: "memory");
  else if (wmode == 1) asm volatile("s_waitcnt vmcnt(0)" ::: "memory");
  __builtin_amdgcn_s_barrier();
}

// modes: 0 = bf16 out (Cb, +z*c_zoff). 1 = fp32 out (Cf, +z*c_zoff).
// 3 = fused MoE: gate/up interleaved at 16-col granularity; writes
// silu(g)*u*wfull[row*3+e] bf16 to Cb[row*c_rs + h], h = ((col32)>>5)*16+fr.
__global__ void __launch_bounds__(512, 2)
gemm8(const bf16* __restrict__ A, long a_rs,
      const bf16* __restrict__ Bt, long b_rs,
      float* __restrict__ Cf, bf16* __restrict__ Cb,
      long c_rs, long c_zoff, int M, int N, int Ksub,
      const float* __restrict__ wfull, int mode)
{
  __shared__ __attribute__((aligned(128))) char ldsc[131072];
  const int tid = threadIdx.x;
  const int wid = tid >> 6, lid = tid & 63;
  const int wm = wid >> 2, wn = wid & 3;           // 2 x 4 wave grid
  const int fr = lid & 15, g8 = (lid >> 4) * 8;
  const int brow = blockIdx.y * 256, bcol = blockIdx.x * 256;
  const long k0b = (long)blockIdx.z * Ksub * 2;
  const long a_rsb = a_rs * 2, b_rsb = b_rs * 2;
  const int srow = tid >> 3;
  const int scol = ((tid & 7) ^ (srow & 7)) << 4;
  const int NT = Ksub >> 6;
  char* ldsw = ldsc + wid * 1024;

  int ra0_ = brow + srow;        if (ra0_ > M-1) ra0_ = M-1;
  int ra1_ = brow + 64 + srow;   if (ra1_ > M-1) ra1_ = M-1;
  int ra2_ = brow + 128 + srow;  if (ra2_ > M-1) ra2_ = M-1;
  int ra3_ = brow + 192 + srow;  if (ra3_ > M-1) ra3_ = M-1;
  int rb0_ = bcol + srow;        if (rb0_ > N-1) rb0_ = N-1;
  int rb1_ = bcol + 64 + srow;   if (rb1_ > N-1) rb1_ = N-1;
  int rb2_ = bcol + 128 + srow;  if (rb2_ > N-1) rb2_ = N-1;
  int rb3_ = bcol + 192 + srow;  if (rb3_ > N-1) rb3_ = N-1;
  const char* pA0 = (const char*)A + (long)ra0_*a_rsb + k0b + scol;
  const char* pA1 = (const char*)A + (long)ra1_*a_rsb + k0b + scol;
  const char* pA2 = (const char*)A + (long)ra2_*a_rsb + k0b + scol;
  const char* pA3 = (const char*)A + (long)ra3_*a_rsb + k0b + scol;
  const char* pB0 = (const char*)Bt + (long)rb0_*b_rsb + k0b + scol;
  const char* pB1 = (const char*)Bt + (long)rb1_*b_rsb + k0b + scol;
  const char* pB2 = (const char*)Bt + (long)rb2_*b_rsb + k0b + scol;
  const char* pB3 = (const char*)Bt + (long)rb3_*b_rsb + k0b + scol;

  const int swz = (fr & 7) << 4;
  const int cx0 = (g8 * 2) ^ swz;
  const int cx1 = (64 + g8 * 2) ^ swz;
  const int rA0 = (wm*128 + fr)*128 + cx0;
  const int rA1 = (wm*128 + fr)*128 + cx1;
  const int rB0 = 32768 + (wn*64 + fr)*128 + cx0;
  const int rB1 = 32768 + (wn*64 + fr)*128 + cx1;

  f32x4 acc[8][4] = {};
  short8 a4[4][2], b4[4][2];

  gld_lds16c(pA0, ldsw);
  gld_lds16c(pA1, ldsw + 8192);
  gld_lds16c(pA2, ldsw + 16384);
  gld_lds16c(pA3, ldsw + 16384 + 8192);
  gld_lds16c(pB0, ldsw + 32768);
  gld_lds16c(pB1, ldsw + 32768 + 8192);
  gld_lds16c(pB2, ldsw + 32768 + 16384);
  gld_lds16c(pB3, ldsw + 32768 + 16384 + 8192);
  gld_lds16c(pA0 + 128, ldsw + 65536);
  gld_lds16c(pA1 + 128, ldsw + 65536 + 8192);
  gld_lds16c(pB0 + 128, ldsw + 65536 + 32768);
  gld_lds16c(pB1 + 128, ldsw + 65536 + 32768 + 8192);
  asm volatile("s_waitcnt vmcnt(4)" ::: "memory");
  __builtin_amdgcn_s_barrier();

  for (int tp = 0; tp < NT; tp += 2) {
    const bool g2 = (tp + 2) < NT;
    tile_step<0>(ldsc, ldsw, rA0, rA1, rB0, rB1,
                 pA0, pA1, pA2, pA3, pB0, pB1, pB2, pB3,
                 128, 256, true, g2, g2 ? 0 : 1, acc, a4, b4);
    tile_step<1>(ldsc, ldsw, rA0, rA1, rB0, rB1,
                 pA0, pA1, pA2, pA3, pB0, pB1, pB2, pB3,
                 256, 384, g2, g2, g2 ? 0 : 2, acc, a4, b4);
    if (g2) {
      pA0 += 256; pA1 += 256; pA2 += 256; pA3 += 256;
      pB0 += 256; pB1 += 256; pB2 += 256; pB3 += 256;
    }
  }

  const int rg = (lid >> 4) * 4;
  if (mode == 3) {
    // fused silu(gate)*up*w epilogue; gate=acc[*][even nf], up=acc[*][odd nf]
    #pragma unroll
    for (int mf = 0; mf < 8; ++mf) {
      #pragma unroll
      for (int np = 0; np < 2; ++np) {
        const int hb = (bcol + wn*64 + np*32) >> 5;   // 32-row block index
        const int h = hb*16 + fr;
        const int e = h >> 11;                         // expert = h / 2048
        #pragma unroll
        for (int j = 0; j < 4; ++j) {
          const int row = brow + wm*128 + mf*16 + rg + j;
          if (row < M) {
            float g = acc[mf][2*np][j];
            float u = acc[mf][2*np+1][j];
            float w = wfull[row*3 + e];
            float sg = g / (1.f + __expf(-g));
            Cb[(long)row*c_rs + h] = __float2bfloat16(sg * u * w);
          }
        }
      }
    }
  } else {
    #pragma unroll
    for (int mf = 0; mf < 8; ++mf) {
      #pragma unroll
      for (int nf = 0; nf < 4; ++nf) {
        const int col = bcol + wn*64 + nf*16 + fr;
        if (col < N) {
          #pragma unroll
          for (int j = 0; j < 4; ++j) {
            const int row = brow + wm*128 + mf*16 + rg + j;
            if (row < M) {
              long off = (long)blockIdx.z*c_zoff + (long)row*c_rs + col;
              if (mode == 0) Cb[off] = __float2bfloat16(acc[mf][nf][j]);
              else           Cf[off] = acc[mf][nf][j];
            }
          }
        }
      }
    }
  }
}

// ---------------- bf16x3 split GEMM: A=(Ah+Al), B=(Bh+Bl), 3 products ----------------
__global__ void __launch_bounds__(256)
gemm3_bt(const bf16* __restrict__ Ah, const bf16* __restrict__ Al,
         long a_rs, long a_oo, long a_oi,
         const bf16* __restrict__ Bth, const bf16* __restrict__ Btl,
         long b_rs, long b_oo, long b_oi,
         float* __restrict__ Cf, bf16* __restrict__ Ch, bf16* __restrict__ Cl,
         long c_rs, long c_oo, long c_oi,
         int M, int N, int K, int nlim, int zdiv)
{
  __shared__ bf16 lAh[4096];
  __shared__ bf16 lAl[4096];
  __shared__ bf16 lBh[4096];
  __shared__ bf16 lBl[4096];
  const int tid = threadIdx.x;
  const int wid = tid >> 6;
  const int lid = tid & 63;
  const int z = blockIdx.z;
  const int zo = z / zdiv, zi = z - zo*zdiv;
  const long aoff = (long)zo*a_oo + (long)zi*a_oi;
  const long boff = (long)zo*b_oo + (long)zi*b_oi;
  const long cbase = (long)zo*c_oo + (long)zi*c_oi;
  const int brow = blockIdx.y * 128;
  const int bcol = blockIdx.x * 128;

  const int ch0 = tid, ch1 = tid + 256;
  int ra0 = brow + (ch0 >> 2); if (ra0 > M-1) ra0 = M-1;
  int ra1 = brow + (ch1 >> 2); if (ra1 > M-1) ra1 = M-1;
  int rb0 = bcol + (ch0 >> 2); if (rb0 > N-1) rb0 = N-1;
  int rb1 = bcol + (ch1 >> 2); if (rb1 > N-1) rb1 = N-1;
  const int sw = ((ch0 ^ (ch0 >> 2)) & 3) * 8;
  const long ia0 = aoff + (long)ra0*a_rs + sw;
  const long ia1 = aoff + (long)ra1*a_rs + sw;
  const long ib0 = boff + (long)rb0*b_rs + sw;
  const long ib1 = boff + (long)rb1*b_rs + sw;
  bf16* dAh0 = (bf16*)((char*)lAh + wid*1024);
  bf16* dAh1 = (bf16*)((char*)lAh + 4096 + wid*1024);
  bf16* dAl0 = (bf16*)((char*)lAl + wid*1024);
  bf16* dAl1 = (bf16*)((char*)lAl + 4096 + wid*1024);
  bf16* dBh0 = (bf16*)((char*)lBh + wid*1024);
  bf16* dBh1 = (bf16*)((char*)lBh + 4096 + wid*1024);
  bf16* dBl0 = (bf16*)((char*)lBl + wid*1024);
  bf16* dBl1 = (bf16*)((char*)lBl + 4096 + wid*1024);

  f32x4 acc[4][4] = {};
  const int wm = wid >> 1, wn = wid & 1;
  const int fr = lid & 15, g8 = (lid >> 4) * 8;
  const int gx = g8 ^ ((lid & 3) << 3);

  for (int kt = 0; kt < K; kt += 32) {
    __syncthreads();
    gld_lds16(Ah + ia0 + kt, dAh0);
    gld_lds16(Ah + ia1 + kt, dAh1);
    gld_lds16(Al + ia0 + kt, dAl0);
    gld_lds16(Al + ia1 + kt, dAl1);
    gld_lds16(Bth + ib0 + kt, dBh0);
    gld_lds16(Bth + ib1 + kt, dBh1);
    gld_lds16(Btl + ib0 + kt, dBl0);
    gld_lds16(Btl + ib1 + kt, dBl1);
    __syncthreads();
    short8 fah[4], fal[4], fbh[4], fbl[4];
    #pragma unroll
    for (int m = 0; m < 4; ++m) {
      int ro = (wm*64 + m*16 + fr)*32 + gx;
      fah[m] = *(const short8*)&lAh[ro];
      fal[m] = *(const short8*)&lAl[ro];
    }
    #pragma unroll
    for (int n = 0; n < 4; ++n) {
      int ro = (wn*64 + n*16 + fr)*32 + gx;
      fbh[n] = *(const short8*)&lBh[ro];
      fbl[n] = *(const short8*)&lBl[ro];
    }
    #pragma unroll
    for (int m = 0; m < 4; ++m)
      #pragma unroll
      for (int n = 0; n < 4; ++n) {
        acc[m][n] = __builtin_amdgcn_mfma_f32_16x16x32_bf16(fal[m], fbh[n], acc[m][n], 0, 0, 0);
        acc[m][n] = __builtin_amdgcn_mfma_f32_16x16x32_bf16(fah[m], fbl[n], acc[m][n], 0, 0, 0);
        acc[m][n] = __builtin_amdgcn_mfma_f32_16x16x32_bf16(fah[m], fbh[n], acc[m][n], 0, 0, 0);
      }
  }

  const int rg = (lid >> 4) * 4;
  #pragma unroll
  for (int m = 0; m < 4; ++m) {
    #pragma unroll
    for (int n = 0; n < 4; ++n) {
      const int col = bcol + wn*64 + n*16 + fr;
      if (col < nlim) {
        #pragma unroll
        for (int j = 0; j < 4; ++j) {
          const int row = brow + wm*64 + m*16 + rg + j;
          if (row < M) {
            long off = cbase + (long)row*c_rs + col;
            float v = acc[m][n][j];
            if (Cl) {
              bf16 h = __float2bfloat16(v);
              Ch[off] = h;
              Cl[off] = __float2bfloat16(v - __bfloat162float(h));
            } else if (Ch) {
              Ch[off] = __float2bfloat16(v);
            } else {
              Cf[off] = v;
            }
          }
        }
      }
    }
  }
}

// ---------------- weight transpose fp32 -> bf16 (opt. 16-row interleave) ----------------
__global__ void wtrans(const float* __restrict__ in, bf16* __restrict__ out,
                       int R, int Cc, long in_rs, long out_rs, long in_bs, long out_bs,
                       int ilv, int radd)
{
  __shared__ float tile[32][33];
  in  += (long)blockIdx.z * in_bs;
  out += (long)blockIdx.z * out_bs;
  int r0 = blockIdx.y*32, c0 = blockIdx.x*32;
  int tx = threadIdx.x, ty = threadIdx.y;
  #pragma unroll
  for (int i = 0; i < 32; i += 8) {
    int r = r0 + ty + i, c = c0 + tx;
    if (r < R && c < Cc) tile[ty+i][tx] = in[(long)r*in_rs + c];
  }
  __syncthreads();
  #pragma unroll
  for (int i = 0; i < 32; i += 8) {
    int ro = c0 + ty + i, co = r0 + tx;
    if (ro < Cc && co < R) {
      int rr = ilv ? (((ro >> 4) << 5) + (ro & 15) + radd) : ro;
      out[(long)rr*out_rs + co] = __float2bfloat16(tile[tx][ty+i]);
    }
  }
}

// ---------------- weight transpose fp32 -> bf16 hi/lo pair ----------------
__global__ void wtrans3(const float* __restrict__ in, bf16* __restrict__ oh, bf16* __restrict__ ol,
                        int R, int Cc, long in_rs, long out_rs)
{
  __shared__ float tile[32][33];
  int r0 = blockIdx.y*32, c0 = blockIdx.x*32;
  int tx = threadIdx.x, ty = threadIdx.y;
  #pragma unroll
  for (int i = 0; i < 32; i += 8) {
    int r = r0 + ty + i, c = c0 + tx;
    if (r < R && c < Cc) tile[ty+i][tx] = in[(long)r*in_rs + c];
  }
  __syncthreads();
  #pragma unroll
  for (int i = 0; i < 32; i += 8) {
    int ro = c0 + ty + i, co = r0 + tx;
    if (ro < Cc && co < R) {
      float v = tile[tx][ty+i];
      bf16 h = __float2bfloat16(v);
      long o = (long)ro*out_rs + co;
      oh[o] = h;
      ol[o] = __float2bfloat16(v - __bfloat162float(h));
    }
  }
}

// ---------------- LayerNorm ----------------
__global__ void ln_partial(const float* __restrict__ x, float* __restrict__ part) {
  int b = blockIdx.y, blk = blockIdx.x;
  const float* xb = x + (long)b*NPB;
  int start = blk * 4374;
  float s = 0.f, ss = 0.f;
  for (int i = start + threadIdx.x; i < start + 4374; i += 256) {
    float v = xb[i]; s += v; ss += v*v;
  }
  #pragma unroll
  for (int o = 32; o; o >>= 1) { s += __shfl_down(s, o); ss += __shfl_down(ss, o); }
  __shared__ float red[2][4];
  int wid = threadIdx.x >> 6, lid = threadIdx.x & 63;
  if (lid == 0) { red[0][wid] = s; red[1][wid] = ss; }
  __syncthreads();
  if (threadIdx.x == 0) {
    float S = 0.f, SS = 0.f;
    for (int w = 0; w < 4; ++w) { S += red[0][w]; SS += red[1][w]; }
    part[(b*128 + blk)*2] = S; part[(b*128 + blk)*2 + 1] = SS;
  }
}

__global__ void ln_final(const float* __restrict__ part, float* __restrict__ stats) {
  int b = blockIdx.x, lid = threadIdx.x;
  float s = 0.f, ss = 0.f;
  for (int i = lid; i < 128; i += 64) { s += part[(b*128+i)*2]; ss += part[(b*128+i)*2+1]; }
  #pragma unroll
  for (int o = 32; o; o >>= 1) { s += __shfl_down(s, o); ss += __shfl_down(ss, o); }
  if (lid == 0) {
    float mean = s / (float)NPB;
    float var = ss / (float)NPB - mean*mean;
    stats[b*2] = mean; stats[b*2+1] = rsqrtf(var + 1e-5f);
  }
}

__global__ void ln_apply3(const float* __restrict__ x, const float* __restrict__ lnw,
                          const float* __restrict__ lnb, const float* __restrict__ stats,
                          bf16* __restrict__ th, bf16* __restrict__ tl, long ts)
{
  __shared__ float tile[32][33];
  int b = blockIdx.z;
  int s0 = blockIdx.x*32, c0 = blockIdx.y*32;
  float mean = stats[b*2], rstd = stats[b*2+1];
  int tx = threadIdx.x, ty = threadIdx.y;
  #pragma unroll
  for (int i = 0; i < 32; i += 8) {
    int c = c0 + ty + i, s = s0 + tx;
    if (s < S_) {
      long o = (long)c*S_ + s;
      tile[ty+i][tx] = (x[(long)b*NPB + o] - mean)*rstd*lnw[o] + lnb[o];
    }
  }
  __syncthreads();
  #pragma unroll
  for (int i = 0; i < 32; i += 8) {
    int s = s0 + ty + i, c = c0 + tx;
    if (s < S_) {
      float v = tile[tx][ty+i];
      bf16 h = __float2bfloat16(v);
      long o = ((long)b*S_ + s)*ts + c;
      th[o] = h;
      tl[o] = __float2bfloat16(v - __bfloat162float(h));
    }
  }
}

// ---------------- V transpose (bf16), zero pad t in [S_, SPAD) ----------------
__global__ void vtrans(const bf16* __restrict__ qkv, bf16* __restrict__ VT) {
  __shared__ float tile[32][33];
  int z = blockIdx.z; int bb = z >> 3, h = z & 7;
  const bf16* v = qkv + (long)bb*S_*C3 + 1536 + h*DH_;
  bf16* o = VT + (long)z*DH_*SPAD;
  int t0 = blockIdx.y*32, d0 = blockIdx.x*32;
  int tx = threadIdx.x, ty = threadIdx.y;
  #pragma unroll
  for (int i = 0; i < 32; i += 8) {
    int t = t0 + ty + i, d = d0 + tx;
    float val = 0.f;
    if (t < S_ && d < DH_) val = __bfloat162float(v[(long)t*C3 + d]);
    tile[ty+i][tx] = val;
  }
  __syncthreads();
  #pragma unroll
  for (int i = 0; i < 32; i += 8) {
    int d = d0 + ty + i, t = t0 + tx;
    if (d < DH_ && t < SPAD) o[(long)d*SPAD + t] = __float2bfloat16(tile[tx][ty+i]);
  }
}

// -------- softmax over bf16 hi/lo score rows, IN PLACE (row stride 2*SPAD) --------
__global__ void softmax3p(bf16* __restrict__ scores, int nrows) {
  int row = blockIdx.x*4 + (threadIdx.x >> 6);
  if (row >= nrows) return;
  int lid = threadIdx.x & 63;
  bf16* ph = scores + (long)row*2*SPAD;
  bf16* pl = ph + SPAD;
  float vals[12];
  float mx = -1e30f;
  #pragma unroll
  for (int i = 0; i < 12; ++i) {
    int t = i*64 + lid;
    float v = -1e30f;
    if (t < S_) v = __bfloat162float(ph[t]) + __bfloat162float(pl[t]);
    vals[i] = v; mx = fmaxf(mx, v);
  }
  #pragma unroll
  for (int o = 32; o; o >>= 1) mx = fmaxf(mx, __shfl_xor(mx, o));
  float sum = 0.f;
  #pragma unroll
  for (int i = 0; i < 12; ++i) { float e = __expf(vals[i] - mx); vals[i] = e; sum += e; }
  #pragma unroll
  for (int o = 32; o; o >>= 1) sum += __shfl_xor(sum, o);
  float inv = 1.f / sum;
  #pragma unroll
  for (int i = 0; i < 12; ++i) {
    int t = i*64 + lid;
    if (t < SPAD) {
      float p = (t < S_) ? vals[i]*inv : 0.f;
      bf16 h = __float2bfloat16(p);
      ph[t] = h;
      pl[t] = __float2bfloat16(p - __bfloat162float(h));
    }
  }
}

// ---------------- residual transpose-add 1 ----------------
__global__ void tadd1(const float* __restrict__ x, const float* __restrict__ oproj,
                      float* __restrict__ xattn, bf16* __restrict__ tok2,
                      float* __restrict__ tok2f)
{
  __shared__ float t_o[32][33];
  __shared__ float t_x[32][33];
  int b = blockIdx.z;
  int s0 = blockIdx.x*32, c0 = blockIdx.y*32;
  int tx = threadIdx.x, ty = threadIdx.y;
  #pragma unroll
  for (int i = 0; i < 32; i += 8) {
    int s = s0 + ty + i;
    if (s < S_) t_o[ty+i][tx] = oproj[((long)b*S_ + s)*C_ + c0 + tx];
    int s2 = s0 + tx;
    if (s2 < S_) t_x[ty+i][tx] = x[(long)b*NPB + (long)(c0+ty+i)*S_ + s2];
  }
  __syncthreads();
  #pragma unroll
  for (int i = 0; i < 32; i += 8) {
    int s = s0 + tx, c = c0 + ty + i;
    if (s < S_) xattn[(long)b*NPB + (long)c*S_ + s] = t_x[ty+i][tx] + t_o[tx][ty+i];
    int s2 = s0 + ty + i, c2 = c0 + tx;
    if (s2 < S_) {
      float v = t_x[tx][ty+i] + t_o[ty+i][tx];
      long o = ((long)b*S_ + s2)*C_ + c2;
      tok2[o] = __float2bfloat16(v);
      tok2f[o] = v;
    }
  }
}

// ---- residual transpose-add 2 (final output), sums 8 bf16 down-partials ----
// partial z for token t, col c at prt[z*MTOK*768 + t*768 + c]
__global__ void tadd2(const float* __restrict__ xattn, const bf16* __restrict__ prt,
                      float* __restrict__ out)
{
  __shared__ float t_m[32][33];
  __shared__ float t_x[32][33];
  int b = blockIdx.z;
  int s0 = blockIdx.x*32, c0 = blockIdx.y*32;
  int tx = threadIdx.x, ty = threadIdx.y;
  #pragma unroll
  for (int i = 0; i < 32; i += 8) {
    int s = s0 + ty + i;
    if (s < S_) {
      const bf16* p = prt + ((long)b*S_ + s)*768 + c0 + tx;
      float acc = 0.f;
      #pragma unroll
      for (int z = 0; z < 8; ++z) acc += __bfloat162float(p[(long)z*MTOK*768]);
      t_m[ty+i][tx] = acc;
    }
    int s2 = s0 + tx;
    if (s2 < S_) t_x[ty+i][tx] = xattn[(long)b*NPB + (long)(c0+ty+i)*S_ + s2];
  }
  __syncthreads();
  #pragma unroll
  for (int i = 0; i < 32; i += 8) {
    int s = s0 + tx, c = c0 + ty + i;
    if (s < S_) out[(long)b*NPB + (long)c*S_ + s] = t_x[ty+i][tx] + t_m[tx][ty+i];
  }
}

// ---------------- router: top-2 of 3 from fp32 tok2, normalized weights ----------------
__global__ void router_k(const float* __restrict__ tok2f, const float* __restrict__ rw,
                         float* __restrict__ wfull)
{
  int t = blockIdx.x*4 + (threadIdx.x >> 6);
  if (t >= MTOK) return;
  int lid = threadIdx.x & 63;
  const float* tk = tok2f + (long)t*C_;
  float a0 = 0.f, a1 = 0.f, a2 = 0.f;
  for (int i = lid; i < C_; i += 64) {
    float v = tk[i];
    a0 += v*rw[i*3+0]; a1 += v*rw[i*3+1]; a2 += v*rw[i*3+2];
  }
  #pragma unroll
  for (int o = 32; o; o >>= 1) {
    a0 += __shfl_xor(a0, o); a1 += __shfl_xor(a1, o); a2 += __shfl_xor(a2, o);
  }
  if (lid == 0) {
    float m = fmaxf(a0, fmaxf(a1, a2));
    float e0 = __expf(a0-m), e1 = __expf(a1-m), e2 = __expf(a2-m);
    int emin = 0; float pm = e0;
    if (e1 <= pm) { pm = e1; emin = 1; }
    if (e2 <= pm) { pm = e2; emin = 2; }
    float rest = e0 + e1 + e2 - pm;
    wfull[t*3+0] = (emin == 0) ? 0.f : e0/rest;
    wfull[t*3+1] = (emin == 1) ? 0.f : e1/rest;
    wfull[t*3+2] = (emin == 2) ? 0.f : e2/rest;
  }
}

// =============================== host ===============================
static inline void launch_gemm3(hipStream_t st,
    const bf16* Ah, const bf16* Al, long a_rs, long a_oo, long a_oi,
    const bf16* Bh, const bf16* Bl, long b_rs, long b_oo, long b_oi,
    float* Cf, bf16* Ch, bf16* Cl, long c_rs, long c_oo, long c_oi,
    int M, int N, int K, int nlim, int zdiv, int nz)
{
  dim3 g((N + 127)/128, (M + 127)/128, nz);
  gemm3_bt<<<g, 256, 0, st>>>(Ah, Al, a_rs, a_oo, a_oi, Bh, Bl, b_rs, b_oo, b_oi,
                              Cf, Ch, Cl, c_rs, c_oo, c_oi, M, N, K, nlim, zdiv);
}

extern "C" void kernel_launch(void* const* d_in, const int* in_sizes, int n_in,
                              void* d_out, int out_size, void* d_ws, size_t ws_size,
                              hipStream_t stream)
{
  const float* x      = (const float*)d_in[0];
  const float* ln_w   = (const float*)d_in[1];
  const float* ln_b   = (const float*)d_in[2];
  const float* qkv_w  = (const float*)d_in[3];
  const float* proj_w = (const float*)d_in[4];
  const float* rout_w = (const float*)d_in[5];
  const float* gate_w = (const float*)d_in[6];
  const float* up_w   = (const float*)d_in[7];
  const float* down_w = (const float*)d_in[8];
  float* out = (float*)d_out;

  char* ws = (char*)d_ws;
  size_t off = 0;
  auto alloc = [&](size_t bytes) { size_t r = off; off += (bytes + 255) & ~(size_t)255; return r; };

  // persistent (~82.6 MB)
  size_t o_stats = alloc(8*2*4);
  size_t o_part  = alloc(8*128*2*4);
  size_t o_wfull = alloc((size_t)MTOK*3*4);
  size_t o_qkvTh = alloc((size_t)C3*C_*2);
  size_t o_qkvTl = alloc((size_t)C3*C_*2);
  size_t o_prjTh = alloc((size_t)C_*C_*2);
  size_t o_prjTl = alloc((size_t)C_*C_*2);
  size_t o_guT   = alloc((size_t)GUN*C_*2);      // gate/up 16-row interleaved
  size_t o_downT = alloc((size_t)C_*DK*2);
  size_t o_xattn = alloc((size_t)B_*NPB*4);
  size_t o_tok2  = alloc((size_t)MTOK*C_*2);
  size_t o_tok2f = alloc((size_t)MTOK*C_*4);
  size_t big0 = off;
  // phase A (attention): fixed buffers + union region (tok | scores | oproj)
  size_t o_qkvh  = alloc((size_t)MTOK*C3*2);
  size_t o_qkvl  = alloc((size_t)MTOK*C3*2);
  size_t o_VTh   = alloc((size_t)64*DH_*SPAD*2);
  size_t o_VTl   = alloc((size_t)64*DH_*SPAD*2);
  size_t o_aoh   = alloc((size_t)MTOK*C_*2);
  size_t o_aol   = alloc((size_t)MTOK*C_*2);
  size_t o_union = alloc((size_t)32*S_*SPAD*4);  // 68.7 MB
  size_t endA = off;
  // phase B (MoE): hidden + 8 bf16 partials
  off = big0;
  size_t o_hid = alloc((size_t)MTOK*DK*2);
  size_t o_prt = alloc((size_t)8*MTOK*768*2);
  size_t endB = off;
  size_t needed = endA > endB ? endA : endB;
  if (ws_size < needed) return;  // insufficient workspace: visible failure

  float* stats  = (float*)(ws + o_stats);
  float* part   = (float*)(ws + o_part);
  float* wfull  = (float*)(ws + o_wfull);
  bf16*  qkvTh  = (bf16*)(ws + o_qkvTh);
  bf16*  qkvTl  = (bf16*)(ws + o_qkvTl);
  bf16*  prjTh  = (bf16*)(ws + o_prjTh);
  bf16*  prjTl  = (bf16*)(ws + o_prjTl);
  bf16*  guT    = (bf16*)(ws + o_guT);
  bf16*  downT  = (bf16*)(ws + o_downT);
  float* xattn  = (float*)(ws + o_xattn);
  bf16*  tok2   = (bf16*)(ws + o_tok2);
  float* tok2f  = (float*)(ws + o_tok2f);
  bf16*  qkvh   = (bf16*)(ws + o_qkvh);
  bf16*  qkvl   = (bf16*)(ws + o_qkvl);
  bf16*  VTh    = (bf16*)(ws + o_VTh);
  bf16*  VTl    = (bf16*)(ws + o_VTl);
  bf16*  aoh    = (bf16*)(ws + o_aoh);
  bf16*  aol    = (bf16*)(ws + o_aol);
  // union region occupants (live ranges disjoint in stream order):
  bf16*  tokh   = (bf16*)(ws + o_union);
  bf16*  tokl   = (bf16*)(ws + o_union + (size_t)MTOK*C_*2);
  bf16*  Pbase  = (bf16*)(ws + o_union);
  float* oproj  = (float*)(ws + o_union);
  bf16*  hidden = (bf16*)(ws + o_hid);
  bf16*  prt    = (bf16*)(ws + o_prt);

  dim3 b32(32, 8);

  // weight conversions (gate/up 16-row interleaved per 32-row block of guT)
  wtrans3<<<dim3(72,24,1), b32, 0, stream>>>(qkv_w,  qkvTh, qkvTl, 768, 2304, 2304, 768);
  wtrans3<<<dim3(24,24,1), b32, 0, stream>>>(proj_w, prjTh, prjTl, 768, 768,  768,  768);
  wtrans<<<dim3(64,24,3), b32, 0, stream>>>(gate_w, guT, 768, 2048, 2048, 768,
                                            (long)768*2048, (long)4096*768, 1, 0);
  wtrans<<<dim3(64,24,3), b32, 0, stream>>>(up_w, guT, 768, 2048, 2048, 768,
                                            (long)768*2048, (long)4096*768, 1, 16);
  wtrans<<<dim3(24,64,3), b32, 0, stream>>>(down_w, downT, 2048, 768, 768, 6144,
                                            (long)2048*768, 2048, 0, 0);

  // LayerNorm -> tok hi/lo (b,s,c)
  ln_partial<<<dim3(128,8), 256, 0, stream>>>(x, part);
  ln_final<<<8, 64, 0, stream>>>(part, stats);
  ln_apply3<<<dim3(23,24,8), b32, 0, stream>>>(x, ln_w, ln_b, stats, tokh, tokl, C_);

  // qkv = tok @ qkv_w (bf16x3, hi/lo out); tok region dead afterwards
  launch_gemm3(stream, tokh, tokl, C_, 0, 0, qkvTh, qkvTl, C_, 0, 0,
               nullptr, qkvh, qkvl, C3, 0, 0, MTOK, C3, C_, C3, 1, 1);

  // V^T per (b,h), zero-padded to SPAD (hi and lo)
  vtrans<<<dim3(3,23,64), b32, 0, stream>>>(qkvh, VTh);
  vtrans<<<dim3(3,23,64), b32, 0, stream>>>(qkvl, VTl);

  // attention in 2 chunks of 32 (b,h)-pairs (4 batches each)
  for (int c = 0; c < 2; ++c) {
    const long qoff = (long)(4*c)*S_*C3;
    launch_gemm3(stream,
        qkvh + qoff, qkvl + qoff, C3, (long)S_*C3, DH_,
        qkvh + qoff + 768, qkvl + qoff + 768, C3, (long)S_*C3, DH_,
        nullptr, Pbase, Pbase + SPAD, 2*SPAD, (long)8*S_*2*SPAD, (long)S_*2*SPAD,
        S_, S_, DH_, SPAD, 8, 32);
    softmax3p<<<5832, 256, 0, stream>>>(Pbase, 32*S_);
    launch_gemm3(stream,
        Pbase, Pbase + SPAD, 2*SPAD, (long)8*S_*2*SPAD, (long)S_*2*SPAD,
        VTh + (size_t)c*32*DH_*SPAD, VTl + (size_t)c*32*DH_*SPAD, SPAD,
        (long)8*DH_*SPAD, (long)DH_*SPAD,
        nullptr, aoh + (size_t)(4*c)*S_*C_, aol + (size_t)(4*c)*S_*C_,
        C_, (long)S_*C_, DH_,
        S_, DH_, SPAD, DH_, 8, 32);
  }

  // oproj = attnout @ proj_w (fp32 out, into union region — P dead now)
  launch_gemm3(stream, aoh, aol, C_, 0, 0, prjTh, prjTl, C_, 0, 0,
               oproj, nullptr, nullptr, C_, 0, 0, MTOK, C_, C_, C_, 1, 1);

  // residual + layouts
  tadd1<<<dim3(23,24,8), b32, 0, stream>>>(x, oproj, xattn, tok2, tok2f);

  // router weights (fp32 path) — must precede fused GU epilogue
  router_k<<<1458, 256, 0, stream>>>(tok2f, rout_w, wfull);

  // GU gemm with fused silu*up*w epilogue -> hidden [MTOK][6144]
  gemm8<<<dim3(GUN/256, 23, 1), 512, 0, stream>>>(
      tok2, C_, guT, C_, nullptr, hidden, DK, 0, MTOK, GUN, C_, wfull, 3);

  // down GEMM (K=6144) nz=8 K-split, bf16 partials
  gemm8<<<dim3(C_/256, 23, 8), 512, 0, stream>>>(
      hidden, DK, downT, DK, nullptr, prt, 768, (long)MTOK*768, MTOK, C_, DK/8,
      nullptr, 0);

  // final residual transpose-add (sums 8 partials) into output
  tadd2<<<dim3(23,24,8), b32, 0, stream>>>(xattn, prt, out);
}